// Round 1
// baseline (6379.541 us; speedup 1.0000x reference)
//
#include <hip/hip_runtime.h>
#include <math.h>

// ---- model dims ----
#define DIN_   1024
#define DSTATE_ 64
#define NH_    32
#define HDIM_  32
#define CONVD_ 1152   // DIN + 2*DSTATE
#define DPROJ_ 2208   // 2*DIN + 2*DSTATE + NH
#define HID_   512
#define LSEQ_  4096
#define BB_    2
#define LT_    2048   // after stride-2 downsample
#define NHEAD_ 8
#define HD_    64     // head dim = 512/8
#define DFF_   1024

__device__ __forceinline__ float siluf(float x) { return x / (1.f + expf(-x)); }

// ============================================================
// Generic fp32 GEMM: C[M,N] = act(A[M,K] @ W[K,N] + bias) + res
// tile 128x64, 256 threads, 8x4 microtile, K-tile 16.
// Requires M%128==0, K%16==0, N%4==0 (cols guarded).
// act: 0=none, 1=gelu(exact)
// ============================================================
__global__ __launch_bounds__(256) void ec_gemm(
    const float* __restrict__ A, const float* __restrict__ W,
    const float* __restrict__ bias, const float* __restrict__ res,
    float* __restrict__ C, int M, int N, int K, int act)
{
  __shared__ float As[16][128];
  __shared__ float Ws[16][64];
  const int tid = threadIdx.x;
  const int m0 = blockIdx.y * 128;
  const int n0 = blockIdx.x * 64;
  const int ty = tid >> 4, tx = tid & 15;       // ty: 8 rows each, tx: 4 cols each
  const int lm = tid >> 1, lkq = (tid & 1) * 8; // A-load mapping
  const int wk = tid >> 4, wn = (tid & 15) * 4; // W-load mapping
  float acc[8][4];
#pragma unroll
  for (int i = 0; i < 8; ++i)
#pragma unroll
    for (int j = 0; j < 4; ++j) acc[i][j] = 0.f;

  for (int k0 = 0; k0 < K; k0 += 16) {
    const float* ap = A + (size_t)(m0 + lm) * K + k0 + lkq;
    const float4 a0 = *(const float4*)ap;
    const float4 a1 = *(const float4*)(ap + 4);
    float4 w4 = make_float4(0.f, 0.f, 0.f, 0.f);
    if (n0 + wn < N) w4 = *(const float4*)(W + (size_t)(k0 + wk) * N + n0 + wn);
    As[lkq + 0][lm] = a0.x; As[lkq + 1][lm] = a0.y; As[lkq + 2][lm] = a0.z; As[lkq + 3][lm] = a0.w;
    As[lkq + 4][lm] = a1.x; As[lkq + 5][lm] = a1.y; As[lkq + 6][lm] = a1.z; As[lkq + 7][lm] = a1.w;
    Ws[wk][wn + 0] = w4.x; Ws[wk][wn + 1] = w4.y; Ws[wk][wn + 2] = w4.z; Ws[wk][wn + 3] = w4.w;
    __syncthreads();
#pragma unroll
    for (int kk = 0; kk < 16; ++kk) {
      float bv[4], av[8];
#pragma unroll
      for (int j = 0; j < 4; ++j) bv[j] = Ws[kk][tx * 4 + j];
#pragma unroll
      for (int i = 0; i < 8; ++i) av[i] = As[kk][ty * 8 + i];
#pragma unroll
      for (int i = 0; i < 8; ++i)
#pragma unroll
        for (int j = 0; j < 4; ++j) acc[i][j] += av[i] * bv[j];
    }
    __syncthreads();
  }
#pragma unroll
  for (int i = 0; i < 8; ++i) {
    const int m = m0 + ty * 8 + i;
#pragma unroll
    for (int j = 0; j < 4; ++j) {
      const int n = n0 + tx * 4 + j;
      if (n < N) {
        float v = acc[i][j];
        if (bias) v += bias[n];
        if (act == 1) v = 0.5f * v * (1.f + erff(v * 0.70710678118f));
        if (res) v += res[(size_t)m * N + n];
        C[(size_t)m * N + n] = v;
      }
    }
  }
}

static inline void gemm(hipStream_t s, const float* A, const float* W, const float* bias,
                        const float* res, float* C, int M, int N, int K, int act) {
  dim3 g((N + 63) / 64, M / 128), b(256);
  ec_gemm<<<g, b, 0, s>>>(A, W, bias, res, C, M, N, K, act);
}

// ============================================================
// Depthwise causal conv (DCONV=4) + SiLU on the xBC slice of zxbcdt.
// ============================================================
__global__ void ec_conv1d_silu(const float* __restrict__ zx, const float* __restrict__ cw,
                               const float* __restrict__ cb, float* __restrict__ xBC)
{
  int idx = blockIdx.x * 256 + threadIdx.x;
  const int total = BB_ * LSEQ_ * CONVD_;
  if (idx >= total) return;
  int c = idx % CONVD_;
  int l = (idx / CONVD_) % LSEQ_;
  int b = idx / (CONVD_ * LSEQ_);
  const float* base = zx + (size_t)b * LSEQ_ * DPROJ_ + DIN_ + c;
  float s = cb[c];
#pragma unroll
  for (int j = 0; j < 4; ++j) {
    int ll = l - 3 + j;
    if (ll >= 0) s += base[(size_t)ll * DPROJ_] * cw[c * 4 + j];
  }
  xBC[idx] = siluf(s);
}

// ============================================================
// dt = softplus(dt_raw + dtb); decay = exp(-exp(Alog)*dt)
// ============================================================
__global__ void ec_dtdecay(const float* __restrict__ zx, const float* __restrict__ dtb,
                           const float* __restrict__ Alog, float* __restrict__ dts,
                           float* __restrict__ dec)
{
  int idx = blockIdx.x * 256 + threadIdx.x;   // B*L*NH total
  int h = idx & 31;
  float x = zx[(size_t)(idx >> 5) * DPROJ_ + (DIN_ + CONVD_) + h] + dtb[h];
  float sp = (x > 20.f) ? x : log1pf(expf(x));
  dts[idx] = sp;
  dec[idx] = expf(-expf(Alog[h]) * sp);
}

// ============================================================
// SSM sequential scan. Block per (h, b): 512 threads own 32x64 state.
// ============================================================
struct SVals { float dsc, dcv, xv; float4 Bv, Cv; };

__device__ __forceinline__ void sload(SVals& s, const float* __restrict__ xBC,
                                      const float* __restrict__ dts, const float* __restrict__ dec,
                                      size_t r, int h, int p, int n0)
{
  const float* xr = xBC + r * CONVD_;
  s.dsc = dts[r * NH_ + h];
  s.dcv = dec[r * NH_ + h];
  s.xv  = xr[h * HDIM_ + p];
  s.Bv  = *(const float4*)(xr + DIN_ + n0);
  s.Cv  = *(const float4*)(xr + DIN_ + DSTATE_ + n0);
}

__global__ __launch_bounds__(512) void ec_scan(
    const float* __restrict__ xBC, const float* __restrict__ dts,
    const float* __restrict__ dec, const float* __restrict__ Dp,
    float* __restrict__ y)
{
  const int h = blockIdx.x, b = blockIdx.y;
  const int tid = threadIdx.x;
  const int p = tid >> 4, ni = tid & 15, n0 = ni * 4;
  const float Dh = Dp[h];
  const size_t rowB = (size_t)b * LSEQ_;
  float h0 = 0.f, h1 = 0.f, h2 = 0.f, h3 = 0.f;
  SVals v0, v1, v2;
  sload(v0, xBC, dts, dec, rowB + 0, h, p, n0);
  sload(v1, xBC, dts, dec, rowB + 1, h, p, n0);
  for (int t = 0; t < LSEQ_; ++t) {
    int tp = (t + 2 < LSEQ_) ? t + 2 : LSEQ_ - 1;
    sload(v2, xBC, dts, dec, rowB + tp, h, p, n0);
    const float dx = v0.dsc * v0.xv;
    h0 = h0 * v0.dcv + dx * v0.Bv.x;
    h1 = h1 * v0.dcv + dx * v0.Bv.y;
    h2 = h2 * v0.dcv + dx * v0.Bv.z;
    h3 = h3 * v0.dcv + dx * v0.Bv.w;
    float acc = h0 * v0.Cv.x + h1 * v0.Cv.y + h2 * v0.Cv.z + h3 * v0.Cv.w;
    acc += __shfl_xor(acc, 1, 16);
    acc += __shfl_xor(acc, 2, 16);
    acc += __shfl_xor(acc, 4, 16);
    acc += __shfl_xor(acc, 8, 16);
    if (ni == 0) y[(rowB + t) * DIN_ + h * HDIM_ + p] = acc + Dh * v0.xv;
    v0 = v1; v1 = v2;
  }
}

// ============================================================
// t = y * silu(z); out = rmsnorm(t)*nw   (row width 1024)
// ============================================================
__global__ __launch_bounds__(256) void ec_gate_rms(
    const float* __restrict__ y, const float* __restrict__ zx,
    const float* __restrict__ nw, float* __restrict__ out)
{
  const int row = blockIdx.x;
  const float* yr = y + (size_t)row * DIN_;
  const float* zr = zx + (size_t)row * DPROJ_;
  float v[4]; float ss = 0.f;
#pragma unroll
  for (int j = 0; j < 4; ++j) {
    int c = j * 256 + threadIdx.x;
    float t = yr[c] * siluf(zr[c]);
    v[j] = t; ss += t * t;
  }
#pragma unroll
  for (int m = 32; m >= 1; m >>= 1) ss += __shfl_xor(ss, m, 64);
  __shared__ float buf[4];
  if ((threadIdx.x & 63) == 0) buf[threadIdx.x >> 6] = ss;
  __syncthreads();
  ss = buf[0] + buf[1] + buf[2] + buf[3];
  float scale = rsqrtf(ss / (float)DIN_ + 1e-5f);
#pragma unroll
  for (int j = 0; j < 4; ++j) {
    int c = j * 256 + threadIdx.x;
    out[(size_t)row * DIN_ + c] = v[j] * scale * nw[c];
  }
}

// ============================================================
// out = rmsnorm(a + b)*w    (row width 512)
// ============================================================
__global__ __launch_bounds__(128) void ec_rmsadd(
    const float* __restrict__ a, const float* __restrict__ bres,
    const float* __restrict__ w, float* __restrict__ out)
{
  const int row = blockIdx.x;
  const float* ar = a + (size_t)row * HID_;
  const float* br = bres + (size_t)row * HID_;
  float v[4]; float ss = 0.f;
#pragma unroll
  for (int j = 0; j < 4; ++j) {
    int c = j * 128 + threadIdx.x;
    float t = ar[c] + br[c];
    v[j] = t; ss += t * t;
  }
#pragma unroll
  for (int m = 32; m >= 1; m >>= 1) ss += __shfl_xor(ss, m, 64);
  __shared__ float buf[2];
  if ((threadIdx.x & 63) == 0) buf[threadIdx.x >> 6] = ss;
  __syncthreads();
  ss = buf[0] + buf[1];
  float scale = rsqrtf(ss / (float)HID_ + 1e-5f);
#pragma unroll
  for (int j = 0; j < 4; ++j) {
    int c = j * 128 + threadIdx.x;
    out[(size_t)row * HID_ + c] = v[j] * scale * w[c];
  }
}

// ============================================================
// layernorm(in)*w + b   (row width 512)
// ============================================================
__global__ __launch_bounds__(128) void ec_ln(
    const float* __restrict__ in, const float* __restrict__ w,
    const float* __restrict__ bb, float* __restrict__ out)
{
  const int row = blockIdx.x;
  const float* ir = in + (size_t)row * HID_;
  float v[4]; float s = 0.f, s2 = 0.f;
#pragma unroll
  for (int j = 0; j < 4; ++j) {
    int c = j * 128 + threadIdx.x;
    float t = ir[c];
    v[j] = t; s += t; s2 += t * t;
  }
#pragma unroll
  for (int m = 32; m >= 1; m >>= 1) { s += __shfl_xor(s, m, 64); s2 += __shfl_xor(s2, m, 64); }
  __shared__ float buf[4];
  if ((threadIdx.x & 63) == 0) { int wi = threadIdx.x >> 6; buf[wi * 2] = s; buf[wi * 2 + 1] = s2; }
  __syncthreads();
  s = buf[0] + buf[2]; s2 = buf[1] + buf[3];
  float mean = s / (float)HID_;
  float var = s2 / (float)HID_ - mean * mean;
  float inv = rsqrtf(var + 1e-5f);
#pragma unroll
  for (int j = 0; j < 4; ++j) {
    int c = j * 128 + threadIdx.x;
    out[(size_t)row * HID_ + c] = (v[j] - mean) * inv * w[c] + bb[c];
  }
}

// ============================================================
// transpose ds_w (O,I,K) -> (K,I,O)
// ============================================================
__global__ void ec_transpose_dsw(const float* __restrict__ w, float* __restrict__ wt)
{
  int idx = blockIdx.x * 256 + threadIdx.x;
  if (idx < HID_ * HID_ * 3) {
    int k = idx % 3;
    int i = (idx / 3) % HID_;
    int o = idx / (3 * HID_);
    wt[((size_t)k * HID_ + i) * HID_ + o] = w[idx];
  }
}

// ============================================================
// strided downsample conv: out[b,lo,o] = sum_{k,i} x[b,2lo+k-1,i]*w[o,i,k] + b[o]
// ============================================================
__global__ __launch_bounds__(512) void ec_dsconv(
    const float* __restrict__ x, const float* __restrict__ wt,
    const float* __restrict__ bias, float* __restrict__ out)
{
  const int b = blockIdx.y;
  const int lo0 = blockIdx.x * 16;
  const int o = threadIdx.x;
  __shared__ float xs[33][64];
  float acc[16];
#pragma unroll
  for (int q = 0; q < 16; ++q) acc[q] = 0.f;
  for (int ic = 0; ic < 8; ++ic) {
    for (int idx = threadIdx.x; idx < 33 * 64; idx += 512) {
      int r = idx >> 6, ii = idx & 63;
      int l = 2 * lo0 - 1 + r;
      xs[r][ii] = (l >= 0) ? x[((size_t)b * LSEQ_ + l) * HID_ + ic * 64 + ii] : 0.f;
    }
    __syncthreads();
    for (int ii = 0; ii < 64; ++ii) {
      int i = ic * 64 + ii;
      float w0 = wt[((size_t)0 * HID_ + i) * HID_ + o];
      float w1 = wt[((size_t)1 * HID_ + i) * HID_ + o];
      float w2 = wt[((size_t)2 * HID_ + i) * HID_ + o];
#pragma unroll
      for (int q = 0; q < 16; ++q)
        acc[q] += xs[2 * q + 0][ii] * w0 + xs[2 * q + 1][ii] * w1 + xs[2 * q + 2][ii] * w2;
    }
    __syncthreads();
  }
#pragma unroll
  for (int q = 0; q < 16; ++q)
    out[((size_t)b * LT_ + lo0 + q) * HID_ + o] = acc[q] + bias[o];
}

// ============================================================
// flash-style attention: qkv [B*LT,1536] -> out [B*LT,512]
// ============================================================
__global__ __launch_bounds__(256) void ec_attn(
    const float* __restrict__ qkv, float* __restrict__ out)
{
  const int b = blockIdx.z, h = blockIdx.y, qt = blockIdx.x;
  __shared__ float Qs[32][65], Ks[64][65], Vs[64][65], Ps[32][65];
  const int tid = threadIdx.x;
  const int tq = tid >> 4, tk = tid & 15;
  {
    int r = tid >> 3;
    int c0 = (tid & 7) * 8;
    const float* qp = qkv + ((size_t)b * LT_ + qt * 32 + r) * 1536 + h * HD_ + c0;
    float4 q0 = *(const float4*)qp;
    float4 q1 = *(const float4*)(qp + 4);
    Qs[r][c0 + 0] = q0.x; Qs[r][c0 + 1] = q0.y; Qs[r][c0 + 2] = q0.z; Qs[r][c0 + 3] = q0.w;
    Qs[r][c0 + 4] = q1.x; Qs[r][c0 + 5] = q1.y; Qs[r][c0 + 6] = q1.z; Qs[r][c0 + 7] = q1.w;
  }
  float mA = -1e30f, mB = -1e30f, lA = 0.f, lB = 0.f;
  float oA[4] = {0.f, 0.f, 0.f, 0.f}, oB[4] = {0.f, 0.f, 0.f, 0.f};
  __syncthreads();
  for (int kt = 0; kt < LT_ / 64; ++kt) {
#pragma unroll
    for (int rr = 0; rr < 4; ++rr) {
      int r = (tid >> 4) + rr * 16;
      int c0 = (tid & 15) * 4;
      const float* kp = qkv + ((size_t)b * LT_ + kt * 64 + r) * 1536 + HID_ + h * HD_ + c0;
      float4 kv = *(const float4*)kp;
      float4 vv = *(const float4*)(kp + HID_);
      Ks[r][c0 + 0] = kv.x; Ks[r][c0 + 1] = kv.y; Ks[r][c0 + 2] = kv.z; Ks[r][c0 + 3] = kv.w;
      Vs[r][c0 + 0] = vv.x; Vs[r][c0 + 1] = vv.y; Vs[r][c0 + 2] = vv.z; Vs[r][c0 + 3] = vv.w;
    }
    __syncthreads();
    float sA[4] = {0.f, 0.f, 0.f, 0.f}, sB[4] = {0.f, 0.f, 0.f, 0.f};
    for (int d = 0; d < HD_; ++d) {
      float qa = Qs[tq * 2][d], qb = Qs[tq * 2 + 1][d];
#pragma unroll
      for (int j = 0; j < 4; ++j) {
        float kvv = Ks[tk * 4 + j][d];
        sA[j] += qa * kvv; sB[j] += qb * kvv;
      }
    }
#pragma unroll
    for (int j = 0; j < 4; ++j) { sA[j] *= 0.125f; sB[j] *= 0.125f; }
    float mtA = fmaxf(fmaxf(sA[0], sA[1]), fmaxf(sA[2], sA[3]));
    float mtB = fmaxf(fmaxf(sB[0], sB[1]), fmaxf(sB[2], sB[3]));
#pragma unroll
    for (int m = 1; m <= 8; m <<= 1) {
      mtA = fmaxf(mtA, __shfl_xor(mtA, m, 16));
      mtB = fmaxf(mtB, __shfl_xor(mtB, m, 16));
    }
    float mnA = fmaxf(mA, mtA), mnB = fmaxf(mB, mtB);
    float rA = expf(mA - mnA), rB = expf(mB - mnB);
    float pA[4], pB[4]; float suA = 0.f, suB = 0.f;
#pragma unroll
    for (int j = 0; j < 4; ++j) {
      pA[j] = expf(sA[j] - mnA); suA += pA[j];
      pB[j] = expf(sB[j] - mnB); suB += pB[j];
      Ps[tq * 2][tk * 4 + j] = pA[j];
      Ps[tq * 2 + 1][tk * 4 + j] = pB[j];
    }
#pragma unroll
    for (int m = 1; m <= 8; m <<= 1) {
      suA += __shfl_xor(suA, m, 16);
      suB += __shfl_xor(suB, m, 16);
    }
    lA = lA * rA + suA; lB = lB * rB + suB;
    mA = mnA; mB = mnB;
    __syncthreads();
#pragma unroll
    for (int j = 0; j < 4; ++j) { oA[j] *= rA; oB[j] *= rB; }
    for (int kk = 0; kk < 64; ++kk) {
      float pa = Ps[tq * 2][kk], pb = Ps[tq * 2 + 1][kk];
#pragma unroll
      for (int j = 0; j < 4; ++j) {
        float vv = Vs[kk][tk * 4 + j];
        oA[j] += pa * vv; oB[j] += pb * vv;
      }
    }
    __syncthreads();
  }
  float invA = 1.f / lA, invB = 1.f / lB;
  size_t rowA = (size_t)b * LT_ + qt * 32 + tq * 2;
#pragma unroll
  for (int j = 0; j < 4; ++j) {
    int c = h * HD_ + tk * 4 + j;
    out[rowA * HID_ + c] = oA[j] * invA;
    out[(rowA + 1) * HID_ + c] = oB[j] * invB;
  }
}

// ============================================================
// host launch
// ============================================================
extern "C" void kernel_launch(void* const* d_in, const int* in_sizes, int n_in,
                              void* d_out, int out_size, void* d_ws, size_t ws_size,
                              hipStream_t stream)
{
  const float* x_in   = (const float*)d_in[0];
  const float* Wp     = (const float*)d_in[1];
  const float* bp     = (const float*)d_in[2];
  const float* m_Wi[2]   = {(const float*)d_in[3],  (const float*)d_in[11]};
  const float* m_cw[2]   = {(const float*)d_in[4],  (const float*)d_in[12]};
  const float* m_cb[2]   = {(const float*)d_in[5],  (const float*)d_in[13]};
  const float* m_dtb[2]  = {(const float*)d_in[6],  (const float*)d_in[14]};
  const float* m_Alog[2] = {(const float*)d_in[7],  (const float*)d_in[15]};
  const float* m_D[2]    = {(const float*)d_in[8],  (const float*)d_in[16]};
  const float* m_nw[2]   = {(const float*)d_in[9],  (const float*)d_in[17]};
  const float* m_Wo[2]   = {(const float*)d_in[10], (const float*)d_in[18]};
  const float* n_w[2]    = {(const float*)d_in[19], (const float*)d_in[20]};
  const float* ds_w   = (const float*)d_in[21];
  const float* ds_b   = (const float*)d_in[22];
  const float* t_Wqkv = (const float*)d_in[23];
  const float* t_bqkv = (const float*)d_in[24];
  const float* t_Wo   = (const float*)d_in[25];
  const float* t_bo   = (const float*)d_in[26];
  const float* t_W1   = (const float*)d_in[27];
  const float* t_b1   = (const float*)d_in[28];
  const float* t_W2   = (const float*)d_in[29];
  const float* t_b2   = (const float*)d_in[30];
  const float* t_ln1w = (const float*)d_in[31];
  const float* t_ln1b = (const float*)d_in[32];
  const float* t_ln2w = (const float*)d_in[33];
  const float* t_ln2b = (const float*)d_in[34];
  const float* on_w   = (const float*)d_in[35];
  const float* on_b   = (const float*)d_in[36];

  char* ws = (char*)d_ws;
  float* bx   = (float*)(ws + 0);           // [8192,512]  residual stream
  float* bzx  = (float*)(ws + 16777216);    // [8192,2208] zxbcdt
  float* bxbc = (float*)(ws + 89128960);    // [8192,1152] xBC / reuse
  float* by   = (float*)(ws + 126877696);   // [8192,1024] scan y / reuse
  float* bdt  = (float*)(ws + 160432128);   // [8192,32]
  float* bdec = (float*)(ws + 161480704);   // [8192,32]
  float* bwt  = (float*)(ws + 162529280);   // [3,512,512]

  const int MR = BB_ * LSEQ_;  // 8192
  const int MT = BB_ * LT_;    // 4096

  gemm(stream, x_in, Wp, bp, nullptr, bx, MR, HID_, 1024, 0);

  for (int blk = 0; blk < 2; ++blk) {
    gemm(stream, bx, m_Wi[blk], nullptr, nullptr, bzx, MR, DPROJ_, HID_, 0);
    ec_conv1d_silu<<<(MR * CONVD_ + 255) / 256, 256, 0, stream>>>(bzx, m_cw[blk], m_cb[blk], bxbc);
    ec_dtdecay<<<(MR * NH_) / 256, 256, 0, stream>>>(bzx, m_dtb[blk], m_Alog[blk], bdt, bdec);
    ec_scan<<<dim3(NH_, BB_), 512, 0, stream>>>(bxbc, bdt, bdec, m_D[blk], by);
    ec_gate_rms<<<MR, 256, 0, stream>>>(by, bzx, m_nw[blk], bxbc);
    gemm(stream, bxbc, m_Wo[blk], nullptr, nullptr, by, MR, HID_, DIN_, 0);
    ec_rmsadd<<<MR, 128, 0, stream>>>(by, bx, n_w[blk], bx);
  }

  ec_transpose_dsw<<<(HID_ * HID_ * 3 + 255) / 256, 256, 0, stream>>>(ds_w, bwt);
  float* bxds = bzx;                                // [4096,512]
  float* bqkv = (float*)((char*)bzx + 8388608);     // [4096,1536]
  ec_dsconv<<<dim3(LT_ / 16, BB_), 512, 0, stream>>>(bx, bwt, ds_b, bxds);

  gemm(stream, bxds, t_Wqkv, t_bqkv, nullptr, bqkv, MT, 3 * HID_, HID_, 0);
  float* batto = bxbc;                              // [4096,512]
  float* bt1   = (float*)((char*)bxbc + 8388608);   // [4096,512]
  ec_attn<<<dim3(LT_ / 32, NHEAD_, BB_), 256, 0, stream>>>(bqkv, batto);
  gemm(stream, batto, t_Wo, t_bo, bxds, bt1, MT, HID_, HID_, 0);
  float* bxt2 = by;                                 // [4096,512]
  ec_ln<<<MT, 128, 0, stream>>>(bt1, t_ln1w, t_ln1b, bxt2);
  float* bff = bzx;                                 // [4096,1024]
  gemm(stream, bxt2, t_W1, t_b1, nullptr, bff, MT, DFF_, HID_, 1);
  float* bt2 = bxbc;                                // [4096,512]
  gemm(stream, bff, t_W2, t_b2, bxt2, bt2, MT, HID_, DFF_, 0);
  float* bxt3 = (float*)((char*)bxbc + 8388608);
  ec_ln<<<MT, 128, 0, stream>>>(bt2, t_ln2w, t_ln2b, bxt3);
  ec_ln<<<MT, 128, 0, stream>>>(bxt3, on_w, on_b, (float*)d_out);
}

// Round 2
// 2840.142 us; speedup vs baseline: 2.2462x; 2.2462x over previous
//
#include <hip/hip_runtime.h>
#include <math.h>

// ---- model dims ----
#define DIN_   1024
#define DSTATE_ 64
#define NH_    32
#define HDIM_  32
#define CONVD_ 1152   // DIN + 2*DSTATE
#define DPROJ_ 2208   // 2*DIN + 2*DSTATE + NH
#define HID_   512
#define LSEQ_  4096
#define BB_    2
#define LT_    2048   // after stride-2 downsample
#define NHEAD_ 8
#define HD_    64     // head dim = 512/8
#define DFF_   1024
#define LC_    256    // scan chunk length
#define NC_    16     // number of chunks (LSEQ_/LC_)

__device__ __forceinline__ float siluf(float x) { return x / (1.f + expf(-x)); }

// ============================================================
// Generic fp32 GEMM: C[M,N] = act(A[M,K] @ W[K,N] + bias) + res
// tile 128x64, 256 threads, 8x4 microtile, K-tile 16.
// act: 0=none, 1=gelu(exact)
// ============================================================
__global__ __launch_bounds__(256) void ec_gemm(
    const float* __restrict__ A, const float* __restrict__ W,
    const float* __restrict__ bias, const float* __restrict__ res,
    float* __restrict__ C, int M, int N, int K, int act)
{
  __shared__ float As[16][128];
  __shared__ float Ws[16][64];
  const int tid = threadIdx.x;
  const int m0 = blockIdx.y * 128;
  const int n0 = blockIdx.x * 64;
  const int ty = tid >> 4, tx = tid & 15;
  const int lm = tid >> 1, lkq = (tid & 1) * 8;
  const int wk = tid >> 4, wn = (tid & 15) * 4;
  float acc[8][4];
#pragma unroll
  for (int i = 0; i < 8; ++i)
#pragma unroll
    for (int j = 0; j < 4; ++j) acc[i][j] = 0.f;

  for (int k0 = 0; k0 < K; k0 += 16) {
    const float* ap = A + (size_t)(m0 + lm) * K + k0 + lkq;
    const float4 a0 = *(const float4*)ap;
    const float4 a1 = *(const float4*)(ap + 4);
    float4 w4 = make_float4(0.f, 0.f, 0.f, 0.f);
    if (n0 + wn < N) w4 = *(const float4*)(W + (size_t)(k0 + wk) * N + n0 + wn);
    As[lkq + 0][lm] = a0.x; As[lkq + 1][lm] = a0.y; As[lkq + 2][lm] = a0.z; As[lkq + 3][lm] = a0.w;
    As[lkq + 4][lm] = a1.x; As[lkq + 5][lm] = a1.y; As[lkq + 6][lm] = a1.z; As[lkq + 7][lm] = a1.w;
    Ws[wk][wn + 0] = w4.x; Ws[wk][wn + 1] = w4.y; Ws[wk][wn + 2] = w4.z; Ws[wk][wn + 3] = w4.w;
    __syncthreads();
#pragma unroll
    for (int kk = 0; kk < 16; ++kk) {
      float bv[4], av[8];
#pragma unroll
      for (int j = 0; j < 4; ++j) bv[j] = Ws[kk][tx * 4 + j];
#pragma unroll
      for (int i = 0; i < 8; ++i) av[i] = As[kk][ty * 8 + i];
#pragma unroll
      for (int i = 0; i < 8; ++i)
#pragma unroll
        for (int j = 0; j < 4; ++j) acc[i][j] += av[i] * bv[j];
    }
    __syncthreads();
  }
#pragma unroll
  for (int i = 0; i < 8; ++i) {
    const int m = m0 + ty * 8 + i;
#pragma unroll
    for (int j = 0; j < 4; ++j) {
      const int n = n0 + tx * 4 + j;
      if (n < N) {
        float v = acc[i][j];
        if (bias) v += bias[n];
        if (act == 1) v = 0.5f * v * (1.f + erff(v * 0.70710678118f));
        if (res) v += res[(size_t)m * N + n];
        C[(size_t)m * N + n] = v;
      }
    }
  }
}

static inline void gemm(hipStream_t s, const float* A, const float* W, const float* bias,
                        const float* res, float* C, int M, int N, int K, int act) {
  dim3 g((N + 63) / 64, M / 128), b(256);
  ec_gemm<<<g, b, 0, s>>>(A, W, bias, res, C, M, N, K, act);
}

// ============================================================
// Depthwise causal conv (DCONV=4) + SiLU on the xBC slice of zxbcdt.
// ============================================================
__global__ void ec_conv1d_silu(const float* __restrict__ zx, const float* __restrict__ cw,
                               const float* __restrict__ cb, float* __restrict__ xBC)
{
  int idx = blockIdx.x * 256 + threadIdx.x;
  const int total = BB_ * LSEQ_ * CONVD_;
  if (idx >= total) return;
  int c = idx % CONVD_;
  int l = (idx / CONVD_) % LSEQ_;
  int b = idx / (CONVD_ * LSEQ_);
  const float* base = zx + (size_t)b * LSEQ_ * DPROJ_ + DIN_ + c;
  float s = cb[c];
#pragma unroll
  for (int j = 0; j < 4; ++j) {
    int ll = l - 3 + j;
    if (ll >= 0) s += base[(size_t)ll * DPROJ_] * cw[c * 4 + j];
  }
  xBC[idx] = siluf(s);
}

// ============================================================
// dt = softplus(dt_raw + dtb); decay = exp(-exp(Alog)*dt)
// ============================================================
__global__ void ec_dtdecay(const float* __restrict__ zx, const float* __restrict__ dtb,
                           const float* __restrict__ Alog, float* __restrict__ dts,
                           float* __restrict__ dec)
{
  int idx = blockIdx.x * 256 + threadIdx.x;   // B*L*NH total
  int h = idx & 31;
  float x = zx[(size_t)(idx >> 5) * DPROJ_ + (DIN_ + CONVD_) + h] + dtb[h];
  float sp = (x > 20.f) ? x : log1pf(expf(x));
  dts[idx] = sp;
  dec[idx] = expf(-expf(Alog[h]) * sp);
}

// ============================================================
// Chunked SSM scan.
// State layout trick: per-(b,c,h) 2048-float chunk state lives in the DEAD
// columns [DIN_, DIN_+1024) of zxbcdt rows 0..2047 (xBC/dt slices are dead
// after conv/dtdecay extract them; z columns [0,DIN_) stay untouched).
// ============================================================
__device__ __forceinline__ float* state_ptr(float* zxbase, int b, int c, int h, int e)
{
  int R = ((b * NC_ + c) * NH_ + h) * 2 + (e >> 10);
  return zxbase + (size_t)R * DPROJ_ + DIN_ + (e & 1023);
}

struct SValsB { float dsc, dcv, xv; float4 Bv; };

__device__ __forceinline__ void sloadB(SValsB& s, const float* __restrict__ xBC,
                                       const float* __restrict__ dts, const float* __restrict__ dec,
                                       size_t r, int h, int p, int n0)
{
  const float* xr = xBC + r * CONVD_;
  s.dsc = dts[r * NH_ + h];
  s.dcv = dec[r * NH_ + h];
  s.xv  = xr[h * HDIM_ + p];
  s.Bv  = *(const float4*)(xr + DIN_ + n0);
}

struct SVals { float dsc, dcv, xv; float4 Bv, Cv; };

__device__ __forceinline__ void sload(SVals& s, const float* __restrict__ xBC,
                                      const float* __restrict__ dts, const float* __restrict__ dec,
                                      size_t r, int h, int p, int n0)
{
  const float* xr = xBC + r * CONVD_;
  s.dsc = dts[r * NH_ + h];
  s.dcv = dec[r * NH_ + h];
  s.xv  = xr[h * HDIM_ + p];
  s.Bv  = *(const float4*)(xr + DIN_ + n0);
  s.Cv  = *(const float4*)(xr + DIN_ + DSTATE_ + n0);
}

// phase 1: per-chunk local state S_c (zero-init) + chunk decay product P_c
__global__ __launch_bounds__(512) void ec_scan_p1(
    const float* __restrict__ xBC, const float* __restrict__ dts,
    const float* __restrict__ dec, float* __restrict__ zxbase, float* __restrict__ Pc)
{
  const int h = blockIdx.x, c = blockIdx.y, b = blockIdx.z;
  const int tid = threadIdx.x;
  const int p = tid >> 4, ni = tid & 15, n0 = ni * 4;
  const size_t rowB = (size_t)b * LSEQ_ + (size_t)c * LC_;
  float s0 = 0.f, s1 = 0.f, s2 = 0.f, s3 = 0.f, pr = 1.f;
  SValsB v0, v1, v2;
  sloadB(v0, xBC, dts, dec, rowB + 0, h, p, n0);
  sloadB(v1, xBC, dts, dec, rowB + 1, h, p, n0);
  for (int t = 0; t < LC_; ++t) {
    int tp = (t + 2 < LC_) ? t + 2 : LC_ - 1;
    sloadB(v2, xBC, dts, dec, rowB + tp, h, p, n0);
    const float dx = v0.dsc * v0.xv;
    s0 = s0 * v0.dcv + dx * v0.Bv.x;
    s1 = s1 * v0.dcv + dx * v0.Bv.y;
    s2 = s2 * v0.dcv + dx * v0.Bv.z;
    s3 = s3 * v0.dcv + dx * v0.Bv.w;
    pr *= v0.dcv;
    v0 = v1; v1 = v2;
  }
  int e = p * 64 + n0;
  *(float4*)state_ptr(zxbase, b, c, h, e) = make_float4(s0, s1, s2, s3);
  if (tid == 0) Pc[(b * NC_ + c) * NH_ + h] = pr;
}

// phase 2: sequential prefix over chunks; state buffer becomes h_init[c]
__global__ __launch_bounds__(512) void ec_scan_p2(
    float* __restrict__ zxbase, const float* __restrict__ Pc)
{
  const int h = blockIdx.x, b = blockIdx.y;
  const int tid = threadIdx.x;
  const int e = (tid >> 4) * 64 + (tid & 15) * 4;
  float h0 = 0.f, h1 = 0.f, h2 = 0.f, h3 = 0.f;
  for (int c = 0; c < NC_; ++c) {
    float* ptr = state_ptr(zxbase, b, c, h, e);
    float4 S = *(float4*)ptr;
    *(float4*)ptr = make_float4(h0, h1, h2, h3);
    float P = Pc[(b * NC_ + c) * NH_ + h];
    h0 = h0 * P + S.x;
    h1 = h1 * P + S.y;
    h2 = h2 * P + S.z;
    h3 = h3 * P + S.w;
  }
}

// phase 3: replay chunk from h_init, emit y
__global__ __launch_bounds__(512) void ec_scan_p3(
    const float* __restrict__ xBC, const float* __restrict__ dts,
    const float* __restrict__ dec, const float* __restrict__ Dp,
    const float* __restrict__ zxbase, float* __restrict__ y)
{
  const int h = blockIdx.x, c = blockIdx.y, b = blockIdx.z;
  const int tid = threadIdx.x;
  const int p = tid >> 4, ni = tid & 15, n0 = ni * 4;
  const float Dh = Dp[h];
  const size_t rowB = (size_t)b * LSEQ_ + (size_t)c * LC_;
  const int e = p * 64 + n0;
  float4 hi = *(const float4*)state_ptr((float*)zxbase, b, c, h, e);
  float h0 = hi.x, h1 = hi.y, h2 = hi.z, h3 = hi.w;
  SVals v0, v1, v2;
  sload(v0, xBC, dts, dec, rowB + 0, h, p, n0);
  sload(v1, xBC, dts, dec, rowB + 1, h, p, n0);
  for (int t = 0; t < LC_; ++t) {
    int tp = (t + 2 < LC_) ? t + 2 : LC_ - 1;
    sload(v2, xBC, dts, dec, rowB + tp, h, p, n0);
    const float dx = v0.dsc * v0.xv;
    h0 = h0 * v0.dcv + dx * v0.Bv.x;
    h1 = h1 * v0.dcv + dx * v0.Bv.y;
    h2 = h2 * v0.dcv + dx * v0.Bv.z;
    h3 = h3 * v0.dcv + dx * v0.Bv.w;
    float acc = h0 * v0.Cv.x + h1 * v0.Cv.y + h2 * v0.Cv.z + h3 * v0.Cv.w;
    acc += __shfl_xor(acc, 1, 16);
    acc += __shfl_xor(acc, 2, 16);
    acc += __shfl_xor(acc, 4, 16);
    acc += __shfl_xor(acc, 8, 16);
    if (ni == 0) y[(rowB + t) * DIN_ + h * HDIM_ + p] = acc + Dh * v0.xv;
    v0 = v1; v1 = v2;
  }
}

// ============================================================
// t = y * silu(z); out = rmsnorm(t)*nw   (row width 1024)
// ============================================================
__global__ __launch_bounds__(256) void ec_gate_rms(
    const float* __restrict__ y, const float* __restrict__ zx,
    const float* __restrict__ nw, float* __restrict__ out)
{
  const int row = blockIdx.x;
  const float* yr = y + (size_t)row * DIN_;
  const float* zr = zx + (size_t)row * DPROJ_;
  float v[4]; float ss = 0.f;
#pragma unroll
  for (int j = 0; j < 4; ++j) {
    int c = j * 256 + threadIdx.x;
    float t = yr[c] * siluf(zr[c]);
    v[j] = t; ss += t * t;
  }
#pragma unroll
  for (int m = 32; m >= 1; m >>= 1) ss += __shfl_xor(ss, m, 64);
  __shared__ float buf[4];
  if ((threadIdx.x & 63) == 0) buf[threadIdx.x >> 6] = ss;
  __syncthreads();
  ss = buf[0] + buf[1] + buf[2] + buf[3];
  float scale = rsqrtf(ss / (float)DIN_ + 1e-5f);
#pragma unroll
  for (int j = 0; j < 4; ++j) {
    int c = j * 256 + threadIdx.x;
    out[(size_t)row * DIN_ + c] = v[j] * scale * nw[c];
  }
}

// ============================================================
// out = rmsnorm(a + b)*w    (row width 512)
// ============================================================
__global__ __launch_bounds__(128) void ec_rmsadd(
    const float* __restrict__ a, const float* __restrict__ bres,
    const float* __restrict__ w, float* __restrict__ out)
{
  const int row = blockIdx.x;
  const float* ar = a + (size_t)row * HID_;
  const float* br = bres + (size_t)row * HID_;
  float v[4]; float ss = 0.f;
#pragma unroll
  for (int j = 0; j < 4; ++j) {
    int c = j * 128 + threadIdx.x;
    float t = ar[c] + br[c];
    v[j] = t; ss += t * t;
  }
#pragma unroll
  for (int m = 32; m >= 1; m >>= 1) ss += __shfl_xor(ss, m, 64);
  __shared__ float buf[2];
  if ((threadIdx.x & 63) == 0) buf[threadIdx.x >> 6] = ss;
  __syncthreads();
  ss = buf[0] + buf[1];
  float scale = rsqrtf(ss / (float)HID_ + 1e-5f);
#pragma unroll
  for (int j = 0; j < 4; ++j) {
    int c = j * 128 + threadIdx.x;
    out[(size_t)row * HID_ + c] = v[j] * scale * w[c];
  }
}

// ============================================================
// layernorm(in)*w + b   (row width 512)
// ============================================================
__global__ __launch_bounds__(128) void ec_ln(
    const float* __restrict__ in, const float* __restrict__ w,
    const float* __restrict__ bb, float* __restrict__ out)
{
  const int row = blockIdx.x;
  const float* ir = in + (size_t)row * HID_;
  float v[4]; float s = 0.f, s2 = 0.f;
#pragma unroll
  for (int j = 0; j < 4; ++j) {
    int c = j * 128 + threadIdx.x;
    float t = ir[c];
    v[j] = t; s += t; s2 += t * t;
  }
#pragma unroll
  for (int m = 32; m >= 1; m >>= 1) { s += __shfl_xor(s, m, 64); s2 += __shfl_xor(s2, m, 64); }
  __shared__ float buf[4];
  if ((threadIdx.x & 63) == 0) { int wi = threadIdx.x >> 6; buf[wi * 2] = s; buf[wi * 2 + 1] = s2; }
  __syncthreads();
  s = buf[0] + buf[2]; s2 = buf[1] + buf[3];
  float mean = s / (float)HID_;
  float var = s2 / (float)HID_ - mean * mean;
  float inv = rsqrtf(var + 1e-5f);
#pragma unroll
  for (int j = 0; j < 4; ++j) {
    int c = j * 128 + threadIdx.x;
    out[(size_t)row * HID_ + c] = (v[j] - mean) * inv * w[c] + bb[c];
  }
}

// ============================================================
// transpose ds_w (O,I,K) -> (K,I,O)
// ============================================================
__global__ void ec_transpose_dsw(const float* __restrict__ w, float* __restrict__ wt)
{
  int idx = blockIdx.x * 256 + threadIdx.x;
  if (idx < HID_ * HID_ * 3) {
    int k = idx % 3;
    int i = (idx / 3) % HID_;
    int o = idx / (3 * HID_);
    wt[((size_t)k * HID_ + i) * HID_ + o] = w[idx];
  }
}

// ============================================================
// strided downsample conv: out[b,lo,o] = sum_{k,i} x[b,2lo+k-1,i]*w[o,i,k] + b[o]
// ============================================================
__global__ __launch_bounds__(512) void ec_dsconv(
    const float* __restrict__ x, const float* __restrict__ wt,
    const float* __restrict__ bias, float* __restrict__ out)
{
  const int b = blockIdx.y;
  const int lo0 = blockIdx.x * 16;
  const int o = threadIdx.x;
  __shared__ float xs[33][64];
  float acc[16];
#pragma unroll
  for (int q = 0; q < 16; ++q) acc[q] = 0.f;
  for (int ic = 0; ic < 8; ++ic) {
    for (int idx = threadIdx.x; idx < 33 * 64; idx += 512) {
      int r = idx >> 6, ii = idx & 63;
      int l = 2 * lo0 - 1 + r;
      xs[r][ii] = (l >= 0) ? x[((size_t)b * LSEQ_ + l) * HID_ + ic * 64 + ii] : 0.f;
    }
    __syncthreads();
    for (int ii = 0; ii < 64; ++ii) {
      int i = ic * 64 + ii;
      float w0 = wt[((size_t)0 * HID_ + i) * HID_ + o];
      float w1 = wt[((size_t)1 * HID_ + i) * HID_ + o];
      float w2 = wt[((size_t)2 * HID_ + i) * HID_ + o];
#pragma unroll
      for (int q = 0; q < 16; ++q)
        acc[q] += xs[2 * q + 0][ii] * w0 + xs[2 * q + 1][ii] * w1 + xs[2 * q + 2][ii] * w2;
    }
    __syncthreads();
  }
#pragma unroll
  for (int q = 0; q < 16; ++q)
    out[((size_t)b * LT_ + lo0 + q) * HID_ + o] = acc[q] + bias[o];
}

// ============================================================
// flash-style attention: qkv [B*LT,1536] -> out [B*LT,512]
// ============================================================
__global__ __launch_bounds__(256) void ec_attn(
    const float* __restrict__ qkv, float* __restrict__ out)
{
  const int b = blockIdx.z, h = blockIdx.y, qt = blockIdx.x;
  __shared__ float Qs[32][65], Ks[64][65], Vs[64][65], Ps[32][65];
  const int tid = threadIdx.x;
  const int tq = tid >> 4, tk = tid & 15;
  {
    int r = tid >> 3;
    int c0 = (tid & 7) * 8;
    const float* qp = qkv + ((size_t)b * LT_ + qt * 32 + r) * 1536 + h * HD_ + c0;
    float4 q0 = *(const float4*)qp;
    float4 q1 = *(const float4*)(qp + 4);
    Qs[r][c0 + 0] = q0.x; Qs[r][c0 + 1] = q0.y; Qs[r][c0 + 2] = q0.z; Qs[r][c0 + 3] = q0.w;
    Qs[r][c0 + 4] = q1.x; Qs[r][c0 + 5] = q1.y; Qs[r][c0 + 6] = q1.z; Qs[r][c0 + 7] = q1.w;
  }
  float mA = -1e30f, mB = -1e30f, lA = 0.f, lB = 0.f;
  float oA[4] = {0.f, 0.f, 0.f, 0.f}, oB[4] = {0.f, 0.f, 0.f, 0.f};
  __syncthreads();
  for (int kt = 0; kt < LT_ / 64; ++kt) {
#pragma unroll
    for (int rr = 0; rr < 4; ++rr) {
      int r = (tid >> 4) + rr * 16;
      int c0 = (tid & 15) * 4;
      const float* kp = qkv + ((size_t)b * LT_ + kt * 64 + r) * 1536 + HID_ + h * HD_ + c0;
      float4 kv = *(const float4*)kp;
      float4 vv = *(const float4*)(kp + HID_);
      Ks[r][c0 + 0] = kv.x; Ks[r][c0 + 1] = kv.y; Ks[r][c0 + 2] = kv.z; Ks[r][c0 + 3] = kv.w;
      Vs[r][c0 + 0] = vv.x; Vs[r][c0 + 1] = vv.y; Vs[r][c0 + 2] = vv.z; Vs[r][c0 + 3] = vv.w;
    }
    __syncthreads();
    float sA[4] = {0.f, 0.f, 0.f, 0.f}, sB[4] = {0.f, 0.f, 0.f, 0.f};
    for (int d = 0; d < HD_; ++d) {
      float qa = Qs[tq * 2][d], qb = Qs[tq * 2 + 1][d];
#pragma unroll
      for (int j = 0; j < 4; ++j) {
        float kvv = Ks[tk * 4 + j][d];
        sA[j] += qa * kvv; sB[j] += qb * kvv;
      }
    }
#pragma unroll
    for (int j = 0; j < 4; ++j) { sA[j] *= 0.125f; sB[j] *= 0.125f; }
    float mtA = fmaxf(fmaxf(sA[0], sA[1]), fmaxf(sA[2], sA[3]));
    float mtB = fmaxf(fmaxf(sB[0], sB[1]), fmaxf(sB[2], sB[3]));
#pragma unroll
    for (int m = 1; m <= 8; m <<= 1) {
      mtA = fmaxf(mtA, __shfl_xor(mtA, m, 16));
      mtB = fmaxf(mtB, __shfl_xor(mtB, m, 16));
    }
    float mnA = fmaxf(mA, mtA), mnB = fmaxf(mB, mtB);
    float rA = expf(mA - mnA), rB = expf(mB - mnB);
    float pA[4], pB[4]; float suA = 0.f, suB = 0.f;
#pragma unroll
    for (int j = 0; j < 4; ++j) {
      pA[j] = expf(sA[j] - mnA); suA += pA[j];
      pB[j] = expf(sB[j] - mnB); suB += pB[j];
      Ps[tq * 2][tk * 4 + j] = pA[j];
      Ps[tq * 2 + 1][tk * 4 + j] = pB[j];
    }
#pragma unroll
    for (int m = 1; m <= 8; m <<= 1) {
      suA += __shfl_xor(suA, m, 16);
      suB += __shfl_xor(suB, m, 16);
    }
    lA = lA * rA + suA; lB = lB * rB + suB;
    mA = mnA; mB = mnB;
    __syncthreads();
#pragma unroll
    for (int j = 0; j < 4; ++j) { oA[j] *= rA; oB[j] *= rB; }
    for (int kk = 0; kk < 64; ++kk) {
      float pa = Ps[tq * 2][kk], pb = Ps[tq * 2 + 1][kk];
#pragma unroll
      for (int j = 0; j < 4; ++j) {
        float vv = Vs[kk][tk * 4 + j];
        oA[j] += pa * vv; oB[j] += pb * vv;
      }
    }
    __syncthreads();
  }
  float invA = 1.f / lA, invB = 1.f / lB;
  size_t rowA = (size_t)b * LT_ + qt * 32 + tq * 2;
#pragma unroll
  for (int j = 0; j < 4; ++j) {
    int c = h * HD_ + tk * 4 + j;
    out[rowA * HID_ + c] = oA[j] * invA;
    out[(rowA + 1) * HID_ + c] = oB[j] * invB;
  }
}

// ============================================================
// host launch
// ============================================================
extern "C" void kernel_launch(void* const* d_in, const int* in_sizes, int n_in,
                              void* d_out, int out_size, void* d_ws, size_t ws_size,
                              hipStream_t stream)
{
  const float* x_in   = (const float*)d_in[0];
  const float* Wp     = (const float*)d_in[1];
  const float* bp     = (const float*)d_in[2];
  const float* m_Wi[2]   = {(const float*)d_in[3],  (const float*)d_in[11]};
  const float* m_cw[2]   = {(const float*)d_in[4],  (const float*)d_in[12]};
  const float* m_cb[2]   = {(const float*)d_in[5],  (const float*)d_in[13]};
  const float* m_dtb[2]  = {(const float*)d_in[6],  (const float*)d_in[14]};
  const float* m_Alog[2] = {(const float*)d_in[7],  (const float*)d_in[15]};
  const float* m_D[2]    = {(const float*)d_in[8],  (const float*)d_in[16]};
  const float* m_nw[2]   = {(const float*)d_in[9],  (const float*)d_in[17]};
  const float* m_Wo[2]   = {(const float*)d_in[10], (const float*)d_in[18]};
  const float* n_w[2]    = {(const float*)d_in[19], (const float*)d_in[20]};
  const float* ds_w   = (const float*)d_in[21];
  const float* ds_b   = (const float*)d_in[22];
  const float* t_Wqkv = (const float*)d_in[23];
  const float* t_bqkv = (const float*)d_in[24];
  const float* t_Wo   = (const float*)d_in[25];
  const float* t_bo   = (const float*)d_in[26];
  const float* t_W1   = (const float*)d_in[27];
  const float* t_b1   = (const float*)d_in[28];
  const float* t_W2   = (const float*)d_in[29];
  const float* t_b2   = (const float*)d_in[30];
  const float* t_ln1w = (const float*)d_in[31];
  const float* t_ln1b = (const float*)d_in[32];
  const float* t_ln2w = (const float*)d_in[33];
  const float* t_ln2b = (const float*)d_in[34];
  const float* on_w   = (const float*)d_in[35];
  const float* on_b   = (const float*)d_in[36];

  char* ws = (char*)d_ws;
  float* bx   = (float*)(ws + 0);           // [8192,512]  residual stream
  float* bzx  = (float*)(ws + 16777216);    // [8192,2208] zxbcdt (+ dead-column scan state)
  float* bxbc = (float*)(ws + 89128960);    // [8192,1152] xBC / reuse
  float* by   = (float*)(ws + 126877696);   // [8192,1024] scan y / reuse
  float* bdt  = (float*)(ws + 160432128);   // [8192,32]
  float* bdec = (float*)(ws + 161480704);   // [8192,32]
  float* bwt  = (float*)(ws + 162529280);   // [3,512,512] (also scratch for Pc during scans)

  const int MR = BB_ * LSEQ_;  // 8192
  const int MT = BB_ * LT_;    // 4096

  gemm(stream, x_in, Wp, bp, nullptr, bx, MR, HID_, 1024, 0);

  float* Pc = bwt;   // [B*NC_*NH_] chunk decay products (bwt written only later)

  for (int blk = 0; blk < 2; ++blk) {
    gemm(stream, bx, m_Wi[blk], nullptr, nullptr, bzx, MR, DPROJ_, HID_, 0);
    ec_conv1d_silu<<<(MR * CONVD_ + 255) / 256, 256, 0, stream>>>(bzx, m_cw[blk], m_cb[blk], bxbc);
    ec_dtdecay<<<(MR * NH_) / 256, 256, 0, stream>>>(bzx, m_dtb[blk], m_Alog[blk], bdt, bdec);
    ec_scan_p1<<<dim3(NH_, NC_, BB_), 512, 0, stream>>>(bxbc, bdt, bdec, bzx, Pc);
    ec_scan_p2<<<dim3(NH_, BB_), 512, 0, stream>>>(bzx, Pc);
    ec_scan_p3<<<dim3(NH_, NC_, BB_), 512, 0, stream>>>(bxbc, bdt, bdec, m_D[blk], bzx, by);
    ec_gate_rms<<<MR, 256, 0, stream>>>(by, bzx, m_nw[blk], bxbc);
    gemm(stream, bxbc, m_Wo[blk], nullptr, nullptr, by, MR, HID_, DIN_, 0);
    ec_rmsadd<<<MR, 128, 0, stream>>>(by, bx, n_w[blk], bx);
  }

  ec_transpose_dsw<<<(HID_ * HID_ * 3 + 255) / 256, 256, 0, stream>>>(ds_w, bwt);
  float* bxds = bzx;                                // [4096,512]
  float* bqkv = (float*)((char*)bzx + 8388608);     // [4096,1536]
  ec_dsconv<<<dim3(LT_ / 16, BB_), 512, 0, stream>>>(bx, bwt, ds_b, bxds);

  gemm(stream, bxds, t_Wqkv, t_bqkv, nullptr, bqkv, MT, 3 * HID_, HID_, 0);
  float* batto = bxbc;                              // [4096,512]
  float* bt1   = (float*)((char*)bxbc + 8388608);   // [4096,512]
  ec_attn<<<dim3(LT_ / 32, NHEAD_, BB_), 256, 0, stream>>>(bqkv, batto);
  gemm(stream, batto, t_Wo, t_bo, bxds, bt1, MT, HID_, HID_, 0);
  float* bxt2 = by;                                 // [4096,512]
  ec_ln<<<MT, 128, 0, stream>>>(bt1, t_ln1w, t_ln1b, bxt2);
  float* bff = bzx;                                 // [4096,1024]
  gemm(stream, bxt2, t_W1, t_b1, nullptr, bff, MT, DFF_, HID_, 1);
  float* bt2 = bxbc;                                // [4096,512]
  gemm(stream, bff, t_W2, t_b2, bxt2, bt2, MT, HID_, DFF_, 0);
  float* bxt3 = (float*)((char*)bxbc + 8388608);
  ec_ln<<<MT, 128, 0, stream>>>(bt2, t_ln2w, t_ln2b, bxt3);
  ec_ln<<<MT, 128, 0, stream>>>(bxt3, on_w, on_b, (float*)d_out);
}

// Round 3
// 1383.566 us; speedup vs baseline: 4.6109x; 2.0528x over previous
//
#include <hip/hip_runtime.h>
#include <math.h>

// ---- model dims ----
#define DIN_   1024
#define DSTATE_ 64
#define NH_    32
#define HDIM_  32
#define CONVD_ 1152   // DIN + 2*DSTATE
#define DPROJ_ 2208   // 2*DIN + 2*DSTATE + NH
#define HID_   512
#define LSEQ_  4096
#define BB_    2
#define LT_    2048   // after stride-2 downsample
#define NHEAD_ 8
#define HD_    64     // head dim = 512/8
#define DFF_   1024
#define LC_    256    // scan chunk length
#define NC_    16     // number of chunks (LSEQ_/LC_)

typedef __attribute__((ext_vector_type(8))) short bf16x8;
typedef __attribute__((ext_vector_type(4))) short s16x4;
typedef __attribute__((ext_vector_type(4))) float f32x4;

__device__ __forceinline__ float siluf(float x) { return x / (1.f + expf(-x)); }

__device__ __forceinline__ short f2b(float f) {
  union { float f; unsigned u; } v; v.f = f;
  unsigned r = (v.u + 0x7fffu + ((v.u >> 16) & 1u)) >> 16;
  return (short)r;
}

// async global->LDS 16B per lane; lds base must be wave-uniform
__device__ __forceinline__ void gload16(const short* g, short* lds_base) {
#if __has_builtin(__builtin_amdgcn_global_load_lds)
  __builtin_amdgcn_global_load_lds((const __attribute__((address_space(1))) void*)g,
                                   (__attribute__((address_space(3))) void*)lds_base, 16, 0, 0);
#else
  int l = threadIdx.x & 63;
  ((bf16x8*)lds_base)[l] = *(const bf16x8*)g;
#endif
}

// ============================================================
// fp32 -> bf16 elementwise (8 per thread)
// ============================================================
__global__ void ec_f2b(const float* __restrict__ in, short* __restrict__ out, int n8)
{
  int i = blockIdx.x * 256 + threadIdx.x;
  if (i >= n8) return;
  const float4* p = (const float4*)(in + (size_t)i * 8);
  float4 a = p[0], b = p[1];
  bf16x8 o;
  o[0] = f2b(a.x); o[1] = f2b(a.y); o[2] = f2b(a.z); o[3] = f2b(a.w);
  o[4] = f2b(b.x); o[5] = f2b(b.y); o[6] = f2b(b.z); o[7] = f2b(b.w);
  *(bf16x8*)(out + (size_t)i * 8) = o;
}

// ============================================================
// weight convert+transpose: W fp32 [K,N] -> Wt bf16 [N,K]
// K,N multiples of 32
// ============================================================
__global__ __launch_bounds__(256) void ec_w2bt(const float* __restrict__ W,
                                               short* __restrict__ Wt, int K, int N)
{
  __shared__ float t[32][33];
  int k0 = blockIdx.x * 32, n0 = blockIdx.y * 32;
  int tx = threadIdx.x & 31, ty = threadIdx.x >> 5;
#pragma unroll
  for (int i = 0; i < 32; i += 8) t[ty + i][tx] = W[(size_t)(k0 + ty + i) * N + n0 + tx];
  __syncthreads();
#pragma unroll
  for (int i = 0; i < 32; i += 8) Wt[(size_t)(n0 + ty + i) * K + k0 + tx] = f2b(t[tx][ty + i]);
}

// ============================================================
// bf16 MFMA GEMM: C = act(A[M,K] @ W + bias) + res, W given as Wt bf16 [N,K]
// 128x128 tile, 4 waves, 4x4 16x16x32 frags, BK=32, double-buffered LDS.
// M%128==0, K%32==0; N tiles guarded (row clamp + col mask).
// act: 0=none, 1=gelu(exact). Cf (fp32) and/or Ch (bf16) outputs.
// ============================================================
__global__ __launch_bounds__(256) void ec_gemm16(
    const short* __restrict__ A, const short* __restrict__ Wt,
    const float* __restrict__ bias, const float* __restrict__ res,
    float* __restrict__ Cf, short* __restrict__ Ch,
    int M, int N, int K, int act)
{
  __shared__ short As_[2][4096];   // [buf][128 rows x 32 k]
  __shared__ short Bs_[2][4096];
  const int tid = threadIdx.x;
  const int l = tid & 63, w = tid >> 6;
  const int m0 = blockIdx.y * 128, n0 = blockIdx.x * 128;
  const int wm = (w >> 1) * 64, wn = (w & 1) * 64;
  const int lr = l & 15, lk = l >> 4;
  const int arow = l >> 2, acol = (l & 3) * 8;

  f32x4 acc[4][4];
#pragma unroll
  for (int i = 0; i < 4; ++i)
#pragma unroll
    for (int j = 0; j < 4; ++j) acc[i][j] = f32x4{0.f, 0.f, 0.f, 0.f};

  // prologue: stage k-tile 0 into buf 0
#pragma unroll
  for (int cc = 0; cc < 2; ++cc) {
    int c = w * 2 + cc;
    const short* ga = A + (size_t)(m0 + c * 16 + arow) * K + acol;
    int rb = n0 + c * 16 + arow; if (rb > N - 1) rb = N - 1;
    const short* gb = Wt + (size_t)rb * K + acol;
    gload16(ga, &As_[0][c * 512]);
    gload16(gb, &Bs_[0][c * 512]);
  }

  const int KT = K >> 5;
  for (int kt = 0; kt < KT; ++kt) {
    __syncthreads();   // staging for buf (kt&1) complete; prev reads done
    if (kt + 1 < KT) {
      int k0 = (kt + 1) << 5;
      int nb = (kt + 1) & 1;
#pragma unroll
      for (int cc = 0; cc < 2; ++cc) {
        int c = w * 2 + cc;
        const short* ga = A + (size_t)(m0 + c * 16 + arow) * K + k0 + acol;
        int rb = n0 + c * 16 + arow; if (rb > N - 1) rb = N - 1;
        const short* gb = Wt + (size_t)rb * K + k0 + acol;
        gload16(ga, &As_[nb][c * 512]);
        gload16(gb, &Bs_[nb][c * 512]);
      }
    }
    int cb = kt & 1;
    bf16x8 af[4], bfv[4];
#pragma unroll
    for (int mf = 0; mf < 4; ++mf)
      af[mf] = *(const bf16x8*)&As_[cb][(wm + mf * 16 + lr) * 32 + lk * 8];
#pragma unroll
    for (int nf = 0; nf < 4; ++nf)
      bfv[nf] = *(const bf16x8*)&Bs_[cb][(wn + nf * 16 + lr) * 32 + lk * 8];
#pragma unroll
    for (int mf = 0; mf < 4; ++mf)
#pragma unroll
      for (int nf = 0; nf < 4; ++nf)
        acc[mf][nf] = __builtin_amdgcn_mfma_f32_16x16x32_bf16(af[mf], bfv[nf], acc[mf][nf], 0, 0, 0);
  }

  // epilogue: C row = (l>>4)*4+r, col = l&15 within each 16x16 frag
#pragma unroll
  for (int mf = 0; mf < 4; ++mf)
#pragma unroll
    for (int nf = 0; nf < 4; ++nf)
#pragma unroll
      for (int r = 0; r < 4; ++r) {
        int m = m0 + wm + mf * 16 + lk * 4 + r;
        int n = n0 + wn + nf * 16 + lr;
        if (n < N) {
          float v = acc[mf][nf][r];
          if (bias) v += bias[n];
          if (act == 1) v = 0.5f * v * (1.f + erff(v * 0.70710678118f));
          if (res) v += res[(size_t)m * N + n];
          if (Cf) Cf[(size_t)m * N + n] = v;
          if (Ch) Ch[(size_t)m * N + n] = f2b(v);
        }
      }
}

static inline void gemm16(hipStream_t s, const short* A, const short* Wt, const float* bias,
                          const float* res, float* Cf, short* Ch, int M, int N, int K, int act) {
  dim3 g((N + 127) / 128, M / 128), b(256);
  ec_gemm16<<<g, b, 0, s>>>(A, Wt, bias, res, Cf, Ch, M, N, K, act);
}

// ============================================================
// Depthwise causal conv (DCONV=4) + SiLU on the xBC slice of zxbcdt.
// ============================================================
__global__ void ec_conv1d_silu(const float* __restrict__ zx, const float* __restrict__ cw,
                               const float* __restrict__ cb, float* __restrict__ xBC)
{
  int idx = blockIdx.x * 256 + threadIdx.x;
  const int total = BB_ * LSEQ_ * CONVD_;
  if (idx >= total) return;
  int c = idx % CONVD_;
  int l = (idx / CONVD_) % LSEQ_;
  int b = idx / (CONVD_ * LSEQ_);
  const float* base = zx + (size_t)b * LSEQ_ * DPROJ_ + DIN_ + c;
  float s = cb[c];
#pragma unroll
  for (int j = 0; j < 4; ++j) {
    int ll = l - 3 + j;
    if (ll >= 0) s += base[(size_t)ll * DPROJ_] * cw[c * 4 + j];
  }
  xBC[idx] = siluf(s);
}

// ============================================================
// dt = softplus(dt_raw + dtb); decay = exp(-exp(Alog)*dt)
// ============================================================
__global__ void ec_dtdecay(const float* __restrict__ zx, const float* __restrict__ dtb,
                           const float* __restrict__ Alog, float* __restrict__ dts,
                           float* __restrict__ dec)
{
  int idx = blockIdx.x * 256 + threadIdx.x;
  int h = idx & 31;
  float x = zx[(size_t)(idx >> 5) * DPROJ_ + (DIN_ + CONVD_) + h] + dtb[h];
  float sp = (x > 20.f) ? x : log1pf(expf(x));
  dts[idx] = sp;
  dec[idx] = expf(-expf(Alog[h]) * sp);
}

// ============================================================
// Chunked SSM scan (states live in dead cols of zxbcdt rows 0..2047)
// ============================================================
__device__ __forceinline__ float* state_ptr(float* zxbase, int b, int c, int h, int e)
{
  int R = ((b * NC_ + c) * NH_ + h) * 2 + (e >> 10);
  return zxbase + (size_t)R * DPROJ_ + DIN_ + (e & 1023);
}

struct SValsB { float dsc, dcv, xv; float4 Bv; };

__device__ __forceinline__ void sloadB(SValsB& s, const float* __restrict__ xBC,
                                       const float* __restrict__ dts, const float* __restrict__ dec,
                                       size_t r, int h, int p, int n0)
{
  const float* xr = xBC + r * CONVD_;
  s.dsc = dts[r * NH_ + h];
  s.dcv = dec[r * NH_ + h];
  s.xv  = xr[h * HDIM_ + p];
  s.Bv  = *(const float4*)(xr + DIN_ + n0);
}

struct SVals { float dsc, dcv, xv; float4 Bv, Cv; };

__device__ __forceinline__ void sload(SVals& s, const float* __restrict__ xBC,
                                      const float* __restrict__ dts, const float* __restrict__ dec,
                                      size_t r, int h, int p, int n0)
{
  const float* xr = xBC + r * CONVD_;
  s.dsc = dts[r * NH_ + h];
  s.dcv = dec[r * NH_ + h];
  s.xv  = xr[h * HDIM_ + p];
  s.Bv  = *(const float4*)(xr + DIN_ + n0);
  s.Cv  = *(const float4*)(xr + DIN_ + DSTATE_ + n0);
}

__global__ __launch_bounds__(512) void ec_scan_p1(
    const float* __restrict__ xBC, const float* __restrict__ dts,
    const float* __restrict__ dec, float* __restrict__ zxbase, float* __restrict__ Pc)
{
  const int h = blockIdx.x, c = blockIdx.y, b = blockIdx.z;
  const int tid = threadIdx.x;
  const int p = tid >> 4, ni = tid & 15, n0 = ni * 4;
  const size_t rowB = (size_t)b * LSEQ_ + (size_t)c * LC_;
  float s0 = 0.f, s1 = 0.f, s2 = 0.f, s3 = 0.f, pr = 1.f;
  SValsB v0, v1, v2;
  sloadB(v0, xBC, dts, dec, rowB + 0, h, p, n0);
  sloadB(v1, xBC, dts, dec, rowB + 1, h, p, n0);
  for (int t = 0; t < LC_; ++t) {
    int tp = (t + 2 < LC_) ? t + 2 : LC_ - 1;
    sloadB(v2, xBC, dts, dec, rowB + tp, h, p, n0);
    const float dx = v0.dsc * v0.xv;
    s0 = s0 * v0.dcv + dx * v0.Bv.x;
    s1 = s1 * v0.dcv + dx * v0.Bv.y;
    s2 = s2 * v0.dcv + dx * v0.Bv.z;
    s3 = s3 * v0.dcv + dx * v0.Bv.w;
    pr *= v0.dcv;
    v0 = v1; v1 = v2;
  }
  int e = p * 64 + n0;
  *(float4*)state_ptr(zxbase, b, c, h, e) = make_float4(s0, s1, s2, s3);
  if (tid == 0) Pc[(b * NC_ + c) * NH_ + h] = pr;
}

__global__ __launch_bounds__(512) void ec_scan_p2(
    float* __restrict__ zxbase, const float* __restrict__ Pc)
{
  const int h = blockIdx.x, b = blockIdx.y;
  const int tid = threadIdx.x;
  const int e = (tid >> 4) * 64 + (tid & 15) * 4;
  float h0 = 0.f, h1 = 0.f, h2 = 0.f, h3 = 0.f;
  for (int c = 0; c < NC_; ++c) {
    float* ptr = state_ptr(zxbase, b, c, h, e);
    float4 S = *(float4*)ptr;
    *(float4*)ptr = make_float4(h0, h1, h2, h3);
    float P = Pc[(b * NC_ + c) * NH_ + h];
    h0 = h0 * P + S.x;
    h1 = h1 * P + S.y;
    h2 = h2 * P + S.z;
    h3 = h3 * P + S.w;
  }
}

__global__ __launch_bounds__(512) void ec_scan_p3(
    const float* __restrict__ xBC, const float* __restrict__ dts,
    const float* __restrict__ dec, const float* __restrict__ Dp,
    const float* __restrict__ zxbase, float* __restrict__ y)
{
  const int h = blockIdx.x, c = blockIdx.y, b = blockIdx.z;
  const int tid = threadIdx.x;
  const int p = tid >> 4, ni = tid & 15, n0 = ni * 4;
  const float Dh = Dp[h];
  const size_t rowB = (size_t)b * LSEQ_ + (size_t)c * LC_;
  const int e = p * 64 + n0;
  float4 hi = *(const float4*)state_ptr((float*)zxbase, b, c, h, e);
  float h0 = hi.x, h1 = hi.y, h2 = hi.z, h3 = hi.w;
  SVals v0, v1, v2;
  sload(v0, xBC, dts, dec, rowB + 0, h, p, n0);
  sload(v1, xBC, dts, dec, rowB + 1, h, p, n0);
  for (int t = 0; t < LC_; ++t) {
    int tp = (t + 2 < LC_) ? t + 2 : LC_ - 1;
    sload(v2, xBC, dts, dec, rowB + tp, h, p, n0);
    const float dx = v0.dsc * v0.xv;
    h0 = h0 * v0.dcv + dx * v0.Bv.x;
    h1 = h1 * v0.dcv + dx * v0.Bv.y;
    h2 = h2 * v0.dcv + dx * v0.Bv.z;
    h3 = h3 * v0.dcv + dx * v0.Bv.w;
    float acc = h0 * v0.Cv.x + h1 * v0.Cv.y + h2 * v0.Cv.z + h3 * v0.Cv.w;
    acc += __shfl_xor(acc, 1, 16);
    acc += __shfl_xor(acc, 2, 16);
    acc += __shfl_xor(acc, 4, 16);
    acc += __shfl_xor(acc, 8, 16);
    if (ni == 0) y[(rowB + t) * DIN_ + h * HDIM_ + p] = acc + Dh * v0.xv;
    v0 = v1; v1 = v2;
  }
}

// ============================================================
// t = y * silu(z); out = rmsnorm(t)*nw  -> bf16  (row width 1024)
// ============================================================
__global__ __launch_bounds__(256) void ec_gate_rms16(
    const float* __restrict__ y, const float* __restrict__ zx,
    const float* __restrict__ nw, short* __restrict__ out)
{
  const int row = blockIdx.x;
  const float* yr = y + (size_t)row * DIN_;
  const float* zr = zx + (size_t)row * DPROJ_;
  float v[4]; float ss = 0.f;
#pragma unroll
  for (int j = 0; j < 4; ++j) {
    int c = j * 256 + threadIdx.x;
    float t = yr[c] * siluf(zr[c]);
    v[j] = t; ss += t * t;
  }
#pragma unroll
  for (int m = 32; m >= 1; m >>= 1) ss += __shfl_xor(ss, m, 64);
  __shared__ float buf[4];
  if ((threadIdx.x & 63) == 0) buf[threadIdx.x >> 6] = ss;
  __syncthreads();
  ss = buf[0] + buf[1] + buf[2] + buf[3];
  float scale = rsqrtf(ss / (float)DIN_ + 1e-5f);
#pragma unroll
  for (int j = 0; j < 4; ++j) {
    int c = j * 256 + threadIdx.x;
    out[(size_t)row * DIN_ + c] = f2b(v[j] * scale * nw[c]);
  }
}

// ============================================================
// out = rmsnorm(a + b)*w  -> fp32 + bf16  (row width 512)
// ============================================================
__global__ __launch_bounds__(128) void ec_rmsadd16(
    const float* __restrict__ a, const float* __restrict__ bres,
    const float* __restrict__ w, float* __restrict__ out, short* __restrict__ out16)
{
  const int row = blockIdx.x;
  const float* ar = a + (size_t)row * HID_;
  const float* br = bres + (size_t)row * HID_;
  float v[4]; float ss = 0.f;
#pragma unroll
  for (int j = 0; j < 4; ++j) {
    int c = j * 128 + threadIdx.x;
    float t = ar[c] + br[c];
    v[j] = t; ss += t * t;
  }
#pragma unroll
  for (int m = 32; m >= 1; m >>= 1) ss += __shfl_xor(ss, m, 64);
  __shared__ float buf[2];
  if ((threadIdx.x & 63) == 0) buf[threadIdx.x >> 6] = ss;
  __syncthreads();
  ss = buf[0] + buf[1];
  float scale = rsqrtf(ss / (float)HID_ + 1e-5f);
#pragma unroll
  for (int j = 0; j < 4; ++j) {
    int c = j * 128 + threadIdx.x;
    float o = v[j] * scale * w[c];
    out[(size_t)row * HID_ + c] = o;
    out16[(size_t)row * HID_ + c] = f2b(o);
  }
}

// ============================================================
// layernorm(in)*w + b -> fp32 (+ optional bf16)  (row width 512)
// ============================================================
__global__ __launch_bounds__(128) void ec_ln16(
    const float* __restrict__ in, const float* __restrict__ w,
    const float* __restrict__ bb, float* __restrict__ out, short* __restrict__ out16)
{
  const int row = blockIdx.x;
  const float* ir = in + (size_t)row * HID_;
  float v[4]; float s = 0.f, s2 = 0.f;
#pragma unroll
  for (int j = 0; j < 4; ++j) {
    int c = j * 128 + threadIdx.x;
    float t = ir[c];
    v[j] = t; s += t; s2 += t * t;
  }
#pragma unroll
  for (int m = 32; m >= 1; m >>= 1) { s += __shfl_xor(s, m, 64); s2 += __shfl_xor(s2, m, 64); }
  __shared__ float buf[4];
  if ((threadIdx.x & 63) == 0) { int wi = threadIdx.x >> 6; buf[wi * 2] = s; buf[wi * 2 + 1] = s2; }
  __syncthreads();
  s = buf[0] + buf[2]; s2 = buf[1] + buf[3];
  float mean = s / (float)HID_;
  float var = s2 / (float)HID_ - mean * mean;
  float inv = rsqrtf(var + 1e-5f);
#pragma unroll
  for (int j = 0; j < 4; ++j) {
    int c = j * 128 + threadIdx.x;
    float o = (v[j] - mean) * inv * w[c] + bb[c];
    out[(size_t)row * HID_ + c] = o;
    if (out16) out16[(size_t)row * HID_ + c] = f2b(o);
  }
}

// ============================================================
// transpose ds_w (O,I,K) -> (K,I,O)
// ============================================================
__global__ void ec_transpose_dsw(const float* __restrict__ w, float* __restrict__ wt)
{
  int idx = blockIdx.x * 256 + threadIdx.x;
  if (idx < HID_ * HID_ * 3) {
    int k = idx % 3;
    int i = (idx / 3) % HID_;
    int o = idx / (3 * HID_);
    wt[((size_t)k * HID_ + i) * HID_ + o] = w[idx];
  }
}

// ============================================================
// strided downsample conv -> fp32 + bf16
// ============================================================
__global__ __launch_bounds__(512) void ec_dsconv16(
    const float* __restrict__ x, const float* __restrict__ wt,
    const float* __restrict__ bias, float* __restrict__ out, short* __restrict__ out16)
{
  const int b = blockIdx.y;
  const int lo0 = blockIdx.x * 16;
  const int o = threadIdx.x;
  __shared__ float xs[33][64];
  float acc[16];
#pragma unroll
  for (int q = 0; q < 16; ++q) acc[q] = 0.f;
  for (int ic = 0; ic < 8; ++ic) {
    for (int idx = threadIdx.x; idx < 33 * 64; idx += 512) {
      int r = idx >> 6, ii = idx & 63;
      int l = 2 * lo0 - 1 + r;
      xs[r][ii] = (l >= 0) ? x[((size_t)b * LSEQ_ + l) * HID_ + ic * 64 + ii] : 0.f;
    }
    __syncthreads();
    for (int ii = 0; ii < 64; ++ii) {
      int i = ic * 64 + ii;
      float w0 = wt[((size_t)0 * HID_ + i) * HID_ + o];
      float w1 = wt[((size_t)1 * HID_ + i) * HID_ + o];
      float w2 = wt[((size_t)2 * HID_ + i) * HID_ + o];
#pragma unroll
      for (int q = 0; q < 16; ++q)
        acc[q] += xs[2 * q + 0][ii] * w0 + xs[2 * q + 1][ii] * w1 + xs[2 * q + 2][ii] * w2;
    }
    __syncthreads();
  }
#pragma unroll
  for (int q = 0; q < 16; ++q) {
    float v = acc[q] + bias[o];
    out[((size_t)b * LT_ + lo0 + q) * HID_ + o] = v;
    out16[((size_t)b * LT_ + lo0 + q) * HID_ + o] = f2b(v);
  }
}

// ============================================================
// MFMA flash attention: qkv bf16 [B*LT,1536] -> out bf16 [B*LT,512]
// block = (qtile 64, head, batch), 4 waves; wave w owns q rows w*16..+16
// ============================================================
__global__ __launch_bounds__(256) void ec_attn16(
    const short* __restrict__ qkv, short* __restrict__ out)
{
  const int b = blockIdx.z, h = blockIdx.y, qt = blockIdx.x;
  __shared__ short Kl[64 * 68];   // [key][d] pad 68
  __shared__ short Vl[64 * 68];   // [d][key] pad 68 (transposed)
  __shared__ short Pl[64 * 68];   // [q][key]  pad 68
  const int tid = threadIdx.x;
  const int l = tid & 63, w = tid >> 6;
  const int lr = l & 15, lk = l >> 4;

  // Q fragments in registers (A-operand: row = l&15, k-octet = l>>4)
  const size_t qrow = (size_t)b * LT_ + qt * 64 + w * 16 + lr;
  bf16x8 qf[2];
  qf[0] = *(const bf16x8*)&qkv[qrow * 1536 + h * HD_ + lk * 8];
  qf[1] = *(const bf16x8*)&qkv[qrow * 1536 + h * HD_ + lk * 8 + 32];

  float mrun[4] = {-INFINITY, -INFINITY, -INFINITY, -INFINITY};
  float lsum[4] = {0.f, 0.f, 0.f, 0.f};
  f32x4 O[4];
#pragma unroll
  for (int df = 0; df < 4; ++df) O[df] = f32x4{0.f, 0.f, 0.f, 0.f};

  const int krow = tid >> 2, kcg = (tid & 3) * 16;
  const int vd = tid & 63, vw = tid >> 6;

  for (int kt = 0; kt < LT_ / 64; ++kt) {
    const size_t krbase = (size_t)b * LT_ + kt * 64;
    // stage K tile [key][d]
    {
      const short* kp = &qkv[(krbase + krow) * 1536 + HID_ + h * HD_ + kcg];
      *(bf16x8*)&Kl[krow * 68 + kcg] = *(const bf16x8*)kp;
      *(bf16x8*)&Kl[krow * 68 + kcg + 8] = *(const bf16x8*)(kp + 8);
    }
    // stage V^T tile [d][key] (coalesced global reads)
#pragma unroll
    for (int kk = 0; kk < 4; ++kk) {
      int key0 = vw * 16 + kk * 4;
      s16x4 pk;
#pragma unroll
      for (int j = 0; j < 4; ++j)
        pk[j] = qkv[(krbase + key0 + j) * 1536 + 2 * HID_ + h * HD_ + vd];
      *(s16x4*)&Vl[vd * 68 + key0] = pk;
    }
    __syncthreads();

    // S = Q @ K^T  (B-operand: col = key = l&15(+16nf), k-octet = l>>4)
    f32x4 S[4];
#pragma unroll
    for (int nf = 0; nf < 4; ++nf) S[nf] = f32x4{0.f, 0.f, 0.f, 0.f};
#pragma unroll
    for (int ks = 0; ks < 2; ++ks)
#pragma unroll
      for (int nf = 0; nf < 4; ++nf) {
        bf16x8 kb = *(const bf16x8*)&Kl[(nf * 16 + lr) * 68 + ks * 32 + lk * 8];
        S[nf] = __builtin_amdgcn_mfma_f32_16x16x32_bf16(qf[ks], kb, S[nf], 0, 0, 0);
      }

    // online softmax; lane's rows are lk*4+r, cols lr+16nf
    float fr[4];
#pragma unroll
    for (int r = 0; r < 4; ++r) {
      float mt = fmaxf(fmaxf(S[0][r], S[1][r]), fmaxf(S[2][r], S[3][r])) * 0.125f;
      mt = fmaxf(mt, __shfl_xor(mt, 1));
      mt = fmaxf(mt, __shfl_xor(mt, 2));
      mt = fmaxf(mt, __shfl_xor(mt, 4));
      mt = fmaxf(mt, __shfl_xor(mt, 8));
      float mn = fmaxf(mrun[r], mt);
      fr[r] = __expf(mrun[r] - mn);
      mrun[r] = mn;
      lsum[r] *= fr[r];
    }
#pragma unroll
    for (int nf = 0; nf < 4; ++nf)
#pragma unroll
      for (int r = 0; r < 4; ++r) {
        float p = __expf(S[nf][r] * 0.125f - mrun[r]);
        lsum[r] += p;
        Pl[(w * 16 + lk * 4 + r) * 68 + nf * 16 + lr] = f2b(p);
      }
#pragma unroll
    for (int df = 0; df < 4; ++df) {
      O[df][0] *= fr[0]; O[df][1] *= fr[1]; O[df][2] *= fr[2]; O[df][3] *= fr[3];
    }

    // O += P @ V  (A = P rows q, B = V^T rows d)
#pragma unroll
    for (int ks = 0; ks < 2; ++ks) {
      bf16x8 pa = *(const bf16x8*)&Pl[(w * 16 + lr) * 68 + ks * 32 + lk * 8];
#pragma unroll
      for (int df = 0; df < 4; ++df) {
        bf16x8 vb = *(const bf16x8*)&Vl[(df * 16 + lr) * 68 + ks * 32 + lk * 8];
        O[df] = __builtin_amdgcn_mfma_f32_16x16x32_bf16(pa, vb, O[df], 0, 0, 0);
      }
    }
    __syncthreads();
  }

#pragma unroll
  for (int r = 0; r < 4; ++r) {
    lsum[r] += __shfl_xor(lsum[r], 1);
    lsum[r] += __shfl_xor(lsum[r], 2);
    lsum[r] += __shfl_xor(lsum[r], 4);
    lsum[r] += __shfl_xor(lsum[r], 8);
    lsum[r] = 1.f / lsum[r];
  }
  const size_t orow0 = (size_t)b * LT_ + qt * 64 + w * 16;
#pragma unroll
  for (int df = 0; df < 4; ++df)
#pragma unroll
    for (int r = 0; r < 4; ++r)
      out[(orow0 + lk * 4 + r) * HID_ + h * HD_ + df * 16 + lr] = f2b(O[df][r] * lsum[r]);
}

// ============================================================
// host launch
// ============================================================
extern "C" void kernel_launch(void* const* d_in, const int* in_sizes, int n_in,
                              void* d_out, int out_size, void* d_ws, size_t ws_size,
                              hipStream_t stream)
{
  const float* x_in   = (const float*)d_in[0];
  const float* Wp     = (const float*)d_in[1];
  const float* bp     = (const float*)d_in[2];
  const float* m_Wi[2]   = {(const float*)d_in[3],  (const float*)d_in[11]};
  const float* m_cw[2]   = {(const float*)d_in[4],  (const float*)d_in[12]};
  const float* m_cb[2]   = {(const float*)d_in[5],  (const float*)d_in[13]};
  const float* m_dtb[2]  = {(const float*)d_in[6],  (const float*)d_in[14]};
  const float* m_Alog[2] = {(const float*)d_in[7],  (const float*)d_in[15]};
  const float* m_D[2]    = {(const float*)d_in[8],  (const float*)d_in[16]};
  const float* m_nw[2]   = {(const float*)d_in[9],  (const float*)d_in[17]};
  const float* m_Wo[2]   = {(const float*)d_in[10], (const float*)d_in[18]};
  const float* n_w[2]    = {(const float*)d_in[19], (const float*)d_in[20]};
  const float* ds_w   = (const float*)d_in[21];
  const float* ds_b   = (const float*)d_in[22];
  const float* t_Wqkv = (const float*)d_in[23];
  const float* t_bqkv = (const float*)d_in[24];
  const float* t_Wo   = (const float*)d_in[25];
  const float* t_bo   = (const float*)d_in[26];
  const float* t_W1   = (const float*)d_in[27];
  const float* t_b1   = (const float*)d_in[28];
  const float* t_W2   = (const float*)d_in[29];
  const float* t_b2   = (const float*)d_in[30];
  const float* t_ln1w = (const float*)d_in[31];
  const float* t_ln1b = (const float*)d_in[32];
  const float* t_ln2w = (const float*)d_in[33];
  const float* t_ln2b = (const float*)d_in[34];
  const float* on_w   = (const float*)d_in[35];
  const float* on_b   = (const float*)d_in[36];

  char* ws = (char*)d_ws;
  float* bx    = (float*)(ws + 0);            // [8192,512] f32 residual
  float* bzx   = (float*)(ws + 16777216);     // [8192,2208] f32 zxbcdt / transformer overlays
  float* bxbc  = (float*)(ws + 89128960);     // [8192,1152] f32 xBC / overlays
  float* by    = (float*)(ws + 126877696);    // [8192,1024] f32 scan y / x16 overlay
  float* bdt   = (float*)(ws + 160432128);
  float* bdec  = (float*)(ws + 161480704);
  float* bwt   = (float*)(ws + 162529280);    // dsw-t f32 [3,512,512] / weight slot
  short* wslot = (short*)(ws + 162529280);    // bf16 weight slot (<= 2.26 MB)
  float* Pc    = (float*)(ws + 162529280 + 2621440);  // 4 KB, disjoint from wslot

  short* x16     = (short*)by;                       // dead before scan writes y
  short* bx16    = (short*)bxbc;                     // alive rmsadd -> next in-proj
  short* gated16 = (short*)((char*)bxbc + 8388608);  // alive gate_rms -> out-proj

  // transformer overlays (bzx region, dead after mamba loop)
  short* ds16  = (short*)bzx;
  float* dsf   = (float*)((char*)bzx + 4194304);
  short* qkv16 = (short*)((char*)bzx + 12582912);
  short* att16 = (short*)((char*)bzx + 25165824);
  float* bt1   = (float*)((char*)bzx + 29360128);
  short* ln116 = (short*)((char*)bzx + 37748736);
  float* bxt2  = (float*)((char*)bzx + 41943040);
  short* ff16  = (short*)((char*)bzx + 50331648);
  float* bt2   = (float*)((char*)bzx + 58720256);
  float* bxt3  = (float*)bxbc;                       // bxbc dead after mamba

  const int MR = BB_ * LSEQ_;  // 8192
  const int MT = BB_ * LT_;    // 4096

  // input projection
  ec_f2b<<<(MR * 1024 / 8 + 255) / 256, 256, 0, stream>>>(x_in, x16, MR * 1024 / 8);
  ec_w2bt<<<dim3(1024 / 32, 512 / 32), 256, 0, stream>>>(Wp, wslot, 1024, 512);
  gemm16(stream, x16, wslot, bp, nullptr, bx, bx16, MR, HID_, 1024, 0);

  for (int blk = 0; blk < 2; ++blk) {
    ec_w2bt<<<dim3(512 / 32, 2208 / 32), 256, 0, stream>>>(m_Wi[blk], wslot, 512, 2208);
    gemm16(stream, bx16, wslot, nullptr, nullptr, bzx, nullptr, MR, DPROJ_, HID_, 0);
    ec_conv1d_silu<<<(MR * CONVD_ + 255) / 256, 256, 0, stream>>>(bzx, m_cw[blk], m_cb[blk], bxbc + 0x0 /*xBC*/ + 0);
    // NOTE: xBC shares the bxbc region start; bx16 was consumed by the gemm above.
    ec_dtdecay<<<(MR * NH_) / 256, 256, 0, stream>>>(bzx, m_dtb[blk], m_Alog[blk], bdt, bdec);
    ec_scan_p1<<<dim3(NH_, NC_, BB_), 512, 0, stream>>>(bxbc, bdt, bdec, bzx, Pc);
    ec_scan_p2<<<dim3(NH_, BB_), 512, 0, stream>>>(bzx, Pc);
    ec_scan_p3<<<dim3(NH_, NC_, BB_), 512, 0, stream>>>(bxbc, bdt, bdec, m_D[blk], bzx, by);
    ec_gate_rms16<<<MR, 256, 0, stream>>>(by, bzx, m_nw[blk], gated16);
    ec_w2bt<<<dim3(1024 / 32, 512 / 32), 256, 0, stream>>>(m_Wo[blk], wslot, 1024, 512);
    gemm16(stream, gated16, wslot, nullptr, nullptr, by, nullptr, MR, HID_, DIN_, 0);
    ec_rmsadd16<<<MR, 128, 0, stream>>>(by, bx, n_w[blk], bx, bx16);
  }

  // downsample conv (stride 2)
  ec_transpose_dsw<<<(HID_ * HID_ * 3 + 255) / 256, 256, 0, stream>>>(ds_w, bwt);
  ec_dsconv16<<<dim3(LT_ / 16, BB_), 512, 0, stream>>>(bx, bwt, ds_b, dsf, ds16);

  // transformer layer
  ec_w2bt<<<dim3(512 / 32, 1536 / 32), 256, 0, stream>>>(t_Wqkv, wslot, 512, 1536);
  gemm16(stream, ds16, wslot, t_bqkv, nullptr, nullptr, qkv16, MT, 3 * HID_, HID_, 0);
  ec_attn16<<<dim3(LT_ / 64, NHEAD_, BB_), 256, 0, stream>>>(qkv16, att16);
  ec_w2bt<<<dim3(512 / 32, 512 / 32), 256, 0, stream>>>(t_Wo, wslot, 512, 512);
  gemm16(stream, att16, wslot, t_bo, dsf, bt1, nullptr, MT, HID_, HID_, 0);
  ec_ln16<<<MT, 128, 0, stream>>>(bt1, t_ln1w, t_ln1b, bxt2, ln116);
  ec_w2bt<<<dim3(512 / 32, 1024 / 32), 256, 0, stream>>>(t_W1, wslot, 512, 1024);
  gemm16(stream, ln116, wslot, t_b1, nullptr, nullptr, ff16, MT, DFF_, HID_, 1);
  ec_w2bt<<<dim3(1024 / 32, 512 / 32), 256, 0, stream>>>(t_W2, wslot, 1024, 512);
  gemm16(stream, ff16, wslot, t_b2, bxt2, bt2, nullptr, MT, HID_, DFF_, 0);
  ec_ln16<<<MT, 128, 0, stream>>>(bt2, t_ln2w, t_ln2b, bxt3, nullptr);
  ec_ln16<<<MT, 128, 0, stream>>>(bxt3, on_w, on_b, (float*)d_out, nullptr);
}

// Round 4
// 1232.608 us; speedup vs baseline: 5.1756x; 1.1225x over previous
//
#include <hip/hip_runtime.h>
#include <math.h>

// ---- model dims ----
#define DIN_   1024
#define DSTATE_ 64
#define NH_    32
#define HDIM_  32
#define CONVD_ 1152   // DIN + 2*DSTATE
#define DPROJ_ 2208   // 2*DIN + 2*DSTATE + NH
#define HID_   512
#define LSEQ_  4096
#define BB_    2
#define LT_    2048   // after stride-2 downsample
#define NHEAD_ 8
#define HD_    64     // head dim = 512/8
#define DFF_   1024
#define LC_    256    // scan chunk length
#define NC_    16     // number of chunks (LSEQ_/LC_)

typedef __attribute__((ext_vector_type(8))) short bf16x8;
typedef __attribute__((ext_vector_type(4))) short s16x4;
typedef __attribute__((ext_vector_type(4))) float f32x4;

__device__ __forceinline__ float siluf(float x) { return x / (1.f + expf(-x)); }

__device__ __forceinline__ short f2b(float f) {
  union { float f; unsigned u; } v; v.f = f;
  unsigned r = (v.u + 0x7fffu + ((v.u >> 16) & 1u)) >> 16;
  return (short)r;
}

__device__ __forceinline__ float b2f(short s) {
  union { unsigned u; float f; } v; v.u = ((unsigned)(unsigned short)s) << 16;
  return v.f;
}

// async global->LDS 16B per lane; lds base must be wave-uniform
__device__ __forceinline__ void gload16(const short* g, short* lds_base) {
#if __has_builtin(__builtin_amdgcn_global_load_lds)
  __builtin_amdgcn_global_load_lds((const __attribute__((address_space(1))) void*)g,
                                   (__attribute__((address_space(3))) void*)lds_base, 16, 0, 0);
#else
  int l = threadIdx.x & 63;
  ((bf16x8*)lds_base)[l] = *(const bf16x8*)g;
#endif
}

// ============================================================
// fp32 -> bf16 elementwise (8 per thread)
// ============================================================
__global__ void ec_f2b(const float* __restrict__ in, short* __restrict__ out, int n8)
{
  int i = blockIdx.x * 256 + threadIdx.x;
  if (i >= n8) return;
  const float4* p = (const float4*)(in + (size_t)i * 8);
  float4 a = p[0], b = p[1];
  bf16x8 o;
  o[0] = f2b(a.x); o[1] = f2b(a.y); o[2] = f2b(a.z); o[3] = f2b(a.w);
  o[4] = f2b(b.x); o[5] = f2b(b.y); o[6] = f2b(b.z); o[7] = f2b(b.w);
  *(bf16x8*)(out + (size_t)i * 8) = o;
}

// ============================================================
// weight convert+transpose: W fp32 [K,N] -> Wt bf16 [N,K]
// ============================================================
__global__ __launch_bounds__(256) void ec_w2bt(const float* __restrict__ W,
                                               short* __restrict__ Wt, int K, int N)
{
  __shared__ float t[32][33];
  int k0 = blockIdx.x * 32, n0 = blockIdx.y * 32;
  int tx = threadIdx.x & 31, ty = threadIdx.x >> 5;
#pragma unroll
  for (int i = 0; i < 32; i += 8) t[ty + i][tx] = W[(size_t)(k0 + ty + i) * N + n0 + tx];
  __syncthreads();
#pragma unroll
  for (int i = 0; i < 32; i += 8) Wt[(size_t)(n0 + ty + i) * K + k0 + tx] = f2b(t[tx][ty + i]);
}

// ============================================================
// ds_w (O,I,K=3) -> Wt bf16 [O, K*512] with layout Wt[o][k*512+i]
// ============================================================
__global__ void ec_dswt(const float* __restrict__ w, short* __restrict__ wt)
{
  int idx = blockIdx.x * 256 + threadIdx.x;
  if (idx >= HID_ * 1536) return;
  int o = idx / 1536, r = idx % 1536;
  int k = r >> 9, i = r & 511;
  wt[idx] = f2b(w[((size_t)o * HID_ + i) * 3 + k]);
}

// ============================================================
// bf16 MFMA GEMM: C = act(A[M,K] @ W + bias) + res, W given as Wt bf16 [N,K]
// 128x128 tile, 4 waves, 4x4 16x16x32 frags, BK=32, double-buffered LDS.
// A row stride = lda; blockIdx.z batches: A += z*Az, C rows += z*Mz.
// M%128==0 (per z), K%32==0; N tiles guarded. act: 0=none, 1=gelu(exact)
// ============================================================
__global__ __launch_bounds__(256) void ec_gemm16(
    const short* __restrict__ A, const short* __restrict__ Wt,
    const float* __restrict__ bias, const float* __restrict__ res,
    float* __restrict__ Cf, short* __restrict__ Ch,
    int M, int N, int K, int act, int lda, long Az, int Mz)
{
  __shared__ short As_[2][4096];   // [buf][128 rows x 32 k]
  __shared__ short Bs_[2][4096];
  A += (size_t)blockIdx.z * Az;
  const int mz = blockIdx.z * Mz;
  const int tid = threadIdx.x;
  const int l = tid & 63, w = tid >> 6;
  const int m0 = blockIdx.y * 128, n0 = blockIdx.x * 128;
  const int wm = (w >> 1) * 64, wn = (w & 1) * 64;
  const int lr = l & 15, lk = l >> 4;
  const int arow = l >> 2, acol = (l & 3) * 8;

  f32x4 acc[4][4];
#pragma unroll
  for (int i = 0; i < 4; ++i)
#pragma unroll
    for (int j = 0; j < 4; ++j) acc[i][j] = f32x4{0.f, 0.f, 0.f, 0.f};

#pragma unroll
  for (int cc = 0; cc < 2; ++cc) {
    int c = w * 2 + cc;
    const short* ga = A + (size_t)(m0 + c * 16 + arow) * lda + acol;
    int rb = n0 + c * 16 + arow; if (rb > N - 1) rb = N - 1;
    const short* gb = Wt + (size_t)rb * K + acol;
    gload16(ga, &As_[0][c * 512]);
    gload16(gb, &Bs_[0][c * 512]);
  }

  const int KT = K >> 5;
  for (int kt = 0; kt < KT; ++kt) {
    __syncthreads();
    if (kt + 1 < KT) {
      int k0 = (kt + 1) << 5;
      int nb = (kt + 1) & 1;
#pragma unroll
      for (int cc = 0; cc < 2; ++cc) {
        int c = w * 2 + cc;
        const short* ga = A + (size_t)(m0 + c * 16 + arow) * lda + k0 + acol;
        int rb = n0 + c * 16 + arow; if (rb > N - 1) rb = N - 1;
        const short* gb = Wt + (size_t)rb * K + k0 + acol;
        gload16(ga, &As_[nb][c * 512]);
        gload16(gb, &Bs_[nb][c * 512]);
      }
    }
    int cb = kt & 1;
    bf16x8 af[4], bfv[4];
#pragma unroll
    for (int mf = 0; mf < 4; ++mf)
      af[mf] = *(const bf16x8*)&As_[cb][(wm + mf * 16 + lr) * 32 + lk * 8];
#pragma unroll
    for (int nf = 0; nf < 4; ++nf)
      bfv[nf] = *(const bf16x8*)&Bs_[cb][(wn + nf * 16 + lr) * 32 + lk * 8];
#pragma unroll
    for (int mf = 0; mf < 4; ++mf)
#pragma unroll
      for (int nf = 0; nf < 4; ++nf)
        acc[mf][nf] = __builtin_amdgcn_mfma_f32_16x16x32_bf16(af[mf], bfv[nf], acc[mf][nf], 0, 0, 0);
  }

#pragma unroll
  for (int mf = 0; mf < 4; ++mf)
#pragma unroll
    for (int nf = 0; nf < 4; ++nf)
#pragma unroll
      for (int r = 0; r < 4; ++r) {
        int m = mz + m0 + wm + mf * 16 + lk * 4 + r;
        int n = n0 + wn + nf * 16 + lr;
        if (n < N) {
          float v = acc[mf][nf][r];
          if (bias) v += bias[n];
          if (act == 1) v = 0.5f * v * (1.f + erff(v * 0.70710678118f));
          if (res) v += res[(size_t)m * N + n];
          if (Cf) Cf[(size_t)m * N + n] = v;
          if (Ch) Ch[(size_t)m * N + n] = f2b(v);
        }
      }
}

static inline void gemm16(hipStream_t s, const short* A, const short* Wt, const float* bias,
                          const float* res, float* Cf, short* Ch, int M, int N, int K, int act) {
  dim3 g((N + 127) / 128, M / 128), b(256);
  ec_gemm16<<<g, b, 0, s>>>(A, Wt, bias, res, Cf, Ch, M, N, K, act, K, 0, 0);
}

// fixup for dsconv GEMM boundary rows (lo=0 per batch: input row -1 is zero pad)
__global__ __launch_bounds__(512) void ec_dsfix(
    const short* __restrict__ x16, const short* __restrict__ wt,
    const float* __restrict__ bias, float* __restrict__ dsf, short* __restrict__ ds16)
{
  const int b = blockIdx.x, o = threadIdx.x;
  float v = bias[o];
#pragma unroll
  for (int k = 1; k < 3; ++k) {
    const short* xr = x16 + ((size_t)b * LSEQ_ + (k - 1)) * HID_;
    const short* wr = wt + (size_t)o * 1536 + k * 512;
    for (int i = 0; i < 512; ++i) v += b2f(xr[i]) * b2f(wr[i]);
  }
  dsf[(size_t)b * LT_ * HID_ + o] = v;
  ds16[(size_t)b * LT_ * HID_ + o] = f2b(v);
}

// ============================================================
// Depthwise causal conv (DCONV=4) + SiLU on the xBC slice of zxbcdt.
// ============================================================
__global__ void ec_conv1d_silu(const float* __restrict__ zx, const float* __restrict__ cw,
                               const float* __restrict__ cb, float* __restrict__ xBC)
{
  int idx = blockIdx.x * 256 + threadIdx.x;
  const int total = BB_ * LSEQ_ * CONVD_;
  if (idx >= total) return;
  int c = idx % CONVD_;
  int l = (idx / CONVD_) % LSEQ_;
  int b = idx / (CONVD_ * LSEQ_);
  const float* base = zx + (size_t)b * LSEQ_ * DPROJ_ + DIN_ + c;
  float s = cb[c];
#pragma unroll
  for (int j = 0; j < 4; ++j) {
    int ll = l - 3 + j;
    if (ll >= 0) s += base[(size_t)ll * DPROJ_] * cw[c * 4 + j];
  }
  xBC[idx] = siluf(s);
}

// ============================================================
// dt = softplus(dt_raw + dtb); decay = exp(-exp(Alog)*dt)
// ============================================================
__global__ void ec_dtdecay(const float* __restrict__ zx, const float* __restrict__ dtb,
                           const float* __restrict__ Alog, float* __restrict__ dts,
                           float* __restrict__ dec)
{
  int idx = blockIdx.x * 256 + threadIdx.x;
  int h = idx & 31;
  float x = zx[(size_t)(idx >> 5) * DPROJ_ + (DIN_ + CONVD_) + h] + dtb[h];
  float sp = (x > 20.f) ? x : log1pf(expf(x));
  dts[idx] = sp;
  dec[idx] = expf(-expf(Alog[h]) * sp);
}

// ============================================================
// Chunked SSM scan (states live in dead cols of zxbcdt rows 0..2047)
// ============================================================
__device__ __forceinline__ float* state_ptr(float* zxbase, int b, int c, int h, int e)
{
  int R = ((b * NC_ + c) * NH_ + h) * 2 + (e >> 10);
  return zxbase + (size_t)R * DPROJ_ + DIN_ + (e & 1023);
}

struct SValsB { float dsc, dcv, xv; float4 Bv; };

__device__ __forceinline__ void sloadB(SValsB& s, const float* __restrict__ xBC,
                                       const float* __restrict__ dts, const float* __restrict__ dec,
                                       size_t r, int h, int p, int n0)
{
  const float* xr = xBC + r * CONVD_;
  s.dsc = dts[r * NH_ + h];
  s.dcv = dec[r * NH_ + h];
  s.xv  = xr[h * HDIM_ + p];
  s.Bv  = *(const float4*)(xr + DIN_ + n0);
}

struct SVals { float dsc, dcv, xv; float4 Bv, Cv; };

__device__ __forceinline__ void sload(SVals& s, const float* __restrict__ xBC,
                                      const float* __restrict__ dts, const float* __restrict__ dec,
                                      size_t r, int h, int p, int n0)
{
  const float* xr = xBC + r * CONVD_;
  s.dsc = dts[r * NH_ + h];
  s.dcv = dec[r * NH_ + h];
  s.xv  = xr[h * HDIM_ + p];
  s.Bv  = *(const float4*)(xr + DIN_ + n0);
  s.Cv  = *(const float4*)(xr + DIN_ + DSTATE_ + n0);
}

__global__ __launch_bounds__(512) void ec_scan_p1(
    const float* __restrict__ xBC, const float* __restrict__ dts,
    const float* __restrict__ dec, float* __restrict__ zxbase, float* __restrict__ Pc)
{
  const int h = blockIdx.x, c = blockIdx.y, b = blockIdx.z;
  const int tid = threadIdx.x;
  const int p = tid >> 4, ni = tid & 15, n0 = ni * 4;
  const size_t rowB = (size_t)b * LSEQ_ + (size_t)c * LC_;
  float s0 = 0.f, s1 = 0.f, s2 = 0.f, s3 = 0.f, pr = 1.f;
  SValsB v0, v1, v2;
  sloadB(v0, xBC, dts, dec, rowB + 0, h, p, n0);
  sloadB(v1, xBC, dts, dec, rowB + 1, h, p, n0);
  for (int t = 0; t < LC_; ++t) {
    int tp = (t + 2 < LC_) ? t + 2 : LC_ - 1;
    sloadB(v2, xBC, dts, dec, rowB + tp, h, p, n0);
    const float dx = v0.dsc * v0.xv;
    s0 = s0 * v0.dcv + dx * v0.Bv.x;
    s1 = s1 * v0.dcv + dx * v0.Bv.y;
    s2 = s2 * v0.dcv + dx * v0.Bv.z;
    s3 = s3 * v0.dcv + dx * v0.Bv.w;
    pr *= v0.dcv;
    v0 = v1; v1 = v2;
  }
  int e = p * 64 + n0;
  *(float4*)state_ptr(zxbase, b, c, h, e) = make_float4(s0, s1, s2, s3);
  if (tid == 0) Pc[(b * NC_ + c) * NH_ + h] = pr;
}

__global__ __launch_bounds__(512) void ec_scan_p2(
    float* __restrict__ zxbase, const float* __restrict__ Pc)
{
  const int h = blockIdx.x, b = blockIdx.y;
  const int tid = threadIdx.x;
  const int e = (tid >> 4) * 64 + (tid & 15) * 4;
  float h0 = 0.f, h1 = 0.f, h2 = 0.f, h3 = 0.f;
  for (int c = 0; c < NC_; ++c) {
    float* ptr = state_ptr(zxbase, b, c, h, e);
    float4 S = *(float4*)ptr;
    *(float4*)ptr = make_float4(h0, h1, h2, h3);
    float P = Pc[(b * NC_ + c) * NH_ + h];
    h0 = h0 * P + S.x;
    h1 = h1 * P + S.y;
    h2 = h2 * P + S.z;
    h3 = h3 * P + S.w;
  }
}

__global__ __launch_bounds__(512) void ec_scan_p3(
    const float* __restrict__ xBC, const float* __restrict__ dts,
    const float* __restrict__ dec, const float* __restrict__ Dp,
    const float* __restrict__ zxbase, float* __restrict__ y)
{
  const int h = blockIdx.x, c = blockIdx.y, b = blockIdx.z;
  const int tid = threadIdx.x;
  const int p = tid >> 4, ni = tid & 15, n0 = ni * 4;
  const float Dh = Dp[h];
  const size_t rowB = (size_t)b * LSEQ_ + (size_t)c * LC_;
  const int e = p * 64 + n0;
  float4 hi = *(const float4*)state_ptr((float*)zxbase, b, c, h, e);
  float h0 = hi.x, h1 = hi.y, h2 = hi.z, h3 = hi.w;
  SVals v0, v1, v2;
  sload(v0, xBC, dts, dec, rowB + 0, h, p, n0);
  sload(v1, xBC, dts, dec, rowB + 1, h, p, n0);
  for (int t = 0; t < LC_; ++t) {
    int tp = (t + 2 < LC_) ? t + 2 : LC_ - 1;
    sload(v2, xBC, dts, dec, rowB + tp, h, p, n0);
    const float dx = v0.dsc * v0.xv;
    h0 = h0 * v0.dcv + dx * v0.Bv.x;
    h1 = h1 * v0.dcv + dx * v0.Bv.y;
    h2 = h2 * v0.dcv + dx * v0.Bv.z;
    h3 = h3 * v0.dcv + dx * v0.Bv.w;
    float acc = h0 * v0.Cv.x + h1 * v0.Cv.y + h2 * v0.Cv.z + h3 * v0.Cv.w;
    acc += __shfl_xor(acc, 1, 16);
    acc += __shfl_xor(acc, 2, 16);
    acc += __shfl_xor(acc, 4, 16);
    acc += __shfl_xor(acc, 8, 16);
    if (ni == 0) y[(rowB + t) * DIN_ + h * HDIM_ + p] = acc + Dh * v0.xv;
    v0 = v1; v1 = v2;
  }
}

// ============================================================
// t = y * silu(z); out = rmsnorm(t)*nw  -> bf16  (row width 1024)
// ============================================================
__global__ __launch_bounds__(256) void ec_gate_rms16(
    const float* __restrict__ y, const float* __restrict__ zx,
    const float* __restrict__ nw, short* __restrict__ out)
{
  const int row = blockIdx.x;
  const float* yr = y + (size_t)row * DIN_;
  const float* zr = zx + (size_t)row * DPROJ_;
  float v[4]; float ss = 0.f;
#pragma unroll
  for (int j = 0; j < 4; ++j) {
    int c = j * 256 + threadIdx.x;
    float t = yr[c] * siluf(zr[c]);
    v[j] = t; ss += t * t;
  }
#pragma unroll
  for (int m = 32; m >= 1; m >>= 1) ss += __shfl_xor(ss, m, 64);
  __shared__ float buf[4];
  if ((threadIdx.x & 63) == 0) buf[threadIdx.x >> 6] = ss;
  __syncthreads();
  ss = buf[0] + buf[1] + buf[2] + buf[3];
  float scale = rsqrtf(ss / (float)DIN_ + 1e-5f);
#pragma unroll
  for (int j = 0; j < 4; ++j) {
    int c = j * 256 + threadIdx.x;
    out[(size_t)row * DIN_ + c] = f2b(v[j] * scale * nw[c]);
  }
}

// ============================================================
// out = rmsnorm(a + b)*w  -> fp32 + bf16  (row width 512)
// ============================================================
__global__ __launch_bounds__(128) void ec_rmsadd16(
    const float* __restrict__ a, const float* __restrict__ bres,
    const float* __restrict__ w, float* __restrict__ out, short* __restrict__ out16)
{
  const int row = blockIdx.x;
  const float* ar = a + (size_t)row * HID_;
  const float* br = bres + (size_t)row * HID_;
  float v[4]; float ss = 0.f;
#pragma unroll
  for (int j = 0; j < 4; ++j) {
    int c = j * 128 + threadIdx.x;
    float t = ar[c] + br[c];
    v[j] = t; ss += t * t;
  }
#pragma unroll
  for (int m = 32; m >= 1; m >>= 1) ss += __shfl_xor(ss, m, 64);
  __shared__ float buf[2];
  if ((threadIdx.x & 63) == 0) buf[threadIdx.x >> 6] = ss;
  __syncthreads();
  ss = buf[0] + buf[1];
  float scale = rsqrtf(ss / (float)HID_ + 1e-5f);
#pragma unroll
  for (int j = 0; j < 4; ++j) {
    int c = j * 128 + threadIdx.x;
    float o = v[j] * scale * w[c];
    out[(size_t)row * HID_ + c] = o;
    out16[(size_t)row * HID_ + c] = f2b(o);
  }
}

// ============================================================
// layernorm(in)*w + b -> fp32 (+ optional bf16)  (row width 512)
// ============================================================
__global__ __launch_bounds__(128) void ec_ln16(
    const float* __restrict__ in, const float* __restrict__ w,
    const float* __restrict__ bb, float* __restrict__ out, short* __restrict__ out16)
{
  const int row = blockIdx.x;
  const float* ir = in + (size_t)row * HID_;
  float v[4]; float s = 0.f, s2 = 0.f;
#pragma unroll
  for (int j = 0; j < 4; ++j) {
    int c = j * 128 + threadIdx.x;
    float t = ir[c];
    v[j] = t; s += t; s2 += t * t;
  }
#pragma unroll
  for (int m = 32; m >= 1; m >>= 1) { s += __shfl_xor(s, m, 64); s2 += __shfl_xor(s2, m, 64); }
  __shared__ float buf[4];
  if ((threadIdx.x & 63) == 0) { int wi = threadIdx.x >> 6; buf[wi * 2] = s; buf[wi * 2 + 1] = s2; }
  __syncthreads();
  s = buf[0] + buf[2]; s2 = buf[1] + buf[3];
  float mean = s / (float)HID_;
  float var = s2 / (float)HID_ - mean * mean;
  float inv = rsqrtf(var + 1e-5f);
#pragma unroll
  for (int j = 0; j < 4; ++j) {
    int c = j * 128 + threadIdx.x;
    float o = (v[j] - mean) * inv * w[c] + bb[c];
    out[(size_t)row * HID_ + c] = o;
    if (out16) out16[(size_t)row * HID_ + c] = f2b(o);
  }
}

// ============================================================
// MFMA flash attention: qkv bf16 [B*LT,1536] -> out bf16 [B*LT,512]
// ============================================================
__global__ __launch_bounds__(256) void ec_attn16(
    const short* __restrict__ qkv, short* __restrict__ out)
{
  const int b = blockIdx.z, h = blockIdx.y, qt = blockIdx.x;
  __shared__ short Kl[64 * 68];
  __shared__ short Vl[64 * 68];
  __shared__ short Pl[64 * 68];
  const int tid = threadIdx.x;
  const int l = tid & 63, w = tid >> 6;
  const int lr = l & 15, lk = l >> 4;

  const size_t qrow = (size_t)b * LT_ + qt * 64 + w * 16 + lr;
  bf16x8 qf[2];
  qf[0] = *(const bf16x8*)&qkv[qrow * 1536 + h * HD_ + lk * 8];
  qf[1] = *(const bf16x8*)&qkv[qrow * 1536 + h * HD_ + lk * 8 + 32];

  float mrun[4] = {-INFINITY, -INFINITY, -INFINITY, -INFINITY};
  float lsum[4] = {0.f, 0.f, 0.f, 0.f};
  f32x4 O[4];
#pragma unroll
  for (int df = 0; df < 4; ++df) O[df] = f32x4{0.f, 0.f, 0.f, 0.f};

  const int krow = tid >> 2, kcg = (tid & 3) * 16;
  const int vd = tid & 63, vw = tid >> 6;

  for (int kt = 0; kt < LT_ / 64; ++kt) {
    const size_t krbase = (size_t)b * LT_ + kt * 64;
    {
      const short* kp = &qkv[(krbase + krow) * 1536 + HID_ + h * HD_ + kcg];
      *(bf16x8*)&Kl[krow * 68 + kcg] = *(const bf16x8*)kp;
      *(bf16x8*)&Kl[krow * 68 + kcg + 8] = *(const bf16x8*)(kp + 8);
    }
#pragma unroll
    for (int kk = 0; kk < 4; ++kk) {
      int key0 = vw * 16 + kk * 4;
      s16x4 pk;
#pragma unroll
      for (int j = 0; j < 4; ++j)
        pk[j] = qkv[(krbase + key0 + j) * 1536 + 2 * HID_ + h * HD_ + vd];
      *(s16x4*)&Vl[vd * 68 + key0] = pk;
    }
    __syncthreads();

    f32x4 S[4];
#pragma unroll
    for (int nf = 0; nf < 4; ++nf) S[nf] = f32x4{0.f, 0.f, 0.f, 0.f};
#pragma unroll
    for (int ks = 0; ks < 2; ++ks)
#pragma unroll
      for (int nf = 0; nf < 4; ++nf) {
        bf16x8 kb = *(const bf16x8*)&Kl[(nf * 16 + lr) * 68 + ks * 32 + lk * 8];
        S[nf] = __builtin_amdgcn_mfma_f32_16x16x32_bf16(qf[ks], kb, S[nf], 0, 0, 0);
      }

    float fr[4];
#pragma unroll
    for (int r = 0; r < 4; ++r) {
      float mt = fmaxf(fmaxf(S[0][r], S[1][r]), fmaxf(S[2][r], S[3][r])) * 0.125f;
      mt = fmaxf(mt, __shfl_xor(mt, 1));
      mt = fmaxf(mt, __shfl_xor(mt, 2));
      mt = fmaxf(mt, __shfl_xor(mt, 4));
      mt = fmaxf(mt, __shfl_xor(mt, 8));
      float mn = fmaxf(mrun[r], mt);
      fr[r] = __expf(mrun[r] - mn);
      mrun[r] = mn;
      lsum[r] *= fr[r];
    }
#pragma unroll
    for (int nf = 0; nf < 4; ++nf)
#pragma unroll
      for (int r = 0; r < 4; ++r) {
        float p = __expf(S[nf][r] * 0.125f - mrun[r]);
        lsum[r] += p;
        Pl[(w * 16 + lk * 4 + r) * 68 + nf * 16 + lr] = f2b(p);
      }
#pragma unroll
    for (int df = 0; df < 4; ++df) {
      O[df][0] *= fr[0]; O[df][1] *= fr[1]; O[df][2] *= fr[2]; O[df][3] *= fr[3];
    }

#pragma unroll
    for (int ks = 0; ks < 2; ++ks) {
      bf16x8 pa = *(const bf16x8*)&Pl[(w * 16 + lr) * 68 + ks * 32 + lk * 8];
#pragma unroll
      for (int df = 0; df < 4; ++df) {
        bf16x8 vb = *(const bf16x8*)&Vl[(df * 16 + lr) * 68 + ks * 32 + lk * 8];
        O[df] = __builtin_amdgcn_mfma_f32_16x16x32_bf16(pa, vb, O[df], 0, 0, 0);
      }
    }
    __syncthreads();
  }

#pragma unroll
  for (int r = 0; r < 4; ++r) {
    lsum[r] += __shfl_xor(lsum[r], 1);
    lsum[r] += __shfl_xor(lsum[r], 2);
    lsum[r] += __shfl_xor(lsum[r], 4);
    lsum[r] += __shfl_xor(lsum[r], 8);
    lsum[r] = 1.f / lsum[r];
  }
  const size_t orow0 = (size_t)b * LT_ + qt * 64 + w * 16;
#pragma unroll
  for (int df = 0; df < 4; ++df)
#pragma unroll
    for (int r = 0; r < 4; ++r)
      out[(orow0 + lk * 4 + r) * HID_ + h * HD_ + df * 16 + lr] = f2b(O[df][r] * lsum[r]);
}

// ============================================================
// host launch
// ============================================================
extern "C" void kernel_launch(void* const* d_in, const int* in_sizes, int n_in,
                              void* d_out, int out_size, void* d_ws, size_t ws_size,
                              hipStream_t stream)
{
  const float* x_in   = (const float*)d_in[0];
  const float* Wp     = (const float*)d_in[1];
  const float* bp     = (const float*)d_in[2];
  const float* m_Wi[2]   = {(const float*)d_in[3],  (const float*)d_in[11]};
  const float* m_cw[2]   = {(const float*)d_in[4],  (const float*)d_in[12]};
  const float* m_cb[2]   = {(const float*)d_in[5],  (const float*)d_in[13]};
  const float* m_dtb[2]  = {(const float*)d_in[6],  (const float*)d_in[14]};
  const float* m_Alog[2] = {(const float*)d_in[7],  (const float*)d_in[15]};
  const float* m_D[2]    = {(const float*)d_in[8],  (const float*)d_in[16]};
  const float* m_nw[2]   = {(const float*)d_in[9],  (const float*)d_in[17]};
  const float* m_Wo[2]   = {(const float*)d_in[10], (const float*)d_in[18]};
  const float* n_w[2]    = {(const float*)d_in[19], (const float*)d_in[20]};
  const float* ds_w   = (const float*)d_in[21];
  const float* ds_b   = (const float*)d_in[22];
  const float* t_Wqkv = (const float*)d_in[23];
  const float* t_bqkv = (const float*)d_in[24];
  const float* t_Wo   = (const float*)d_in[25];
  const float* t_bo   = (const float*)d_in[26];
  const float* t_W1   = (const float*)d_in[27];
  const float* t_b1   = (const float*)d_in[28];
  const float* t_W2   = (const float*)d_in[29];
  const float* t_b2   = (const float*)d_in[30];
  const float* t_ln1w = (const float*)d_in[31];
  const float* t_ln1b = (const float*)d_in[32];
  const float* t_ln2w = (const float*)d_in[33];
  const float* t_ln2b = (const float*)d_in[34];
  const float* on_w   = (const float*)d_in[35];
  const float* on_b   = (const float*)d_in[36];

  char* ws = (char*)d_ws;
  float* bx    = (float*)(ws + 0);            // [8192,512] f32 residual
  float* bzx   = (float*)(ws + 16777216);     // [8192,2208] f32 zxbcdt / transformer overlays
  float* bxbc  = (float*)(ws + 89128960);     // [8192,1152] f32 xBC / overlays
  float* by    = (float*)(ws + 126877696);    // [8192,1024] f32 scan y / x16 overlay
  float* bdt   = (float*)(ws + 160432128);
  float* bdec  = (float*)(ws + 161480704);
  short* wslot = (short*)(ws + 162529280);    // bf16 weight slot (<= 2.26 MB)
  float* Pc    = (float*)(ws + 162529280 + 2621440);

  short* x16     = (short*)by;
  short* bx16    = (short*)bxbc;
  short* gated16 = (short*)((char*)bxbc + 8388608);

  short* ds16  = (short*)bzx;
  float* dsf   = (float*)((char*)bzx + 4194304);
  short* qkv16 = (short*)((char*)bzx + 12582912);
  short* att16 = (short*)((char*)bzx + 25165824);
  float* bt1   = (float*)((char*)bzx + 29360128);
  short* ln116 = (short*)((char*)bzx + 37748736);
  float* bxt2  = (float*)((char*)bzx + 41943040);
  short* ff16  = (short*)((char*)bzx + 50331648);
  float* bt2   = (float*)((char*)bzx + 58720256);
  float* bxt3  = (float*)bxbc;

  const int MR = BB_ * LSEQ_;  // 8192
  const int MT = BB_ * LT_;    // 4096

  // input projection
  ec_f2b<<<(MR * 1024 / 8 + 255) / 256, 256, 0, stream>>>(x_in, x16, MR * 1024 / 8);
  ec_w2bt<<<dim3(1024 / 32, 512 / 32), 256, 0, stream>>>(Wp, wslot, 1024, 512);
  gemm16(stream, x16, wslot, bp, nullptr, bx, bx16, MR, HID_, 1024, 0);

  for (int blk = 0; blk < 2; ++blk) {
    ec_w2bt<<<dim3(512 / 32, 2208 / 32), 256, 0, stream>>>(m_Wi[blk], wslot, 512, 2208);
    gemm16(stream, bx16, wslot, nullptr, nullptr, bzx, nullptr, MR, DPROJ_, HID_, 0);
    ec_conv1d_silu<<<(MR * CONVD_ + 255) / 256, 256, 0, stream>>>(bzx, m_cw[blk], m_cb[blk], bxbc);
    ec_dtdecay<<<(MR * NH_) / 256, 256, 0, stream>>>(bzx, m_dtb[blk], m_Alog[blk], bdt, bdec);
    ec_scan_p1<<<dim3(NH_, NC_, BB_), 512, 0, stream>>>(bxbc, bdt, bdec, bzx, Pc);
    ec_scan_p2<<<dim3(NH_, BB_), 512, 0, stream>>>(bzx, Pc);
    ec_scan_p3<<<dim3(NH_, NC_, BB_), 512, 0, stream>>>(bxbc, bdt, bdec, m_D[blk], bzx, by);
    ec_gate_rms16<<<MR, 256, 0, stream>>>(by, bzx, m_nw[blk], gated16);
    ec_w2bt<<<dim3(1024 / 32, 512 / 32), 256, 0, stream>>>(m_Wo[blk], wslot, 1024, 512);
    gemm16(stream, gated16, wslot, nullptr, nullptr, by, nullptr, MR, HID_, DIN_, 0);
    ec_rmsadd16<<<MR, 128, 0, stream>>>(by, bx, n_w[blk], bx, bx16);
  }

  // downsample conv as implicit-im2col GEMM:
  // A row lo = bx16 rows (2lo-1, 2lo, 2lo+1) = 1536 contiguous bf16, lda=1024.
  // Row lo=0 reads 512 elems of dead workspace before bx16 -> fixed by ec_dsfix.
  ec_dswt<<<(HID_ * 1536 + 255) / 256, 256, 0, stream>>>(ds_w, wslot);
  {
    dim3 g(512 / 128, LT_ / 128, BB_), b(256);
    ec_gemm16<<<g, b, 0, stream>>>(bx16 - 512, wslot, ds_b, nullptr, dsf, ds16,
                                   LT_, HID_, 1536, 0, 1024, (long)LSEQ_ * HID_, LT_);
  }
  ec_dsfix<<<BB_, 512, 0, stream>>>(bx16, wslot, ds_b, dsf, ds16);

  // transformer layer
  ec_w2bt<<<dim3(512 / 32, 1536 / 32), 256, 0, stream>>>(t_Wqkv, wslot, 512, 1536);
  gemm16(stream, ds16, wslot, t_bqkv, nullptr, nullptr, qkv16, MT, 3 * HID_, HID_, 0);
  ec_attn16<<<dim3(LT_ / 64, NHEAD_, BB_), 256, 0, stream>>>(qkv16, att16);
  ec_w2bt<<<dim3(512 / 32, 512 / 32), 256, 0, stream>>>(t_Wo, wslot, 512, 512);
  gemm16(stream, att16, wslot, t_bo, dsf, bt1, nullptr, MT, HID_, HID_, 0);
  ec_ln16<<<MT, 128, 0, stream>>>(bt1, t_ln1w, t_ln1b, bxt2, ln116);
  ec_w2bt<<<dim3(512 / 32, 1024 / 32), 256, 0, stream>>>(t_W1, wslot, 512, 1024);
  gemm16(stream, ln116, wslot, t_b1, nullptr, nullptr, ff16, MT, DFF_, HID_, 1);
  ec_w2bt<<<dim3(1024 / 32, 512 / 32), 256, 0, stream>>>(t_W2, wslot, 1024, 512);
  gemm16(stream, ff16, wslot, t_b2, bxt2, bt2, nullptr, MT, HID_, DFF_, 0);
  ec_ln16<<<MT, 128, 0, stream>>>(bt2, t_ln2w, t_ln2b, bxt3, nullptr);
  ec_ln16<<<MT, 128, 0, stream>>>(bxt3, on_w, on_b, (float*)d_out, nullptr);
}

// Round 6
// 1048.083 us; speedup vs baseline: 6.0869x; 1.1761x over previous
//
#include <hip/hip_runtime.h>
#include <math.h>

// ---- model dims ----
#define DIN_   1024
#define DSTATE_ 64
#define NH_    32
#define HDIM_  32
#define CONVD_ 1152   // DIN + 2*DSTATE
#define DPROJ_ 2208   // 2*DIN + 2*DSTATE + NH
#define HID_   512
#define LSEQ_  4096
#define BB_    2
#define LT_    2048   // after stride-2 downsample
#define NHEAD_ 8
#define HD_    64     // head dim = 512/8
#define DFF_   1024
#define LC_    256    // scan chunk length
#define NC_    16     // number of chunks (LSEQ_/LC_)

typedef __attribute__((ext_vector_type(8))) short bf16x8;
typedef __attribute__((ext_vector_type(4))) short s16x4;
typedef __attribute__((ext_vector_type(4))) float f32x4;

__device__ __forceinline__ float siluf(float x) { return x / (1.f + expf(-x)); }

__device__ __forceinline__ short f2b(float f) {
  union { float f; unsigned u; } v; v.f = f;
  unsigned r = (v.u + 0x7fffu + ((v.u >> 16) & 1u)) >> 16;
  return (short)r;
}

__device__ __forceinline__ float b2f(short s) {
  union { unsigned u; float f; } v; v.u = ((unsigned)(unsigned short)s) << 16;
  return v.f;
}

// async global->LDS 16B per lane; lds base must be wave-uniform
__device__ __forceinline__ void gload16(const short* g, short* lds_base) {
#if __has_builtin(__builtin_amdgcn_global_load_lds)
  __builtin_amdgcn_global_load_lds((const __attribute__((address_space(1))) void*)g,
                                   (__attribute__((address_space(3))) void*)lds_base, 16, 0, 0);
#else
  int l = threadIdx.x & 63;
  ((bf16x8*)lds_base)[l] = *(const bf16x8*)g;
#endif
}

// ============================================================
// fp32 -> bf16 elementwise (8 per thread)
// ============================================================
__global__ void ec_f2b(const float* __restrict__ in, short* __restrict__ out, int n8)
{
  int i = blockIdx.x * 256 + threadIdx.x;
  if (i >= n8) return;
  const float4* p = (const float4*)(in + (size_t)i * 8);
  float4 a = p[0], b = p[1];
  bf16x8 o;
  o[0] = f2b(a.x); o[1] = f2b(a.y); o[2] = f2b(a.z); o[3] = f2b(a.w);
  o[4] = f2b(b.x); o[5] = f2b(b.y); o[6] = f2b(b.z); o[7] = f2b(b.w);
  *(bf16x8*)(out + (size_t)i * 8) = o;
}

// ============================================================
// weight convert+transpose: W fp32 [K,N] -> Wt bf16 [N,K]
// ============================================================
__global__ __launch_bounds__(256) void ec_w2bt(const float* __restrict__ W,
                                               short* __restrict__ Wt, int K, int N)
{
  __shared__ float t[32][33];
  int k0 = blockIdx.x * 32, n0 = blockIdx.y * 32;
  int tx = threadIdx.x & 31, ty = threadIdx.x >> 5;
#pragma unroll
  for (int i = 0; i < 32; i += 8) t[ty + i][tx] = W[(size_t)(k0 + ty + i) * N + n0 + tx];
  __syncthreads();
#pragma unroll
  for (int i = 0; i < 32; i += 8) Wt[(size_t)(n0 + ty + i) * K + k0 + tx] = f2b(t[tx][ty + i]);
}

// ============================================================
// ds_w (O,I,K=3) -> Wt bf16 [O, K*512] with layout Wt[o][k*512+i]
// ============================================================
__global__ void ec_dswt(const float* __restrict__ w, short* __restrict__ wt)
{
  int idx = blockIdx.x * 256 + threadIdx.x;
  if (idx >= HID_ * 1536) return;
  int o = idx / 1536, r = idx % 1536;
  int k = r >> 9, i = r & 511;
  wt[idx] = f2b(w[((size_t)o * HID_ + i) * 3 + k]);
}

// ============================================================
// bf16 MFMA GEMM: C = act(A[M,K] @ W + bias) + res, W given as Wt bf16 [N,K]
// 128x128 tile, 4 waves, 4x4 16x16x32 frags, BK=32, double-buffered LDS.
// ============================================================
__global__ __launch_bounds__(256) void ec_gemm16(
    const short* __restrict__ A, const short* __restrict__ Wt,
    const float* __restrict__ bias, const float* __restrict__ res,
    float* __restrict__ Cf, short* __restrict__ Ch,
    int M, int N, int K, int act, int lda, long Az, int Mz)
{
  __shared__ short As_[2][4096];
  __shared__ short Bs_[2][4096];
  A += (size_t)blockIdx.z * Az;
  const int mz = blockIdx.z * Mz;
  const int tid = threadIdx.x;
  const int l = tid & 63, w = tid >> 6;
  const int m0 = blockIdx.y * 128, n0 = blockIdx.x * 128;
  const int wm = (w >> 1) * 64, wn = (w & 1) * 64;
  const int lr = l & 15, lk = l >> 4;
  const int arow = l >> 2, acol = (l & 3) * 8;

  f32x4 acc[4][4];
#pragma unroll
  for (int i = 0; i < 4; ++i)
#pragma unroll
    for (int j = 0; j < 4; ++j) acc[i][j] = f32x4{0.f, 0.f, 0.f, 0.f};

#pragma unroll
  for (int cc = 0; cc < 2; ++cc) {
    int c = w * 2 + cc;
    const short* ga = A + (size_t)(m0 + c * 16 + arow) * lda + acol;
    int rb = n0 + c * 16 + arow; if (rb > N - 1) rb = N - 1;
    const short* gb = Wt + (size_t)rb * K + acol;
    gload16(ga, &As_[0][c * 512]);
    gload16(gb, &Bs_[0][c * 512]);
  }

  const int KT = K >> 5;
  for (int kt = 0; kt < KT; ++kt) {
    __syncthreads();
    if (kt + 1 < KT) {
      int k0 = (kt + 1) << 5;
      int nb = (kt + 1) & 1;
#pragma unroll
      for (int cc = 0; cc < 2; ++cc) {
        int c = w * 2 + cc;
        const short* ga = A + (size_t)(m0 + c * 16 + arow) * lda + k0 + acol;
        int rb = n0 + c * 16 + arow; if (rb > N - 1) rb = N - 1;
        const short* gb = Wt + (size_t)rb * K + k0 + acol;
        gload16(ga, &As_[nb][c * 512]);
        gload16(gb, &Bs_[nb][c * 512]);
      }
    }
    int cb = kt & 1;
    bf16x8 af[4], bfv[4];
#pragma unroll
    for (int mf = 0; mf < 4; ++mf)
      af[mf] = *(const bf16x8*)&As_[cb][(wm + mf * 16 + lr) * 32 + lk * 8];
#pragma unroll
    for (int nf = 0; nf < 4; ++nf)
      bfv[nf] = *(const bf16x8*)&Bs_[cb][(wn + nf * 16 + lr) * 32 + lk * 8];
#pragma unroll
    for (int mf = 0; mf < 4; ++mf)
#pragma unroll
      for (int nf = 0; nf < 4; ++nf)
        acc[mf][nf] = __builtin_amdgcn_mfma_f32_16x16x32_bf16(af[mf], bfv[nf], acc[mf][nf], 0, 0, 0);
  }

#pragma unroll
  for (int mf = 0; mf < 4; ++mf)
#pragma unroll
    for (int nf = 0; nf < 4; ++nf)
#pragma unroll
      for (int r = 0; r < 4; ++r) {
        int m = mz + m0 + wm + mf * 16 + lk * 4 + r;
        int n = n0 + wn + nf * 16 + lr;
        if (n < N) {
          float v = acc[mf][nf][r];
          if (bias) v += bias[n];
          if (act == 1) v = 0.5f * v * (1.f + erff(v * 0.70710678118f));
          if (res) v += res[(size_t)m * N + n];
          if (Cf) Cf[(size_t)m * N + n] = v;
          if (Ch) Ch[(size_t)m * N + n] = f2b(v);
        }
      }
}

static inline void gemm16(hipStream_t s, const short* A, const short* Wt, const float* bias,
                          const float* res, float* Cf, short* Ch, int M, int N, int K, int act) {
  dim3 g((N + 127) / 128, M / 128), b(256);
  ec_gemm16<<<g, b, 0, s>>>(A, Wt, bias, res, Cf, Ch, M, N, K, act, K, 0, 0);
}

// fixup for dsconv GEMM boundary rows (lo=0 per batch)
__global__ __launch_bounds__(512) void ec_dsfix(
    const short* __restrict__ x16, const short* __restrict__ wt,
    const float* __restrict__ bias, float* __restrict__ dsf, short* __restrict__ ds16)
{
  const int b = blockIdx.x, o = threadIdx.x;
  float v = bias[o];
#pragma unroll
  for (int k = 1; k < 3; ++k) {
    const short* xr = x16 + ((size_t)b * LSEQ_ + (k - 1)) * HID_;
    const short* wr = wt + (size_t)o * 1536 + k * 512;
    for (int i = 0; i < 512; ++i) v += b2f(xr[i]) * b2f(wr[i]);
  }
  dsf[(size_t)b * LT_ * HID_ + o] = v;
  ds16[(size_t)b * LT_ * HID_ + o] = f2b(v);
}

// ============================================================
// Depthwise causal conv (DCONV=4) + SiLU on the xBC slice of zxbcdt.
// ============================================================
__global__ void ec_conv1d_silu(const float* __restrict__ zx, const float* __restrict__ cw,
                               const float* __restrict__ cb, float* __restrict__ xBC)
{
  int idx = blockIdx.x * 256 + threadIdx.x;
  const int total = BB_ * LSEQ_ * CONVD_;
  if (idx >= total) return;
  int c = idx % CONVD_;
  int l = (idx / CONVD_) % LSEQ_;
  int b = idx / (CONVD_ * LSEQ_);
  const float* base = zx + (size_t)b * LSEQ_ * DPROJ_ + DIN_ + c;
  float s = cb[c];
#pragma unroll
  for (int j = 0; j < 4; ++j) {
    int ll = l - 3 + j;
    if (ll >= 0) s += base[(size_t)ll * DPROJ_] * cw[c * 4 + j];
  }
  xBC[idx] = siluf(s);
}

// ============================================================
// SSD prep 1: per-chunk softplus(dt)+cumsum -> dts, lp (log decay prefix), Pc
// ============================================================
__global__ __launch_bounds__(256) void ec_ssd_cumsum(
    const float* __restrict__ zx, const float* __restrict__ dtb,
    const float* __restrict__ Alog, float* __restrict__ dts,
    float* __restrict__ lp, float* __restrict__ Pc)
{
  const int c = blockIdx.x, b = blockIdx.y;
  const int t = threadIdx.x;
  const size_t row = (size_t)b * LSEQ_ + (size_t)c * LC_ + t;
  __shared__ float A[256][33];
  __shared__ float eAs[32];
  float dt[32];
#pragma unroll
  for (int h = 0; h < 32; ++h) {
    float x = zx[row * DPROJ_ + (DIN_ + CONVD_) + h] + dtb[h];
    float sp = (x > 20.f) ? x : log1pf(expf(x));
    dt[h] = sp;
    A[t][h] = sp;
  }
  if (t < 32) eAs[t] = expf(Alog[t]);
  __syncthreads();
  for (int d = 1; d < 256; d <<= 1) {
    float tmp[32];
#pragma unroll
    for (int h = 0; h < 32; ++h) tmp[h] = (t >= d) ? A[t - d][h] : 0.f;
    __syncthreads();
#pragma unroll
    for (int h = 0; h < 32; ++h) A[t][h] += tmp[h];
    __syncthreads();
  }
#pragma unroll
  for (int h = 0; h < 32; ++h) {
    dts[row * NH_ + h] = dt[h];
    float lpv = -eAs[h] * A[t][h];
    lp[row * NH_ + h] = lpv;
    if (t == LC_ - 1) Pc[(b * NC_ + c) * NH_ + h] = expf(lpv);
  }
}

// ============================================================
// SSD prep 2: xBC B/C slices -> bf16
// ============================================================
__global__ void ec_bc16(const float* __restrict__ xBC, short* __restrict__ B16,
                        short* __restrict__ C16)
{
  int idx = blockIdx.x * 256 + threadIdx.x;
  if (idx >= BB_ * LSEQ_ * 128) return;
  int row = idx >> 7, col = idx & 127;
  float v = xBC[(size_t)row * CONVD_ + DIN_ + col];
  if (col < 64) B16[(size_t)row * 64 + col] = f2b(v);
  else          C16[(size_t)row * 64 + col - 64] = f2b(v);
}

// ============================================================
// SSD prep 3: VT[b,c,h][p][t] = bf16( dt[t,h] * x[t, h*32+p] )
// ============================================================
__global__ __launch_bounds__(64) void ec_vt(
    const float* __restrict__ xBC, const float* __restrict__ dts, short* __restrict__ VT)
{
  const int h = blockIdx.x, c = blockIdx.y, b = blockIdx.z;
  const int l = threadIdx.x;
  const size_t rowB = (size_t)b * LSEQ_ + (size_t)c * LC_;
  const size_t vtbase = (size_t)((b * NC_ + c) * NH_ + h) * 32;
  __shared__ float tile[32][33];
  for (int tt = 0; tt < 8; ++tt) {
#pragma unroll
    for (int i = 0; i < 16; ++i) {
      int r = i * 2 + (l >> 5);
      size_t row = rowB + tt * 32 + r;
      tile[r][l & 31] = xBC[row * CONVD_ + h * 32 + (l & 31)] * dts[row * NH_ + h];
    }
    __syncthreads();
#pragma unroll
    for (int j = 0; j < 16; ++j) {
      int p = j * 2 + (l >> 5);
      VT[(vtbase + p) * 256 + tt * 32 + (l & 31)] = f2b(tile[l & 31][p]);
    }
    __syncthreads();
  }
}

// ============================================================
// state lives in dead cols [DIN_, DIN_+1024) of zxbcdt rows 0..2047
// ============================================================
__device__ __forceinline__ float* state_ptr(float* zxbase, int b, int c, int h, int e)
{
  int R = ((b * NC_ + c) * NH_ + h) * 2 + (e >> 10);
  return zxbase + (size_t)R * DPROJ_ + DIN_ + (e & 1023);
}

// ============================================================
// SSD p1 (MFMA): chunk state S[p][n] = sum_t exp(lpEnd-lp_t)*dtx[t,p]*B[t,n]
// ============================================================
__global__ __launch_bounds__(64) void ec_ssd_p1(
    const short* __restrict__ B16, const short* __restrict__ VT,
    const float* __restrict__ lp, float* __restrict__ zxbase)
{
  const int h = blockIdx.x, c = blockIdx.y, b = blockIdx.z;
  const int l = threadIdx.x, lr = l & 15, lk = l >> 4;
  const size_t rowB = (size_t)b * LSEQ_ + (size_t)c * LC_;
  const size_t vtbase = (size_t)((b * NC_ + c) * NH_ + h) * 32;
  __shared__ short BT[64][264];   // B^T [n][t]
  for (int i = 0; i < 4; ++i) {
    int t = i * 64 + l;
#pragma unroll
    for (int g = 0; g < 8; ++g) {
      bf16x8 v = *(const bf16x8*)&B16[(rowB + t) * 64 + g * 8];
#pragma unroll
      for (int j = 0; j < 8; ++j) BT[g * 8 + j][t] = v[j];
    }
  }
  __syncthreads();
  const float lpE = lp[(rowB + LC_ - 1) * NH_ + h];
  f32x4 acc[2][4];
#pragma unroll
  for (int i = 0; i < 2; ++i)
#pragma unroll
    for (int j = 0; j < 4; ++j) acc[i][j] = f32x4{0.f, 0.f, 0.f, 0.f};

  for (int ks = 0; ks < 8; ++ks) {
    float wv[8];
#pragma unroll
    for (int j = 0; j < 8; ++j) {
      int t = ks * 32 + lk * 8 + j;
      wv[j] = __expf(lpE - lp[(rowB + t) * NH_ + h]);
    }
    bf16x8 af[2];
#pragma unroll
    for (int mf = 0; mf < 2; ++mf) {
      bf16x8 v = *(const bf16x8*)&VT[(vtbase + mf * 16 + lr) * 256 + ks * 32 + lk * 8];
#pragma unroll
      for (int j = 0; j < 8; ++j) af[mf][j] = f2b(b2f(v[j]) * wv[j]);
    }
#pragma unroll
    for (int nf = 0; nf < 4; ++nf) {
      bf16x8 bf = *(const bf16x8*)&BT[nf * 16 + lr][ks * 32 + lk * 8];
#pragma unroll
      for (int mf = 0; mf < 2; ++mf)
        acc[mf][nf] = __builtin_amdgcn_mfma_f32_16x16x32_bf16(af[mf], bf, acc[mf][nf], 0, 0, 0);
    }
  }
#pragma unroll
  for (int mf = 0; mf < 2; ++mf)
#pragma unroll
    for (int nf = 0; nf < 4; ++nf)
#pragma unroll
      for (int r = 0; r < 4; ++r) {
        int p = mf * 16 + lk * 4 + r, n = nf * 16 + lr;
        *state_ptr(zxbase, b, c, h, p * 64 + n) = acc[mf][nf][r];
      }
}

// ============================================================
// SSD p2: sequential prefix over chunks (state buffer becomes h_init[c])
// ============================================================
__global__ __launch_bounds__(512) void ec_scan_p2(
    float* __restrict__ zxbase, const float* __restrict__ Pc)
{
  const int h = blockIdx.x, b = blockIdx.y;
  const int tid = threadIdx.x;
  const int e = (tid >> 4) * 64 + (tid & 15) * 4;
  float h0 = 0.f, h1 = 0.f, h2 = 0.f, h3 = 0.f;
  for (int c = 0; c < NC_; ++c) {
    float* ptr = state_ptr(zxbase, b, c, h, e);
    float4 S = *(float4*)ptr;
    *(float4*)ptr = make_float4(h0, h1, h2, h3);
    float P = Pc[(b * NC_ + c) * NH_ + h];
    h0 = h0 * P + S.x;
    h1 = h1 * P + S.y;
    h2 = h2 * P + S.z;
    h3 = h3 * P + S.w;
  }
}

// ============================================================
// SSD p3 (MFMA, flash-like):
//   Y[t][p] = exp(lp_t)*(C_t @ hInit^T)[p]
//           + sum_{s<=t} exp(lp_t-lp_s)*(C_t.B_s)*dtx[s,p]  + D*x[t,p]
// ============================================================
__global__ __launch_bounds__(256) void ec_ssd_p3(
    const short* __restrict__ B16, const short* __restrict__ C16,
    const short* __restrict__ VT, const float* __restrict__ lp,
    const float* __restrict__ xBC, const float* __restrict__ Dp,
    float* __restrict__ zxbase, short* __restrict__ y16)
{
  const int h = blockIdx.x, c = blockIdx.y, b = blockIdx.z;
  const int tid = threadIdx.x;
  const int w = tid >> 6, l = tid & 63, lr = l & 15, lk = l >> 4;
  const size_t rowB = (size_t)b * LSEQ_ + (size_t)c * LC_;
  const size_t vtbase = (size_t)((b * NC_ + c) * NH_ + h) * 32;
  __shared__ short hI[32][72];
  __shared__ short Pl[4][64][72];

  for (int i = tid; i < 2048; i += 256)
    hI[i >> 6][i & 63] = f2b(*state_ptr(zxbase, b, c, h, i));
  __syncthreads();

  const int t0 = w * 64;
  bf16x8 cf[4][2];
#pragma unroll
  for (int tf = 0; tf < 4; ++tf)
#pragma unroll
    for (int ks = 0; ks < 2; ++ks)
      cf[tf][ks] = *(const bf16x8*)&C16[(rowB + t0 + tf * 16 + lr) * 64 + ks * 32 + lk * 8];

  // Y1 = C @ hInit^T
  f32x4 Y[4][2];
#pragma unroll
  for (int i = 0; i < 4; ++i)
#pragma unroll
    for (int j = 0; j < 2; ++j) Y[i][j] = f32x4{0.f, 0.f, 0.f, 0.f};
#pragma unroll
  for (int nf = 0; nf < 2; ++nf)
#pragma unroll
    for (int ks = 0; ks < 2; ++ks) {
      bf16x8 hf = *(const bf16x8*)&hI[nf * 16 + lr][ks * 32 + lk * 8];
#pragma unroll
      for (int mf = 0; mf < 4; ++mf)
        Y[mf][nf] = __builtin_amdgcn_mfma_f32_16x16x32_bf16(cf[mf][ks], hf, Y[mf][nf], 0, 0, 0);
    }
#pragma unroll
  for (int mf = 0; mf < 4; ++mf)
#pragma unroll
    for (int r = 0; r < 4; ++r) {
      float e = __expf(lp[(rowB + t0 + mf * 16 + lk * 4 + r) * NH_ + h]);
      Y[mf][0][r] *= e;
      Y[mf][1][r] *= e;
    }
  float tlp[4];
#pragma unroll
  for (int tf = 0; tf < 4; ++tf)
    tlp[tf] = lp[(rowB + t0 + tf * 16 + lr) * NH_ + h];

  for (int st = 0; st <= w; ++st) {
    const int s0 = st * 64;
#pragma unroll
    for (int half = 0; half < 2; ++half) {
      f32x4 ST[2][4];
#pragma unroll
      for (int i = 0; i < 2; ++i)
#pragma unroll
        for (int j = 0; j < 4; ++j) ST[i][j] = f32x4{0.f, 0.f, 0.f, 0.f};
#pragma unroll
      for (int sf2 = 0; sf2 < 2; ++sf2) {
        int sf = half * 2 + sf2;
#pragma unroll
        for (int ks = 0; ks < 2; ++ks) {
          bf16x8 bfr = *(const bf16x8*)&B16[(rowB + s0 + sf * 16 + lr) * 64 + ks * 32 + lk * 8];
#pragma unroll
          for (int tf = 0; tf < 4; ++tf)
            ST[sf2][tf] = __builtin_amdgcn_mfma_f32_16x16x32_bf16(bfr, cf[tf][ks], ST[sf2][tf], 0, 0, 0);
        }
      }
#pragma unroll
      for (int sf2 = 0; sf2 < 2; ++sf2) {
        int sf = half * 2 + sf2;
        float slp[4];
#pragma unroll
        for (int r = 0; r < 4; ++r)
          slp[r] = lp[(rowB + s0 + sf * 16 + lk * 4 + r) * NH_ + h];
#pragma unroll
        for (int tf = 0; tf < 4; ++tf) {
          float pv[4];
#pragma unroll
          for (int r = 0; r < 4; ++r) {
            pv[r] = ST[sf2][tf][r] * __expf(tlp[tf] - slp[r]);
            if (st == w && (sf * 16 + lk * 4 + r) > (tf * 16 + lr)) pv[r] = 0.f;
          }
          uint2 pk;
          pk.x = (unsigned)(unsigned short)f2b(pv[0]) | ((unsigned)(unsigned short)f2b(pv[1]) << 16);
          pk.y = (unsigned)(unsigned short)f2b(pv[2]) | ((unsigned)(unsigned short)f2b(pv[3]) << 16);
          *(uint2*)&Pl[w][tf * 16 + lr][sf * 16 + lk * 4] = pk;
        }
      }
    }
    // wave-private LDS write->read fence (rule #18)
    __builtin_amdgcn_sched_barrier(0);
    asm volatile("s_waitcnt lgkmcnt(0)" ::: "memory");
    __builtin_amdgcn_sched_barrier(0);
#pragma unroll
    for (int ks = 0; ks < 2; ++ks) {
      bf16x8 vf[2];
#pragma unroll
      for (int nf = 0; nf < 2; ++nf)
        vf[nf] = *(const bf16x8*)&VT[(vtbase + nf * 16 + lr) * 256 + s0 + ks * 32 + lk * 8];
#pragma unroll
      for (int mf = 0; mf < 4; ++mf) {
        bf16x8 pf = *(const bf16x8*)&Pl[w][mf * 16 + lr][ks * 32 + lk * 8];
#pragma unroll
        for (int nf = 0; nf < 2; ++nf)
          Y[mf][nf] = __builtin_amdgcn_mfma_f32_16x16x32_bf16(pf, vf[nf], Y[mf][nf], 0, 0, 0);
      }
    }
  }
  // epilogue with D*x: y16[row][h*32+p] = Y + D*x
  const float Dh = Dp[h];
#pragma unroll
  for (int mf = 0; mf < 4; ++mf)
#pragma unroll
    for (int r = 0; r < 4; ++r) {
      size_t yrow = rowB + t0 + mf * 16 + lk * 4 + r;
#pragma unroll
      for (int nf = 0; nf < 2; ++nf) {
        float xv = xBC[yrow * CONVD_ + h * 32 + nf * 16 + lr];
        y16[yrow * DIN_ + h * 32 + nf * 16 + lr] = f2b(Y[mf][nf][r] + Dh * xv);
      }
    }
}

// ============================================================
// t = y * silu(z); out = rmsnorm(t)*nw -> bf16 (row width 1024)
// (y16 already includes D*x)
// ============================================================
__global__ __launch_bounds__(256) void ec_gate_rms16(
    const short* __restrict__ y16, const float* __restrict__ zx,
    const float* __restrict__ nw, short* __restrict__ out)
{
  const int row = blockIdx.x;
  const short* yr = y16 + (size_t)row * DIN_;
  const float* zr = zx + (size_t)row * DPROJ_;
  float v[4]; float ss = 0.f;
#pragma unroll
  for (int j = 0; j < 4; ++j) {
    int cc = j * 256 + threadIdx.x;
    float t = b2f(yr[cc]) * siluf(zr[cc]);
    v[j] = t; ss += t * t;
  }
#pragma unroll
  for (int m = 32; m >= 1; m >>= 1) ss += __shfl_xor(ss, m, 64);
  __shared__ float buf[4];
  if ((threadIdx.x & 63) == 0) buf[threadIdx.x >> 6] = ss;
  __syncthreads();
  ss = buf[0] + buf[1] + buf[2] + buf[3];
  float scale = rsqrtf(ss / (float)DIN_ + 1e-5f);
#pragma unroll
  for (int j = 0; j < 4; ++j) {
    int cc = j * 256 + threadIdx.x;
    out[(size_t)row * DIN_ + cc] = f2b(v[j] * scale * nw[cc]);
  }
}

// ============================================================
// out = rmsnorm(a + b)*w -> fp32 + bf16 (row width 512)
// ============================================================
__global__ __launch_bounds__(128) void ec_rmsadd16(
    const float* __restrict__ a, const float* __restrict__ bres,
    const float* __restrict__ w, float* __restrict__ out, short* __restrict__ out16)
{
  const int row = blockIdx.x;
  const float* ar = a + (size_t)row * HID_;
  const float* br = bres + (size_t)row * HID_;
  float v[4]; float ss = 0.f;
#pragma unroll
  for (int j = 0; j < 4; ++j) {
    int c = j * 128 + threadIdx.x;
    float t = ar[c] + br[c];
    v[j] = t; ss += t * t;
  }
#pragma unroll
  for (int m = 32; m >= 1; m >>= 1) ss += __shfl_xor(ss, m, 64);
  __shared__ float buf[2];
  if ((threadIdx.x & 63) == 0) buf[threadIdx.x >> 6] = ss;
  __syncthreads();
  ss = buf[0] + buf[1];
  float scale = rsqrtf(ss / (float)HID_ + 1e-5f);
#pragma unroll
  for (int j = 0; j < 4; ++j) {
    int c = j * 128 + threadIdx.x;
    float o = v[j] * scale * w[c];
    out[(size_t)row * HID_ + c] = o;
    out16[(size_t)row * HID_ + c] = f2b(o);
  }
}

// ============================================================
// layernorm(in)*w + b -> fp32 (+ optional bf16) (row width 512)
// ============================================================
__global__ __launch_bounds__(128) void ec_ln16(
    const float* __restrict__ in, const float* __restrict__ w,
    const float* __restrict__ bb, float* __restrict__ out, short* __restrict__ out16)
{
  const int row = blockIdx.x;
  const float* ir = in + (size_t)row * HID_;
  float v[4]; float s = 0.f, s2 = 0.f;
#pragma unroll
  for (int j = 0; j < 4; ++j) {
    int c = j * 128 + threadIdx.x;
    float t = ir[c];
    v[j] = t; s += t; s2 += t * t;
  }
#pragma unroll
  for (int m = 32; m >= 1; m >>= 1) { s += __shfl_xor(s, m, 64); s2 += __shfl_xor(s2, m, 64); }
  __shared__ float buf[4];
  if ((threadIdx.x & 63) == 0) { int wi = threadIdx.x >> 6; buf[wi * 2] = s; buf[wi * 2 + 1] = s2; }
  __syncthreads();
  s = buf[0] + buf[2]; s2 = buf[1] + buf[3];
  float mean = s / (float)HID_;
  float var = s2 / (float)HID_ - mean * mean;
  float inv = rsqrtf(var + 1e-5f);
#pragma unroll
  for (int j = 0; j < 4; ++j) {
    int c = j * 128 + threadIdx.x;
    float o = (v[j] - mean) * inv * w[c] + bb[c];
    out[(size_t)row * HID_ + c] = o;
    if (out16) out16[(size_t)row * HID_ + c] = f2b(o);
  }
}

// ============================================================
// MFMA flash attention: qkv bf16 [B*LT,1536] -> out bf16 [B*LT,512]
// ============================================================
__global__ __launch_bounds__(256) void ec_attn16(
    const short* __restrict__ qkv, short* __restrict__ out)
{
  const int b = blockIdx.z, h = blockIdx.y, qt = blockIdx.x;
  __shared__ short Kl[64 * 68];
  __shared__ short Vl[64 * 68];
  __shared__ short Pl[64 * 68];
  const int tid = threadIdx.x;
  const int l = tid & 63, w = tid >> 6;
  const int lr = l & 15, lk = l >> 4;

  const size_t qrow = (size_t)b * LT_ + qt * 64 + w * 16 + lr;
  bf16x8 qf[2];
  qf[0] = *(const bf16x8*)&qkv[qrow * 1536 + h * HD_ + lk * 8];
  qf[1] = *(const bf16x8*)&qkv[qrow * 1536 + h * HD_ + lk * 8 + 32];

  float mrun[4] = {-INFINITY, -INFINITY, -INFINITY, -INFINITY};
  float lsum[4] = {0.f, 0.f, 0.f, 0.f};
  f32x4 O[4];
#pragma unroll
  for (int df = 0; df < 4; ++df) O[df] = f32x4{0.f, 0.f, 0.f, 0.f};

  const int krow = tid >> 2, kcg = (tid & 3) * 16;
  const int vd = tid & 63, vw = tid >> 6;

  for (int kt = 0; kt < LT_ / 64; ++kt) {
    const size_t krbase = (size_t)b * LT_ + kt * 64;
    {
      const short* kp = &qkv[(krbase + krow) * 1536 + HID_ + h * HD_ + kcg];
      *(bf16x8*)&Kl[krow * 68 + kcg] = *(const bf16x8*)kp;
      *(bf16x8*)&Kl[krow * 68 + kcg + 8] = *(const bf16x8*)(kp + 8);
    }
#pragma unroll
    for (int kk = 0; kk < 4; ++kk) {
      int key0 = vw * 16 + kk * 4;
      s16x4 pk;
#pragma unroll
      for (int j = 0; j < 4; ++j)
        pk[j] = qkv[(krbase + key0 + j) * 1536 + 2 * HID_ + h * HD_ + vd];
      *(s16x4*)&Vl[vd * 68 + key0] = pk;
    }
    __syncthreads();

    f32x4 S[4];
#pragma unroll
    for (int nf = 0; nf < 4; ++nf) S[nf] = f32x4{0.f, 0.f, 0.f, 0.f};
#pragma unroll
    for (int ks = 0; ks < 2; ++ks)
#pragma unroll
      for (int nf = 0; nf < 4; ++nf) {
        bf16x8 kb = *(const bf16x8*)&Kl[(nf * 16 + lr) * 68 + ks * 32 + lk * 8];
        S[nf] = __builtin_amdgcn_mfma_f32_16x16x32_bf16(qf[ks], kb, S[nf], 0, 0, 0);
      }

    float fr[4];
#pragma unroll
    for (int r = 0; r < 4; ++r) {
      float mt = fmaxf(fmaxf(S[0][r], S[1][r]), fmaxf(S[2][r], S[3][r])) * 0.125f;
      mt = fmaxf(mt, __shfl_xor(mt, 1));
      mt = fmaxf(mt, __shfl_xor(mt, 2));
      mt = fmaxf(mt, __shfl_xor(mt, 4));
      mt = fmaxf(mt, __shfl_xor(mt, 8));
      float mn = fmaxf(mrun[r], mt);
      fr[r] = __expf(mrun[r] - mn);
      mrun[r] = mn;
      lsum[r] *= fr[r];
    }
#pragma unroll
    for (int nf = 0; nf < 4; ++nf)
#pragma unroll
      for (int r = 0; r < 4; ++r) {
        float p = __expf(S[nf][r] * 0.125f - mrun[r]);
        lsum[r] += p;
        Pl[(w * 16 + lk * 4 + r) * 68 + nf * 16 + lr] = f2b(p);
      }
#pragma unroll
    for (int df = 0; df < 4; ++df) {
      O[df][0] *= fr[0]; O[df][1] *= fr[1]; O[df][2] *= fr[2]; O[df][3] *= fr[3];
    }

#pragma unroll
    for (int ks = 0; ks < 2; ++ks) {
      bf16x8 pa = *(const bf16x8*)&Pl[(w * 16 + lr) * 68 + ks * 32 + lk * 8];
#pragma unroll
      for (int df = 0; df < 4; ++df) {
        bf16x8 vb = *(const bf16x8*)&Vl[(df * 16 + lr) * 68 + ks * 32 + lk * 8];
        O[df] = __builtin_amdgcn_mfma_f32_16x16x32_bf16(pa, vb, O[df], 0, 0, 0);
      }
    }
    __syncthreads();
  }

#pragma unroll
  for (int r = 0; r < 4; ++r) {
    lsum[r] += __shfl_xor(lsum[r], 1);
    lsum[r] += __shfl_xor(lsum[r], 2);
    lsum[r] += __shfl_xor(lsum[r], 4);
    lsum[r] += __shfl_xor(lsum[r], 8);
    lsum[r] = 1.f / lsum[r];
  }
  const size_t orow0 = (size_t)b * LT_ + qt * 64 + w * 16;
#pragma unroll
  for (int df = 0; df < 4; ++df)
#pragma unroll
    for (int r = 0; r < 4; ++r)
      out[(orow0 + lk * 4 + r) * HID_ + h * HD_ + df * 16 + lr] = f2b(O[df][r] * lsum[r]);
}

// ============================================================
// host launch
// ============================================================
extern "C" void kernel_launch(void* const* d_in, const int* in_sizes, int n_in,
                              void* d_out, int out_size, void* d_ws, size_t ws_size,
                              hipStream_t stream)
{
  const float* x_in   = (const float*)d_in[0];
  const float* Wp     = (const float*)d_in[1];
  const float* bp     = (const float*)d_in[2];
  const float* m_Wi[2]   = {(const float*)d_in[3],  (const float*)d_in[11]};
  const float* m_cw[2]   = {(const float*)d_in[4],  (const float*)d_in[12]};
  const float* m_cb[2]   = {(const float*)d_in[5],  (const float*)d_in[13]};
  const float* m_dtb[2]  = {(const float*)d_in[6],  (const float*)d_in[14]};
  const float* m_Alog[2] = {(const float*)d_in[7],  (const float*)d_in[15]};
  const float* m_D[2]    = {(const float*)d_in[8],  (const float*)d_in[16]};
  const float* m_nw[2]   = {(const float*)d_in[9],  (const float*)d_in[17]};
  const float* m_Wo[2]   = {(const float*)d_in[10], (const float*)d_in[18]};
  const float* n_w[2]    = {(const float*)d_in[19], (const float*)d_in[20]};
  const float* ds_w   = (const float*)d_in[21];
  const float* ds_b   = (const float*)d_in[22];
  const float* t_Wqkv = (const float*)d_in[23];
  const float* t_bqkv = (const float*)d_in[24];
  const float* t_Wo   = (const float*)d_in[25];
  const float* t_bo   = (const float*)d_in[26];
  const float* t_W1   = (const float*)d_in[27];
  const float* t_b1   = (const float*)d_in[28];
  const float* t_W2   = (const float*)d_in[29];
  const float* t_b2   = (const float*)d_in[30];
  const float* t_ln1w = (const float*)d_in[31];
  const float* t_ln1b = (const float*)d_in[32];
  const float* t_ln2w = (const float*)d_in[33];
  const float* t_ln2b = (const float*)d_in[34];
  const float* on_w   = (const float*)d_in[35];
  const float* on_b   = (const float*)d_in[36];

  char* ws = (char*)d_ws;
  float* bx    = (float*)(ws + 0);            // [8192,512] f32 residual
  float* bzx   = (float*)(ws + 16777216);     // [8192,2208] f32 zxbcdt (+ state dead-cols)
  float* bxbc  = (float*)(ws + 89128960);     // [8192,1152] f32 xBC
  short* y16   = (short*)(ws + 126877696);    // [8192,1024] bf16 scan y
  short* VT    = (short*)(ws + 143654912);    // [b,c,h][32][256] bf16 dtx^T
  float* lp    = (float*)(ws + 160432128);    // [8192,32] log-decay prefix
  float* dts   = (float*)(ws + 161480704);    // [8192,32] dt
  short* wslot = (short*)(ws + 162529280);    // bf16 weight slot / B16+C16 during scan
  float* Pc    = (float*)(ws + 165150720);

  short* B16 = wslot;                          // [8192,64] bf16 (scan window only)
  short* C16 = wslot + 524288;                 // [8192,64]
  float* byf = (float*)(ws + 126877696);       // out-proj f32 out (over dead y16)

  short* x16     = (short*)(ws + 126877696);   // input bf16 (dead before p3)
  short* bx16    = (short*)bxbc;               // residual bf16
  short* gated16 = (short*)((char*)bxbc + 8388608);

  short* ds16  = (short*)bzx;
  float* dsf   = (float*)((char*)bzx + 4194304);
  short* qkv16 = (short*)((char*)bzx + 12582912);
  short* att16 = (short*)((char*)bzx + 25165824);
  float* bt1   = (float*)((char*)bzx + 29360128);
  short* ln116 = (short*)((char*)bzx + 37748736);
  float* bxt2  = (float*)((char*)bzx + 41943040);
  short* ff16  = (short*)((char*)bzx + 50331648);
  float* bt2   = (float*)((char*)bzx + 58720256);
  float* bxt3  = (float*)bxbc;

  const int MR = BB_ * LSEQ_;  // 8192
  const int MT = BB_ * LT_;    // 4096

  // input projection
  ec_f2b<<<(MR * 1024 / 8 + 255) / 256, 256, 0, stream>>>(x_in, x16, MR * 1024 / 8);
  ec_w2bt<<<dim3(1024 / 32, 512 / 32), 256, 0, stream>>>(Wp, wslot, 1024, 512);
  gemm16(stream, x16, wslot, bp, nullptr, bx, bx16, MR, HID_, 1024, 0);

  for (int blk = 0; blk < 2; ++blk) {
    ec_w2bt<<<dim3(512 / 32, 2208 / 32), 256, 0, stream>>>(m_Wi[blk], wslot, 512, 2208);
    gemm16(stream, bx16, wslot, nullptr, nullptr, bzx, nullptr, MR, DPROJ_, HID_, 0);
    ec_conv1d_silu<<<(MR * CONVD_ + 255) / 256, 256, 0, stream>>>(bzx, m_cw[blk], m_cb[blk], bxbc);
    ec_ssd_cumsum<<<dim3(NC_, BB_), 256, 0, stream>>>(bzx, m_dtb[blk], m_Alog[blk], dts, lp, Pc);
    ec_bc16<<<(MR * 128 + 255) / 256, 256, 0, stream>>>(bxbc, B16, C16);
    ec_vt<<<dim3(NH_, NC_, BB_), 64, 0, stream>>>(bxbc, dts, VT);
    ec_ssd_p1<<<dim3(NH_, NC_, BB_), 64, 0, stream>>>(B16, VT, lp, bzx);
    ec_scan_p2<<<dim3(NH_, BB_), 512, 0, stream>>>(bzx, Pc);
    ec_ssd_p3<<<dim3(NH_, NC_, BB_), 256, 0, stream>>>(B16, C16, VT, lp, bxbc, m_D[blk], bzx, y16);
    ec_gate_rms16<<<MR, 256, 0, stream>>>(y16, bzx, m_nw[blk], gated16);
    ec_w2bt<<<dim3(1024 / 32, 512 / 32), 256, 0, stream>>>(m_Wo[blk], wslot, 1024, 512);
    gemm16(stream, gated16, wslot, nullptr, nullptr, byf, nullptr, MR, HID_, DIN_, 0);
    ec_rmsadd16<<<MR, 128, 0, stream>>>(byf, bx, n_w[blk], bx, bx16);
  }

  // downsample conv as implicit-im2col GEMM
  ec_dswt<<<(HID_ * 1536 + 255) / 256, 256, 0, stream>>>(ds_w, wslot);
  {
    dim3 g(512 / 128, LT_ / 128, BB_), b(256);
    ec_gemm16<<<g, b, 0, stream>>>(bx16 - 512, wslot, ds_b, nullptr, dsf, ds16,
                                   LT_, HID_, 1536, 0, 1024, (long)LSEQ_ * HID_, LT_);
  }
  ec_dsfix<<<BB_, 512, 0, stream>>>(bx16, wslot, ds_b, dsf, ds16);

  // transformer layer
  ec_w2bt<<<dim3(512 / 32, 1536 / 32), 256, 0, stream>>>(t_Wqkv, wslot, 512, 1536);
  gemm16(stream, ds16, wslot, t_bqkv, nullptr, nullptr, qkv16, MT, 3 * HID_, HID_, 0);
  ec_attn16<<<dim3(LT_ / 64, NHEAD_, BB_), 256, 0, stream>>>(qkv16, att16);
  ec_w2bt<<<dim3(512 / 32, 512 / 32), 256, 0, stream>>>(t_Wo, wslot, 512, 512);
  gemm16(stream, att16, wslot, t_bo, dsf, bt1, nullptr, MT, HID_, HID_, 0);
  ec_ln16<<<MT, 128, 0, stream>>>(bt1, t_ln1w, t_ln1b, bxt2, ln116);
  ec_w2bt<<<dim3(512 / 32, 1024 / 32), 256, 0, stream>>>(t_W1, wslot, 512, 1024);
  gemm16(stream, ln116, wslot, t_b1, nullptr, nullptr, ff16, MT, DFF_, HID_, 1);
  ec_w2bt<<<dim3(1024 / 32, 512 / 32), 256, 0, stream>>>(t_W2, wslot, 1024, 512);
  gemm16(stream, ff16, wslot, t_b2, bxt2, bt2, nullptr, MT, HID_, DFF_, 0);
  ec_ln16<<<MT, 128, 0, stream>>>(bt2, t_ln2w, t_ln2b, bxt3, nullptr);
  ec_ln16<<<MT, 128, 0, stream>>>(bxt3, on_w, on_b, (float*)d_out, nullptr);
}

// Round 7
// 903.596 us; speedup vs baseline: 7.0602x; 1.1599x over previous
//
#include <hip/hip_runtime.h>
#include <math.h>

// ---- model dims ----
#define DIN_   1024
#define DSTATE_ 64
#define NH_    32
#define HDIM_  32
#define CONVD_ 1152   // DIN + 2*DSTATE
#define DPROJ_ 2208   // 2*DIN + 2*DSTATE + NH
#define HID_   512
#define LSEQ_  4096
#define BB_    2
#define LT_    2048   // after stride-2 downsample
#define NHEAD_ 8
#define HD_    64     // head dim = 512/8
#define DFF_   1024
#define LC_    256    // scan chunk length
#define NC_    16     // number of chunks (LSEQ_/LC_)

typedef __attribute__((ext_vector_type(8))) short bf16x8;
typedef __attribute__((ext_vector_type(4))) short s16x4;
typedef __attribute__((ext_vector_type(4))) float f32x4;

__device__ __forceinline__ float siluf(float x) { return x / (1.f + expf(-x)); }

__device__ __forceinline__ short f2b(float f) {
  union { float f; unsigned u; } v; v.f = f;
  unsigned r = (v.u + 0x7fffu + ((v.u >> 16) & 1u)) >> 16;
  return (short)r;
}

__device__ __forceinline__ float b2f(short s) {
  union { unsigned u; float f; } v; v.u = ((unsigned)(unsigned short)s) << 16;
  return v.f;
}

// async global->LDS 16B per lane; lds base must be wave-uniform
__device__ __forceinline__ void gload16(const short* g, short* lds_base) {
#if __has_builtin(__builtin_amdgcn_global_load_lds)
  __builtin_amdgcn_global_load_lds((const __attribute__((address_space(1))) void*)g,
                                   (__attribute__((address_space(3))) void*)lds_base, 16, 0, 0);
#else
  int l = threadIdx.x & 63;
  ((bf16x8*)lds_base)[l] = *(const bf16x8*)g;
#endif
}

// ============================================================
// fp32 -> bf16 elementwise (8 per thread)
// ============================================================
__global__ void ec_f2b(const float* __restrict__ in, short* __restrict__ out, int n8)
{
  int i = blockIdx.x * 256 + threadIdx.x;
  if (i >= n8) return;
  const float4* p = (const float4*)(in + (size_t)i * 8);
  float4 a = p[0], b = p[1];
  bf16x8 o;
  o[0] = f2b(a.x); o[1] = f2b(a.y); o[2] = f2b(a.z); o[3] = f2b(a.w);
  o[4] = f2b(b.x); o[5] = f2b(b.y); o[6] = f2b(b.z); o[7] = f2b(b.w);
  *(bf16x8*)(out + (size_t)i * 8) = o;
}

// ============================================================
// weight convert+transpose: W fp32 [K,N] -> Wt bf16 [N,K]
// ============================================================
__global__ __launch_bounds__(256) void ec_w2bt(const float* __restrict__ W,
                                               short* __restrict__ Wt, int K, int N)
{
  __shared__ float t[32][33];
  int k0 = blockIdx.x * 32, n0 = blockIdx.y * 32;
  int tx = threadIdx.x & 31, ty = threadIdx.x >> 5;
#pragma unroll
  for (int i = 0; i < 32; i += 8) t[ty + i][tx] = W[(size_t)(k0 + ty + i) * N + n0 + tx];
  __syncthreads();
#pragma unroll
  for (int i = 0; i < 32; i += 8) Wt[(size_t)(n0 + ty + i) * K + k0 + tx] = f2b(t[tx][ty + i]);
}

// ============================================================
// ds_w (O,I,K=3) -> Wt bf16 [O, K*512] with layout Wt[o][k*512+i]
// ============================================================
__global__ void ec_dswt(const float* __restrict__ w, short* __restrict__ wt)
{
  int idx = blockIdx.x * 256 + threadIdx.x;
  if (idx >= HID_ * 1536) return;
  int o = idx / 1536, r = idx % 1536;
  int k = r >> 9, i = r & 511;
  wt[idx] = f2b(w[((size_t)o * HID_ + i) * 3 + k]);
}

// ============================================================
// bf16 MFMA GEMM: C = act(A[M,K] @ W + bias) + res, W given as Wt bf16 [N,K]
// 128x128 tile, 4 waves, 4x4 16x16x32 frags, BK=32, double-buffered LDS.
// ============================================================
__global__ __launch_bounds__(256) void ec_gemm16(
    const short* __restrict__ A, const short* __restrict__ Wt,
    const float* __restrict__ bias, const float* __restrict__ res,
    float* __restrict__ Cf, short* __restrict__ Ch,
    int M, int N, int K, int act, int lda, long Az, int Mz)
{
  __shared__ short As_[2][4096];
  __shared__ short Bs_[2][4096];
  A += (size_t)blockIdx.z * Az;
  const int mz = blockIdx.z * Mz;
  const int tid = threadIdx.x;
  const int l = tid & 63, w = tid >> 6;
  const int m0 = blockIdx.y * 128, n0 = blockIdx.x * 128;
  const int wm = (w >> 1) * 64, wn = (w & 1) * 64;
  const int lr = l & 15, lk = l >> 4;
  const int arow = l >> 2, acol = (l & 3) * 8;

  f32x4 acc[4][4];
#pragma unroll
  for (int i = 0; i < 4; ++i)
#pragma unroll
    for (int j = 0; j < 4; ++j) acc[i][j] = f32x4{0.f, 0.f, 0.f, 0.f};

#pragma unroll
  for (int cc = 0; cc < 2; ++cc) {
    int c = w * 2 + cc;
    const short* ga = A + (size_t)(m0 + c * 16 + arow) * lda + acol;
    int rb = n0 + c * 16 + arow; if (rb > N - 1) rb = N - 1;
    const short* gb = Wt + (size_t)rb * K + acol;
    gload16(ga, &As_[0][c * 512]);
    gload16(gb, &Bs_[0][c * 512]);
  }

  const int KT = K >> 5;
  for (int kt = 0; kt < KT; ++kt) {
    __syncthreads();
    if (kt + 1 < KT) {
      int k0 = (kt + 1) << 5;
      int nb = (kt + 1) & 1;
#pragma unroll
      for (int cc = 0; cc < 2; ++cc) {
        int c = w * 2 + cc;
        const short* ga = A + (size_t)(m0 + c * 16 + arow) * lda + k0 + acol;
        int rb = n0 + c * 16 + arow; if (rb > N - 1) rb = N - 1;
        const short* gb = Wt + (size_t)rb * K + k0 + acol;
        gload16(ga, &As_[nb][c * 512]);
        gload16(gb, &Bs_[nb][c * 512]);
      }
    }
    int cb = kt & 1;
    bf16x8 af[4], bfv[4];
#pragma unroll
    for (int mf = 0; mf < 4; ++mf)
      af[mf] = *(const bf16x8*)&As_[cb][(wm + mf * 16 + lr) * 32 + lk * 8];
#pragma unroll
    for (int nf = 0; nf < 4; ++nf)
      bfv[nf] = *(const bf16x8*)&Bs_[cb][(wn + nf * 16 + lr) * 32 + lk * 8];
#pragma unroll
    for (int mf = 0; mf < 4; ++mf)
#pragma unroll
      for (int nf = 0; nf < 4; ++nf)
        acc[mf][nf] = __builtin_amdgcn_mfma_f32_16x16x32_bf16(af[mf], bfv[nf], acc[mf][nf], 0, 0, 0);
  }

#pragma unroll
  for (int mf = 0; mf < 4; ++mf)
#pragma unroll
    for (int nf = 0; nf < 4; ++nf)
#pragma unroll
      for (int r = 0; r < 4; ++r) {
        int m = mz + m0 + wm + mf * 16 + lk * 4 + r;
        int n = n0 + wn + nf * 16 + lr;
        if (n < N) {
          float v = acc[mf][nf][r];
          if (bias) v += bias[n];
          if (act == 1) v = 0.5f * v * (1.f + erff(v * 0.70710678118f));
          if (res) v += res[(size_t)m * N + n];
          if (Cf) Cf[(size_t)m * N + n] = v;
          if (Ch) Ch[(size_t)m * N + n] = f2b(v);
        }
      }
}

static inline void gemm16(hipStream_t s, const short* A, const short* Wt, const float* bias,
                          const float* res, float* Cf, short* Ch, int M, int N, int K, int act) {
  dim3 g((N + 127) / 128, M / 128), b(256);
  ec_gemm16<<<g, b, 0, s>>>(A, Wt, bias, res, Cf, Ch, M, N, K, act, K, 0, 0);
}

// fixup for dsconv GEMM boundary rows (lo=0 per batch)
__global__ __launch_bounds__(512) void ec_dsfix(
    const short* __restrict__ x16, const short* __restrict__ wt,
    const float* __restrict__ bias, float* __restrict__ dsf, short* __restrict__ ds16)
{
  const int b = blockIdx.x, o = threadIdx.x;
  float v = bias[o];
#pragma unroll
  for (int k = 1; k < 3; ++k) {
    const short* xr = x16 + ((size_t)b * LSEQ_ + (k - 1)) * HID_;
    const short* wr = wt + (size_t)o * 1536 + k * 512;
    for (int i = 0; i < 512; ++i) v += b2f(xr[i]) * b2f(wr[i]);
  }
  dsf[(size_t)b * LT_ * HID_ + o] = v;
  ds16[(size_t)b * LT_ * HID_ + o] = f2b(v);
}

// ============================================================
// Depthwise causal conv (DCONV=4) + SiLU on the xBC slice of zxbcdt.
// ============================================================
__global__ void ec_conv1d_silu(const float* __restrict__ zx, const float* __restrict__ cw,
                               const float* __restrict__ cb, float* __restrict__ xBC)
{
  int idx = blockIdx.x * 256 + threadIdx.x;
  const int total = BB_ * LSEQ_ * CONVD_;
  if (idx >= total) return;
  int c = idx % CONVD_;
  int l = (idx / CONVD_) % LSEQ_;
  int b = idx / (CONVD_ * LSEQ_);
  const float* base = zx + (size_t)b * LSEQ_ * DPROJ_ + DIN_ + c;
  float s = cb[c];
#pragma unroll
  for (int j = 0; j < 4; ++j) {
    int ll = l - 3 + j;
    if (ll >= 0) s += base[(size_t)ll * DPROJ_] * cw[c * 4 + j];
  }
  xBC[idx] = siluf(s);
}

// ============================================================
// SSD prep 1: per-chunk softplus(dt)+cumsum -> dts, lp, Pc
// grid (NC_, BB_, NH_/8), block 256 (thread = t); 8 heads per block.
// Wave-level shuffle scan (6 steps) + one cross-wave LDS combine.
// ============================================================
__global__ __launch_bounds__(256) void ec_ssd_cumsum(
    const float* __restrict__ zx, const float* __restrict__ dtb,
    const float* __restrict__ Alog, float* __restrict__ dts,
    float* __restrict__ lp, float* __restrict__ Pc)
{
  const int c = blockIdx.x, b = blockIdx.y, hg = blockIdx.z;
  const int t = threadIdx.x;
  const int lane = t & 63, wv = t >> 6;
  const size_t row = (size_t)b * LSEQ_ + (size_t)c * LC_ + t;
  const int h0 = hg * 8;
  __shared__ float wsum[4][8];

  const float* dp = zx + row * DPROJ_ + (DIN_ + CONVD_) + h0;
  float4 d0 = *(const float4*)dp;
  float4 d1 = *(const float4*)(dp + 4);
  float dt[8], cs[8];
  {
    float xv[8] = {d0.x, d0.y, d0.z, d0.w, d1.x, d1.y, d1.z, d1.w};
#pragma unroll
    for (int j = 0; j < 8; ++j) {
      float x = xv[j] + dtb[h0 + j];
      float sp = (x > 20.f) ? x : log1pf(expf(x));
      dt[j] = sp;
      cs[j] = sp;
    }
  }
  // wave inclusive scan over 64 lanes
#pragma unroll
  for (int d = 1; d < 64; d <<= 1) {
#pragma unroll
    for (int j = 0; j < 8; ++j) {
      float o = __shfl_up(cs[j], d, 64);
      if (lane >= d) cs[j] += o;
    }
  }
  if (lane == 63)
#pragma unroll
    for (int j = 0; j < 8; ++j) wsum[wv][j] = cs[j];
  __syncthreads();
#pragma unroll
  for (int j = 0; j < 8; ++j) {
    float base = 0.f;
#pragma unroll
    for (int k = 0; k < 3; ++k) if (k < wv) base += wsum[k][j];
    cs[j] += base;
  }
#pragma unroll
  for (int j = 0; j < 8; ++j) {
    int h = h0 + j;
    float lpv = -expf(Alog[h]) * cs[j];
    dts[row * NH_ + h] = dt[j];
    lp[row * NH_ + h] = lpv;
    if (t == LC_ - 1) Pc[(b * NC_ + c) * NH_ + h] = expf(lpv);
  }
}

// ============================================================
// SSD prep 2: xBC B/C slices -> bf16
// ============================================================
__global__ void ec_bc16(const float* __restrict__ xBC, short* __restrict__ B16,
                        short* __restrict__ C16)
{
  int idx = blockIdx.x * 256 + threadIdx.x;
  if (idx >= BB_ * LSEQ_ * 128) return;
  int row = idx >> 7, col = idx & 127;
  float v = xBC[(size_t)row * CONVD_ + DIN_ + col];
  if (col < 64) B16[(size_t)row * 64 + col] = f2b(v);
  else          C16[(size_t)row * 64 + col - 64] = f2b(v);
}

// ============================================================
// SSD prep 3: VT[b,c,h][p][t] = bf16( dt[t,h] * x[t, h*32+p] )
// ============================================================
__global__ __launch_bounds__(64) void ec_vt(
    const float* __restrict__ xBC, const float* __restrict__ dts, short* __restrict__ VT)
{
  const int h = blockIdx.x, c = blockIdx.y, b = blockIdx.z;
  const int l = threadIdx.x;
  const size_t rowB = (size_t)b * LSEQ_ + (size_t)c * LC_;
  const size_t vtbase = (size_t)((b * NC_ + c) * NH_ + h) * 32;
  __shared__ float tile[32][33];
  for (int tt = 0; tt < 8; ++tt) {
#pragma unroll
    for (int i = 0; i < 16; ++i) {
      int r = i * 2 + (l >> 5);
      size_t row = rowB + tt * 32 + r;
      tile[r][l & 31] = xBC[row * CONVD_ + h * 32 + (l & 31)] * dts[row * NH_ + h];
    }
    __syncthreads();
#pragma unroll
    for (int j = 0; j < 16; ++j) {
      int p = j * 2 + (l >> 5);
      VT[(vtbase + p) * 256 + tt * 32 + (l & 31)] = f2b(tile[l & 31][p]);
    }
    __syncthreads();
  }
}

// ============================================================
// state lives in dead cols [DIN_, DIN_+1024) of zxbcdt rows 0..2047
// ============================================================
__device__ __forceinline__ float* state_ptr(float* zxbase, int b, int c, int h, int e)
{
  int R = ((b * NC_ + c) * NH_ + h) * 2 + (e >> 10);
  return zxbase + (size_t)R * DPROJ_ + DIN_ + (e & 1023);
}

// ============================================================
// SSD p1 (MFMA): chunk state S[p][n] = sum_t exp(lpEnd-lp_t)*dtx[t,p]*B[t,n]
// ============================================================
__global__ __launch_bounds__(64) void ec_ssd_p1(
    const short* __restrict__ B16, const short* __restrict__ VT,
    const float* __restrict__ lp, float* __restrict__ zxbase)
{
  const int h = blockIdx.x, c = blockIdx.y, b = blockIdx.z;
  const int l = threadIdx.x, lr = l & 15, lk = l >> 4;
  const size_t rowB = (size_t)b * LSEQ_ + (size_t)c * LC_;
  const size_t vtbase = (size_t)((b * NC_ + c) * NH_ + h) * 32;
  __shared__ short BT[64][264];   // B^T [n][t]
  for (int i = 0; i < 4; ++i) {
    int t = i * 64 + l;
#pragma unroll
    for (int g = 0; g < 8; ++g) {
      bf16x8 v = *(const bf16x8*)&B16[(rowB + t) * 64 + g * 8];
#pragma unroll
      for (int j = 0; j < 8; ++j) BT[g * 8 + j][t] = v[j];
    }
  }
  __syncthreads();
  const float lpE = lp[(rowB + LC_ - 1) * NH_ + h];
  f32x4 acc[2][4];
#pragma unroll
  for (int i = 0; i < 2; ++i)
#pragma unroll
    for (int j = 0; j < 4; ++j) acc[i][j] = f32x4{0.f, 0.f, 0.f, 0.f};

  for (int ks = 0; ks < 8; ++ks) {
    float wv[8];
#pragma unroll
    for (int j = 0; j < 8; ++j) {
      int t = ks * 32 + lk * 8 + j;
      wv[j] = __expf(lpE - lp[(rowB + t) * NH_ + h]);
    }
    bf16x8 af[2];
#pragma unroll
    for (int mf = 0; mf < 2; ++mf) {
      bf16x8 v = *(const bf16x8*)&VT[(vtbase + mf * 16 + lr) * 256 + ks * 32 + lk * 8];
#pragma unroll
      for (int j = 0; j < 8; ++j) af[mf][j] = f2b(b2f(v[j]) * wv[j]);
    }
#pragma unroll
    for (int nf = 0; nf < 4; ++nf) {
      bf16x8 bf = *(const bf16x8*)&BT[nf * 16 + lr][ks * 32 + lk * 8];
#pragma unroll
      for (int mf = 0; mf < 2; ++mf)
        acc[mf][nf] = __builtin_amdgcn_mfma_f32_16x16x32_bf16(af[mf], bf, acc[mf][nf], 0, 0, 0);
    }
  }
#pragma unroll
  for (int mf = 0; mf < 2; ++mf)
#pragma unroll
    for (int nf = 0; nf < 4; ++nf)
#pragma unroll
      for (int r = 0; r < 4; ++r) {
        int p = mf * 16 + lk * 4 + r, n = nf * 16 + lr;
        *state_ptr(zxbase, b, c, h, p * 64 + n) = acc[mf][nf][r];
      }
}

// ============================================================
// SSD p2: sequential prefix over chunks (state buffer becomes h_init[c])
// ============================================================
__global__ __launch_bounds__(512) void ec_scan_p2(
    float* __restrict__ zxbase, const float* __restrict__ Pc)
{
  const int h = blockIdx.x, b = blockIdx.y;
  const int tid = threadIdx.x;
  const int e = (tid >> 4) * 64 + (tid & 15) * 4;
  float h0 = 0.f, h1 = 0.f, h2 = 0.f, h3 = 0.f;
  for (int c = 0; c < NC_; ++c) {
    float* ptr = state_ptr(zxbase, b, c, h, e);
    float4 S = *(float4*)ptr;
    *(float4*)ptr = make_float4(h0, h1, h2, h3);
    float P = Pc[(b * NC_ + c) * NH_ + h];
    h0 = h0 * P + S.x;
    h1 = h1 * P + S.y;
    h2 = h2 * P + S.z;
    h3 = h3 * P + S.w;
  }
}

// ============================================================
// SSD p3 (MFMA, flash-like):
//   Y[t][p] = exp(lp_t)*(C_t @ hInit^T)[p]
//           + sum_{s<=t} exp(lp_t-lp_s)*(C_t.B_s)*dtx[s,p]  + D*x[t,p]
// ============================================================
__global__ __launch_bounds__(256) void ec_ssd_p3(
    const short* __restrict__ B16, const short* __restrict__ C16,
    const short* __restrict__ VT, const float* __restrict__ lp,
    const float* __restrict__ xBC, const float* __restrict__ Dp,
    float* __restrict__ zxbase, short* __restrict__ y16)
{
  const int h = blockIdx.x, c = blockIdx.y, b = blockIdx.z;
  const int tid = threadIdx.x;
  const int w = tid >> 6, l = tid & 63, lr = l & 15, lk = l >> 4;
  const size_t rowB = (size_t)b * LSEQ_ + (size_t)c * LC_;
  const size_t vtbase = (size_t)((b * NC_ + c) * NH_ + h) * 32;
  __shared__ short hI[32][72];
  __shared__ short Pl[4][64][72];

  for (int i = tid; i < 2048; i += 256)
    hI[i >> 6][i & 63] = f2b(*state_ptr(zxbase, b, c, h, i));
  __syncthreads();

  const int t0 = w * 64;
  bf16x8 cf[4][2];
#pragma unroll
  for (int tf = 0; tf < 4; ++tf)
#pragma unroll
    for (int ks = 0; ks < 2; ++ks)
      cf[tf][ks] = *(const bf16x8*)&C16[(rowB + t0 + tf * 16 + lr) * 64 + ks * 32 + lk * 8];

  // Y1 = C @ hInit^T
  f32x4 Y[4][2];
#pragma unroll
  for (int i = 0; i < 4; ++i)
#pragma unroll
    for (int j = 0; j < 2; ++j) Y[i][j] = f32x4{0.f, 0.f, 0.f, 0.f};
#pragma unroll
  for (int nf = 0; nf < 2; ++nf)
#pragma unroll
    for (int ks = 0; ks < 2; ++ks) {
      bf16x8 hf = *(const bf16x8*)&hI[nf * 16 + lr][ks * 32 + lk * 8];
#pragma unroll
      for (int mf = 0; mf < 4; ++mf)
        Y[mf][nf] = __builtin_amdgcn_mfma_f32_16x16x32_bf16(cf[mf][ks], hf, Y[mf][nf], 0, 0, 0);
    }
#pragma unroll
  for (int mf = 0; mf < 4; ++mf)
#pragma unroll
    for (int r = 0; r < 4; ++r) {
      float e = __expf(lp[(rowB + t0 + mf * 16 + lk * 4 + r) * NH_ + h]);
      Y[mf][0][r] *= e;
      Y[mf][1][r] *= e;
    }
  float tlp[4];
#pragma unroll
  for (int tf = 0; tf < 4; ++tf)
    tlp[tf] = lp[(rowB + t0 + tf * 16 + lr) * NH_ + h];

  for (int st = 0; st <= w; ++st) {
    const int s0 = st * 64;
#pragma unroll
    for (int half = 0; half < 2; ++half) {
      f32x4 ST[2][4];
#pragma unroll
      for (int i = 0; i < 2; ++i)
#pragma unroll
        for (int j = 0; j < 4; ++j) ST[i][j] = f32x4{0.f, 0.f, 0.f, 0.f};
#pragma unroll
      for (int sf2 = 0; sf2 < 2; ++sf2) {
        int sf = half * 2 + sf2;
#pragma unroll
        for (int ks = 0; ks < 2; ++ks) {
          bf16x8 bfr = *(const bf16x8*)&B16[(rowB + s0 + sf * 16 + lr) * 64 + ks * 32 + lk * 8];
#pragma unroll
          for (int tf = 0; tf < 4; ++tf)
            ST[sf2][tf] = __builtin_amdgcn_mfma_f32_16x16x32_bf16(bfr, cf[tf][ks], ST[sf2][tf], 0, 0, 0);
        }
      }
#pragma unroll
      for (int sf2 = 0; sf2 < 2; ++sf2) {
        int sf = half * 2 + sf2;
        float slp[4];
#pragma unroll
        for (int r = 0; r < 4; ++r)
          slp[r] = lp[(rowB + s0 + sf * 16 + lk * 4 + r) * NH_ + h];
#pragma unroll
        for (int tf = 0; tf < 4; ++tf) {
          float pv[4];
#pragma unroll
          for (int r = 0; r < 4; ++r) {
            pv[r] = ST[sf2][tf][r] * __expf(tlp[tf] - slp[r]);
            if (st == w && (sf * 16 + lk * 4 + r) > (tf * 16 + lr)) pv[r] = 0.f;
          }
          uint2 pk;
          pk.x = (unsigned)(unsigned short)f2b(pv[0]) | ((unsigned)(unsigned short)f2b(pv[1]) << 16);
          pk.y = (unsigned)(unsigned short)f2b(pv[2]) | ((unsigned)(unsigned short)f2b(pv[3]) << 16);
          *(uint2*)&Pl[w][tf * 16 + lr][sf * 16 + lk * 4] = pk;
        }
      }
    }
    // wave-private LDS write->read fence (rule #18)
    __builtin_amdgcn_sched_barrier(0);
    asm volatile("s_waitcnt lgkmcnt(0)" ::: "memory");
    __builtin_amdgcn_sched_barrier(0);
#pragma unroll
    for (int ks = 0; ks < 2; ++ks) {
      bf16x8 vf[2];
#pragma unroll
      for (int nf = 0; nf < 2; ++nf)
        vf[nf] = *(const bf16x8*)&VT[(vtbase + nf * 16 + lr) * 256 + s0 + ks * 32 + lk * 8];
#pragma unroll
      for (int mf = 0; mf < 4; ++mf) {
        bf16x8 pf = *(const bf16x8*)&Pl[w][mf * 16 + lr][ks * 32 + lk * 8];
#pragma unroll
        for (int nf = 0; nf < 2; ++nf)
          Y[mf][nf] = __builtin_amdgcn_mfma_f32_16x16x32_bf16(pf, vf[nf], Y[mf][nf], 0, 0, 0);
      }
    }
  }
  // epilogue with D*x
  const float Dh = Dp[h];
#pragma unroll
  for (int mf = 0; mf < 4; ++mf)
#pragma unroll
    for (int r = 0; r < 4; ++r) {
      size_t yrow = rowB + t0 + mf * 16 + lk * 4 + r;
#pragma unroll
      for (int nf = 0; nf < 2; ++nf) {
        float xv = xBC[yrow * CONVD_ + h * 32 + nf * 16 + lr];
        y16[yrow * DIN_ + h * 32 + nf * 16 + lr] = f2b(Y[mf][nf][r] + Dh * xv);
      }
    }
}

// ============================================================
// t = y * silu(z); out = rmsnorm(t)*nw -> bf16 (row width 1024)
// ============================================================
__global__ __launch_bounds__(256) void ec_gate_rms16(
    const short* __restrict__ y16, const float* __restrict__ zx,
    const float* __restrict__ nw, short* __restrict__ out)
{
  const int row = blockIdx.x;
  const short* yr = y16 + (size_t)row * DIN_;
  const float* zr = zx + (size_t)row * DPROJ_;
  float v[4]; float ss = 0.f;
#pragma unroll
  for (int j = 0; j < 4; ++j) {
    int cc = j * 256 + threadIdx.x;
    float t = b2f(yr[cc]) * siluf(zr[cc]);
    v[j] = t; ss += t * t;
  }
#pragma unroll
  for (int m = 32; m >= 1; m >>= 1) ss += __shfl_xor(ss, m, 64);
  __shared__ float buf[4];
  if ((threadIdx.x & 63) == 0) buf[threadIdx.x >> 6] = ss;
  __syncthreads();
  ss = buf[0] + buf[1] + buf[2] + buf[3];
  float scale = rsqrtf(ss / (float)DIN_ + 1e-5f);
#pragma unroll
  for (int j = 0; j < 4; ++j) {
    int cc = j * 256 + threadIdx.x;
    out[(size_t)row * DIN_ + cc] = f2b(v[j] * scale * nw[cc]);
  }
}

// ============================================================
// out = rmsnorm(a + b)*w -> fp32 + bf16 (row width 512)
// ============================================================
__global__ __launch_bounds__(128) void ec_rmsadd16(
    const float* __restrict__ a, const float* __restrict__ bres,
    const float* __restrict__ w, float* __restrict__ out, short* __restrict__ out16)
{
  const int row = blockIdx.x;
  const float* ar = a + (size_t)row * HID_;
  const float* br = bres + (size_t)row * HID_;
  float v[4]; float ss = 0.f;
#pragma unroll
  for (int j = 0; j < 4; ++j) {
    int c = j * 128 + threadIdx.x;
    float t = ar[c] + br[c];
    v[j] = t; ss += t * t;
  }
#pragma unroll
  for (int m = 32; m >= 1; m >>= 1) ss += __shfl_xor(ss, m, 64);
  __shared__ float buf[2];
  if ((threadIdx.x & 63) == 0) buf[threadIdx.x >> 6] = ss;
  __syncthreads();
  ss = buf[0] + buf[1];
  float scale = rsqrtf(ss / (float)HID_ + 1e-5f);
#pragma unroll
  for (int j = 0; j < 4; ++j) {
    int c = j * 128 + threadIdx.x;
    float o = v[j] * scale * w[c];
    out[(size_t)row * HID_ + c] = o;
    out16[(size_t)row * HID_ + c] = f2b(o);
  }
}

// ============================================================
// layernorm(in)*w + b -> fp32 (+ optional bf16) (row width 512)
// ============================================================
__global__ __launch_bounds__(128) void ec_ln16(
    const float* __restrict__ in, const float* __restrict__ w,
    const float* __restrict__ bb, float* __restrict__ out, short* __restrict__ out16)
{
  const int row = blockIdx.x;
  const float* ir = in + (size_t)row * HID_;
  float v[4]; float s = 0.f, s2 = 0.f;
#pragma unroll
  for (int j = 0; j < 4; ++j) {
    int c = j * 128 + threadIdx.x;
    float t = ir[c];
    v[j] = t; s += t; s2 += t * t;
  }
#pragma unroll
  for (int m = 32; m >= 1; m >>= 1) { s += __shfl_xor(s, m, 64); s2 += __shfl_xor(s2, m, 64); }
  __shared__ float buf[4];
  if ((threadIdx.x & 63) == 0) { int wi = threadIdx.x >> 6; buf[wi * 2] = s; buf[wi * 2 + 1] = s2; }
  __syncthreads();
  s = buf[0] + buf[2]; s2 = buf[1] + buf[3];
  float mean = s / (float)HID_;
  float var = s2 / (float)HID_ - mean * mean;
  float inv = rsqrtf(var + 1e-5f);
#pragma unroll
  for (int j = 0; j < 4; ++j) {
    int c = j * 128 + threadIdx.x;
    float o = (v[j] - mean) * inv * w[c] + bb[c];
    out[(size_t)row * HID_ + c] = o;
    if (out16) out16[(size_t)row * HID_ + c] = f2b(o);
  }
}

// ============================================================
// MFMA flash attention: qkv bf16 [B*LT,1536] -> out bf16 [B*LT,512]
// ============================================================
__global__ __launch_bounds__(256) void ec_attn16(
    const short* __restrict__ qkv, short* __restrict__ out)
{
  const int b = blockIdx.z, h = blockIdx.y, qt = blockIdx.x;
  __shared__ short Kl[64 * 68];
  __shared__ short Vl[64 * 68];
  __shared__ short Pl[64 * 68];
  const int tid = threadIdx.x;
  const int l = tid & 63, w = tid >> 6;
  const int lr = l & 15, lk = l >> 4;

  const size_t qrow = (size_t)b * LT_ + qt * 64 + w * 16 + lr;
  bf16x8 qf[2];
  qf[0] = *(const bf16x8*)&qkv[qrow * 1536 + h * HD_ + lk * 8];
  qf[1] = *(const bf16x8*)&qkv[qrow * 1536 + h * HD_ + lk * 8 + 32];

  float mrun[4] = {-INFINITY, -INFINITY, -INFINITY, -INFINITY};
  float lsum[4] = {0.f, 0.f, 0.f, 0.f};
  f32x4 O[4];
#pragma unroll
  for (int df = 0; df < 4; ++df) O[df] = f32x4{0.f, 0.f, 0.f, 0.f};

  const int krow = tid >> 2, kcg = (tid & 3) * 16;
  const int vd = tid & 63, vw = tid >> 6;

  for (int kt = 0; kt < LT_ / 64; ++kt) {
    const size_t krbase = (size_t)b * LT_ + kt * 64;
    {
      const short* kp = &qkv[(krbase + krow) * 1536 + HID_ + h * HD_ + kcg];
      *(bf16x8*)&Kl[krow * 68 + kcg] = *(const bf16x8*)kp;
      *(bf16x8*)&Kl[krow * 68 + kcg + 8] = *(const bf16x8*)(kp + 8);
    }
#pragma unroll
    for (int kk = 0; kk < 4; ++kk) {
      int key0 = vw * 16 + kk * 4;
      s16x4 pk;
#pragma unroll
      for (int j = 0; j < 4; ++j)
        pk[j] = qkv[(krbase + key0 + j) * 1536 + 2 * HID_ + h * HD_ + vd];
      *(s16x4*)&Vl[vd * 68 + key0] = pk;
    }
    __syncthreads();

    f32x4 S[4];
#pragma unroll
    for (int nf = 0; nf < 4; ++nf) S[nf] = f32x4{0.f, 0.f, 0.f, 0.f};
#pragma unroll
    for (int ks = 0; ks < 2; ++ks)
#pragma unroll
      for (int nf = 0; nf < 4; ++nf) {
        bf16x8 kb = *(const bf16x8*)&Kl[(nf * 16 + lr) * 68 + ks * 32 + lk * 8];
        S[nf] = __builtin_amdgcn_mfma_f32_16x16x32_bf16(qf[ks], kb, S[nf], 0, 0, 0);
      }

    float fr[4];
#pragma unroll
    for (int r = 0; r < 4; ++r) {
      float mt = fmaxf(fmaxf(S[0][r], S[1][r]), fmaxf(S[2][r], S[3][r])) * 0.125f;
      mt = fmaxf(mt, __shfl_xor(mt, 1));
      mt = fmaxf(mt, __shfl_xor(mt, 2));
      mt = fmaxf(mt, __shfl_xor(mt, 4));
      mt = fmaxf(mt, __shfl_xor(mt, 8));
      float mn = fmaxf(mrun[r], mt);
      fr[r] = __expf(mrun[r] - mn);
      mrun[r] = mn;
      lsum[r] *= fr[r];
    }
#pragma unroll
    for (int nf = 0; nf < 4; ++nf)
#pragma unroll
      for (int r = 0; r < 4; ++r) {
        float p = __expf(S[nf][r] * 0.125f - mrun[r]);
        lsum[r] += p;
        Pl[(w * 16 + lk * 4 + r) * 68 + nf * 16 + lr] = f2b(p);
      }
#pragma unroll
    for (int df = 0; df < 4; ++df) {
      O[df][0] *= fr[0]; O[df][1] *= fr[1]; O[df][2] *= fr[2]; O[df][3] *= fr[3];
    }

#pragma unroll
    for (int ks = 0; ks < 2; ++ks) {
      bf16x8 pa = *(const bf16x8*)&Pl[(w * 16 + lr) * 68 + ks * 32 + lk * 8];
#pragma unroll
      for (int df = 0; df < 4; ++df) {
        bf16x8 vb = *(const bf16x8*)&Vl[(df * 16 + lr) * 68 + ks * 32 + lk * 8];
        O[df] = __builtin_amdgcn_mfma_f32_16x16x32_bf16(pa, vb, O[df], 0, 0, 0);
      }
    }
    __syncthreads();
  }

#pragma unroll
  for (int r = 0; r < 4; ++r) {
    lsum[r] += __shfl_xor(lsum[r], 1);
    lsum[r] += __shfl_xor(lsum[r], 2);
    lsum[r] += __shfl_xor(lsum[r], 4);
    lsum[r] += __shfl_xor(lsum[r], 8);
    lsum[r] = 1.f / lsum[r];
  }
  const size_t orow0 = (size_t)b * LT_ + qt * 64 + w * 16;
#pragma unroll
  for (int df = 0; df < 4; ++df)
#pragma unroll
    for (int r = 0; r < 4; ++r)
      out[(orow0 + lk * 4 + r) * HID_ + h * HD_ + df * 16 + lr] = f2b(O[df][r] * lsum[r]);
}

// ============================================================
// host launch
// ============================================================
extern "C" void kernel_launch(void* const* d_in, const int* in_sizes, int n_in,
                              void* d_out, int out_size, void* d_ws, size_t ws_size,
                              hipStream_t stream)
{
  const float* x_in   = (const float*)d_in[0];
  const float* Wp     = (const float*)d_in[1];
  const float* bp     = (const float*)d_in[2];
  const float* m_Wi[2]   = {(const float*)d_in[3],  (const float*)d_in[11]};
  const float* m_cw[2]   = {(const float*)d_in[4],  (const float*)d_in[12]};
  const float* m_cb[2]   = {(const float*)d_in[5],  (const float*)d_in[13]};
  const float* m_dtb[2]  = {(const float*)d_in[6],  (const float*)d_in[14]};
  const float* m_Alog[2] = {(const float*)d_in[7],  (const float*)d_in[15]};
  const float* m_D[2]    = {(const float*)d_in[8],  (const float*)d_in[16]};
  const float* m_nw[2]   = {(const float*)d_in[9],  (const float*)d_in[17]};
  const float* m_Wo[2]   = {(const float*)d_in[10], (const float*)d_in[18]};
  const float* n_w[2]    = {(const float*)d_in[19], (const float*)d_in[20]};
  const float* ds_w   = (const float*)d_in[21];
  const float* ds_b   = (const float*)d_in[22];
  const float* t_Wqkv = (const float*)d_in[23];
  const float* t_bqkv = (const float*)d_in[24];
  const float* t_Wo   = (const float*)d_in[25];
  const float* t_bo   = (const float*)d_in[26];
  const float* t_W1   = (const float*)d_in[27];
  const float* t_b1   = (const float*)d_in[28];
  const float* t_W2   = (const float*)d_in[29];
  const float* t_b2   = (const float*)d_in[30];
  const float* t_ln1w = (const float*)d_in[31];
  const float* t_ln1b = (const float*)d_in[32];
  const float* t_ln2w = (const float*)d_in[33];
  const float* t_ln2b = (const float*)d_in[34];
  const float* on_w   = (const float*)d_in[35];
  const float* on_b   = (const float*)d_in[36];

  char* ws = (char*)d_ws;
  float* bx    = (float*)(ws + 0);            // [8192,512] f32 residual
  float* bzx   = (float*)(ws + 16777216);     // [8192,2208] f32 zxbcdt (+ state dead-cols)
  float* bxbc  = (float*)(ws + 89128960);     // [8192,1152] f32 xBC
  short* y16   = (short*)(ws + 126877696);    // [8192,1024] bf16 scan y
  short* VT    = (short*)(ws + 143654912);    // [b,c,h][32][256] bf16 dtx^T
  float* lp    = (float*)(ws + 160432128);    // [8192,32] log-decay prefix
  float* dts   = (float*)(ws + 161480704);    // [8192,32] dt
  short* wslot = (short*)(ws + 162529280);    // bf16 weight slot / B16+C16 during scan
  float* Pc    = (float*)(ws + 165150720);

  short* B16 = wslot;                          // [8192,64] bf16 (scan window only)
  short* C16 = wslot + 524288;                 // [8192,64]
  float* byf = (float*)(ws + 126877696);       // out-proj f32 out (over dead y16)

  short* x16     = (short*)(ws + 126877696);   // input bf16 (dead before p3)
  short* bx16    = (short*)bxbc;               // residual bf16
  short* gated16 = (short*)((char*)bxbc + 8388608);

  short* ds16  = (short*)bzx;
  float* dsf   = (float*)((char*)bzx + 4194304);
  short* qkv16 = (short*)((char*)bzx + 12582912);
  short* att16 = (short*)((char*)bzx + 25165824);
  float* bt1   = (float*)((char*)bzx + 29360128);
  short* ln116 = (short*)((char*)bzx + 37748736);
  float* bxt2  = (float*)((char*)bzx + 41943040);
  short* ff16  = (short*)((char*)bzx + 50331648);
  float* bt2   = (float*)((char*)bzx + 58720256);
  float* bxt3  = (float*)bxbc;

  const int MR = BB_ * LSEQ_;  // 8192
  const int MT = BB_ * LT_;    // 4096

  // input projection
  ec_f2b<<<(MR * 1024 / 8 + 255) / 256, 256, 0, stream>>>(x_in, x16, MR * 1024 / 8);
  ec_w2bt<<<dim3(1024 / 32, 512 / 32), 256, 0, stream>>>(Wp, wslot, 1024, 512);
  gemm16(stream, x16, wslot, bp, nullptr, bx, bx16, MR, HID_, 1024, 0);

  for (int blk = 0; blk < 2; ++blk) {
    ec_w2bt<<<dim3(512 / 32, 2208 / 32), 256, 0, stream>>>(m_Wi[blk], wslot, 512, 2208);
    gemm16(stream, bx16, wslot, nullptr, nullptr, bzx, nullptr, MR, DPROJ_, HID_, 0);
    ec_conv1d_silu<<<(MR * CONVD_ + 255) / 256, 256, 0, stream>>>(bzx, m_cw[blk], m_cb[blk], bxbc);
    ec_ssd_cumsum<<<dim3(NC_, BB_, NH_ / 8), 256, 0, stream>>>(bzx, m_dtb[blk], m_Alog[blk], dts, lp, Pc);
    ec_bc16<<<(MR * 128 + 255) / 256, 256, 0, stream>>>(bxbc, B16, C16);
    ec_vt<<<dim3(NH_, NC_, BB_), 64, 0, stream>>>(bxbc, dts, VT);
    ec_ssd_p1<<<dim3(NH_, NC_, BB_), 64, 0, stream>>>(B16, VT, lp, bzx);
    ec_scan_p2<<<dim3(NH_, BB_), 512, 0, stream>>>(bzx, Pc);
    ec_ssd_p3<<<dim3(NH_, NC_, BB_), 256, 0, stream>>>(B16, C16, VT, lp, bxbc, m_D[blk], bzx, y16);
    ec_gate_rms16<<<MR, 256, 0, stream>>>(y16, bzx, m_nw[blk], gated16);
    ec_w2bt<<<dim3(1024 / 32, 512 / 32), 256, 0, stream>>>(m_Wo[blk], wslot, 1024, 512);
    gemm16(stream, gated16, wslot, nullptr, nullptr, byf, nullptr, MR, HID_, DIN_, 0);
    ec_rmsadd16<<<MR, 128, 0, stream>>>(byf, bx, n_w[blk], bx, bx16);
  }

  // downsample conv as implicit-im2col GEMM
  ec_dswt<<<(HID_ * 1536 + 255) / 256, 256, 0, stream>>>(ds_w, wslot);
  {
    dim3 g(512 / 128, LT_ / 128, BB_), b(256);
    ec_gemm16<<<g, b, 0, stream>>>(bx16 - 512, wslot, ds_b, nullptr, dsf, ds16,
                                   LT_, HID_, 1536, 0, 1024, (long)LSEQ_ * HID_, LT_);
  }
  ec_dsfix<<<BB_, 512, 0, stream>>>(bx16, wslot, ds_b, dsf, ds16);

  // transformer layer
  ec_w2bt<<<dim3(512 / 32, 1536 / 32), 256, 0, stream>>>(t_Wqkv, wslot, 512, 1536);
  gemm16(stream, ds16, wslot, t_bqkv, nullptr, nullptr, qkv16, MT, 3 * HID_, HID_, 0);
  ec_attn16<<<dim3(LT_ / 64, NHEAD_, BB_), 256, 0, stream>>>(qkv16, att16);
  ec_w2bt<<<dim3(512 / 32, 512 / 32), 256, 0, stream>>>(t_Wo, wslot, 512, 512);
  gemm16(stream, att16, wslot, t_bo, dsf, bt1, nullptr, MT, HID_, HID_, 0);
  ec_ln16<<<MT, 128, 0, stream>>>(bt1, t_ln1w, t_ln1b, bxt2, ln116);
  ec_w2bt<<<dim3(512 / 32, 1024 / 32), 256, 0, stream>>>(t_W1, wslot, 512, 1024);
  gemm16(stream, ln116, wslot, t_b1, nullptr, nullptr, ff16, MT, DFF_, HID_, 1);
  ec_w2bt<<<dim3(1024 / 32, 512 / 32), 256, 0, stream>>>(t_W2, wslot, 1024, 512);
  gemm16(stream, ff16, wslot, t_b2, bxt2, bt2, nullptr, MT, HID_, DFF_, 0);
  ec_ln16<<<MT, 128, 0, stream>>>(bt2, t_ln2w, t_ln2b, bxt3, nullptr);
  ec_ln16<<<MT, 128, 0, stream>>>(bxt3, on_w, on_b, (float*)d_out, nullptr);
}